// Round 3
// baseline (542.844 us; speedup 1.0000x reference)
//
#include <hip/hip_runtime.h>
#include <hip/hip_bf16.h>
#include <stdint.h>

#define QL   2048
#define KLn  2048
#define DIM  512
#define NH   8
#define DH   64
#define NB   2
#define MROWS (NB*QL)   // 4096
#define FFD  2048

typedef unsigned short u16;
typedef unsigned int u32;
typedef __attribute__((ext_vector_type(8))) short short8;
typedef __attribute__((ext_vector_type(4))) float f32x4;

__device__ __forceinline__ u16 f2b(float f){
  union { float f; u32 i; } v; v.f = f;
  u32 r = v.i + 0x7FFFu + ((v.i >> 16) & 1u);
  return (u16)(r >> 16);
}
// pack two fp32 -> bf16x2 word (round-half-up; inputs are softmax probs >= 0)
__device__ __forceinline__ u32 pack2(float a, float b){
  union { float f; u32 i; } va, vb; va.f = a; vb.f = b;
  return ((va.i + 0x8000u) >> 16) | ((vb.i + 0x8000u) & 0xFFFF0000u);
}

typedef __attribute__((address_space(3))) void as3void;
typedef __attribute__((address_space(1))) void as1void;
__device__ __forceinline__ void gload_lds16(const void* g, void* l){
  __builtin_amdgcn_global_load_lds((as1void*)g, (as3void*)l, 16, 0, 0);
}

// ---------------------------------------------------------------- GEMM
#define BM 128
#define BN 128
#define BK 32
enum { EPI_BIAS=0, EPI_SCALEQ=1, EPI_RELU=2, EPI_RES=3 };
// 1/sqrt(64) * log2(e): folds softmax exp->exp2 conversion into Q scale
#define QSCALE 0.1803368801111244f

template<int EPI>
__global__ __launch_bounds__(256, 2)
void gemm_bt(const u16* __restrict__ A, const u16* __restrict__ Bt,
             const float* __restrict__ bias,
             u16* __restrict__ Obf, float* __restrict__ Ores,
             int K, int N)
{
  __shared__ __align__(16) u16 As[BM*BK];
  __shared__ __align__(16) u16 Bs[BN*BK];
  const int t  = threadIdx.x;
  const int l  = t & 63;
  const int lq = l & 15, lg = l >> 4;
  const int w  = t >> 6;
  const int wm = (w >> 1) * 64;
  const int wn = (w & 1) * 64;
  const int m0 = blockIdx.y * BM;
  const int n0 = blockIdx.x * BN;

  const int srow  = t >> 2;        // 0..63
  const int skseg = (t & 3) * 8;   // 0,8,16,24

  const u16* Ag = A  + (size_t)(m0 + srow) * K + skseg;
  const u16* Bg = Bt + (size_t)(n0 + srow) * K + skseg;
  u16* As0 = &As[srow*BK + skseg];
  u16* As1 = &As[(srow+64)*BK + skseg];
  u16* Bs0 = &Bs[srow*BK + skseg];
  u16* Bs1 = &Bs[(srow+64)*BK + skseg];
  const size_t rowhop = (size_t)64 * K;

  f32x4 acc[4][4];
  #pragma unroll
  for (int i=0;i<4;i++)
    #pragma unroll
    for (int j=0;j<4;j++) acc[i][j] = (f32x4){0.f,0.f,0.f,0.f};

  for (int k0 = 0; k0 < K; k0 += BK){
    gload_lds16(Ag + k0,          As0);
    gload_lds16(Ag + k0 + rowhop, As1);
    gload_lds16(Bg + k0,          Bs0);
    gload_lds16(Bg + k0 + rowhop, Bs1);
    __syncthreads();
    short8 af[4], bf[4];
    #pragma unroll
    for (int i=0;i<4;i++) af[i] = *(const short8*)&As[(wm + i*16 + lq)*BK + lg*8];
    #pragma unroll
    for (int j=0;j<4;j++) bf[j] = *(const short8*)&Bs[(wn + j*16 + lq)*BK + lg*8];
    #pragma unroll
    for (int i=0;i<4;i++)
      #pragma unroll
      for (int j=0;j<4;j++)
        acc[i][j] = __builtin_amdgcn_mfma_f32_16x16x32_bf16(af[i], bf[j], acc[i][j], 0,0,0);
    __syncthreads();
  }

  #pragma unroll
  for (int i=0;i<4;i++){
    #pragma unroll
    for (int j=0;j<4;j++){
      #pragma unroll
      for (int r=0;r<4;r++){
        const int row = m0 + wm + i*16 + lg*4 + r;
        const int col = n0 + wn + j*16 + lq;
        float v = acc[i][j][r] + bias[col];
        if (EPI == EPI_SCALEQ) v *= QSCALE;
        if (EPI == EPI_RELU)   v = fmaxf(v, 0.f);
        if (EPI == EPI_RES)    Ores[(size_t)row*N + col] += v;
        else                   Obf[(size_t)row*N + col] = f2b(v);
      }
    }
  }
}

// ---------------------------------------------------------------- attention v3
// 4 waves per block, intra-block KV split (wave w takes tiles t%4==w) with
// per-wave online softmax and a final LDS merge. Swapped QK^T keeps each
// lane's q-row scores in-register; PV K-slot permutation (V pre-permuted)
// keeps P lane-local; exp2-domain softmax.
template<bool CAUSAL>
__global__ __launch_bounds__(256, 8)
void attn3(const u16* __restrict__ Q, const u16* __restrict__ Kb,
           const u16* __restrict__ Vt, const float* __restrict__ bias,
           u16* __restrict__ O)
{
  const int tid = threadIdx.x;
  const int l  = tid & 63;
  const int w  = tid >> 6;         // kv-split index 0..3
  const int lq = l & 15, lg = l >> 4;
  const int q0 = blockIdx.x * 16;
  const int h  = blockIdx.y;
  const int b  = blockIdx.z;

  short8 aq[2];
  #pragma unroll
  for (int kc = 0; kc < 2; ++kc)
    aq[kc] = *(const short8*)(Q + (size_t)(b*QL + q0 + lq)*DIM + h*DH + kc*32 + lg*8);

  f32x4 ctx[4];
  #pragma unroll
  for (int d = 0; d < 4; ++d) ctx[d] = (f32x4){0.f,0.f,0.f,0.f};
  float m = -INFINITY, lsum = 0.f;

  const int ntiles = CAUSAL ? ((q0 + 16 + 63) >> 6) : (KLn >> 6);
  for (int t = w; t < ntiles; t += 4){
    const int kvs = t * 64;
    f32x4 s[4];
    #pragma unroll
    for (int sub = 0; sub < 4; ++sub) s[sub] = (f32x4){0.f,0.f,0.f,0.f};
    #pragma unroll
    for (int sub = 0; sub < 4; ++sub){
      const u16* kp = Kb + (size_t)(b*KLn + kvs + sub*16 + lq)*DIM + h*DH;
      #pragma unroll
      for (int kc = 0; kc < 2; ++kc){
        short8 bk = *(const short8*)(kp + kc*32 + lg*8);
        s[sub] = __builtin_amdgcn_mfma_f32_16x16x32_bf16(bk, aq[kc], s[sub], 0,0,0);
      }
    }
    // lane holds S[kv = kvs+sub*16+lg*4+r][q = q0+lq]
    if (CAUSAL){
      if (kvs + 63 > q0){
        #pragma unroll
        for (int sub = 0; sub < 4; ++sub)
          #pragma unroll
          for (int r = 0; r < 4; ++r)
            if (kvs + sub*16 + lg*4 + r > q0 + lq) s[sub][r] = -INFINITY;
      }
    } else {
      #pragma unroll
      for (int sub = 0; sub < 4; ++sub){
        f32x4 bv = *(const f32x4*)(bias + b*KLn + kvs + sub*16 + lg*4);
        s[sub] += bv;
      }
    }
    float pmax = s[0][0];
    #pragma unroll
    for (int sub = 0; sub < 4; ++sub)
      #pragma unroll
      for (int r = 0; r < 4; ++r) pmax = fmaxf(pmax, s[sub][r]);
    pmax = fmaxf(pmax, __shfl_xor(pmax, 16));
    pmax = fmaxf(pmax, __shfl_xor(pmax, 32));
    const float mnew = fmaxf(m, pmax);
    const float corr = exp2f(m - mnew);
    float psum = 0.f;
    u32 pk[4][2];
    #pragma unroll
    for (int sub = 0; sub < 4; ++sub){
      float p0 = exp2f(s[sub][0] - mnew);
      float p1 = exp2f(s[sub][1] - mnew);
      float p2 = exp2f(s[sub][2] - mnew);
      float p3 = exp2f(s[sub][3] - mnew);
      psum += (p0 + p1) + (p2 + p3);
      pk[sub][0] = pack2(p0, p1);
      pk[sub][1] = pack2(p2, p3);
    }
    psum += __shfl_xor(psum, 16);
    psum += __shfl_xor(psum, 32);
    lsum = lsum * corr + psum;
    m = mnew;
    float corr4[4];
    #pragma unroll
    for (int r = 0; r < 4; ++r) corr4[r] = __shfl(corr, lg*4 + r);
    #pragma unroll
    for (int d = 0; d < 4; ++d)
      #pragma unroll
      for (int r = 0; r < 4; ++r) ctx[d][r] *= corr4[r];
    union { u32 u[4]; short8 s8; } pa0, pa1;
    pa0.u[0] = pk[0][0]; pa0.u[1] = pk[0][1]; pa0.u[2] = pk[1][0]; pa0.u[3] = pk[1][1];
    pa1.u[0] = pk[2][0]; pa1.u[1] = pk[2][1]; pa1.u[2] = pk[3][0]; pa1.u[3] = pk[3][1];
    #pragma unroll
    for (int d0 = 0; d0 < 4; ++d0){
      const u16* vp = Vt + (size_t)(b*DIM + h*DH + d0*16 + lq)*KLn + kvs;
      short8 v0 = *(const short8*)(vp + lg*8);
      short8 v1 = *(const short8*)(vp + 32 + lg*8);
      ctx[d0] = __builtin_amdgcn_mfma_f32_16x16x32_bf16(pa0.s8, v0, ctx[d0], 0,0,0);
      ctx[d0] = __builtin_amdgcn_mfma_f32_16x16x32_bf16(pa1.s8, v1, ctx[d0], 0,0,0);
    }
  }

  // ---- merge the 4 KV-split partials
  __shared__ __align__(16) float ctx_lds[4][64][16];  // [wave][lane][elem]
  __shared__ float ml[4][2][16];                      // [wave][{m,l}][qrow]
  #pragma unroll
  for (int d0 = 0; d0 < 4; ++d0)
    *(f32x4*)&ctx_lds[w][l][d0*4] = ctx[d0];
  if (l < 16){ ml[w][0][l] = m; ml[w][1][l] = lsum; }
  __syncthreads();

  const int col = tid & 63;
  const int r0  = tid >> 6;
  #pragma unroll
  for (int i = 0; i < 4; ++i){
    const int row = i*4 + r0;
    const int srclane = ((row >> 2) << 4) | (col & 15);
    const int idx = (col >> 4)*4 + (row & 3);
    float mg = ml[0][0][row];
    #pragma unroll
    for (int w2 = 1; w2 < 4; ++w2) mg = fmaxf(mg, ml[w2][0][row]);
    float num = 0.f, den = 0.f;
    #pragma unroll
    for (int w2 = 0; w2 < 4; ++w2){
      const float sc = exp2f(ml[w2][0][row] - mg);
      den += ml[w2][1][row] * sc;
      num += ctx_lds[w2][srclane][idx] * sc;
    }
    O[(size_t)(b*QL + q0 + row)*DIM + h*DH + col] = f2b(num / den);
  }
}

// ---------------------------------------------------------------- layernorm
template<int MODE>
__global__ __launch_bounds__(128)
void ln_kernel(const float* __restrict__ in0, const float* __restrict__ in1,
               const float* __restrict__ tkpm,
               const float* __restrict__ g, const float* __restrict__ bvec,
               float* __restrict__ xres, u16* __restrict__ outb)
{
  const int row = blockIdx.x;
  const int t = threadIdx.x;
  float v[4];
  #pragma unroll
  for (int i = 0; i < 4; ++i){
    const int c = t + i*128;
    float x = in0[(size_t)row*DIM + c];
    if (MODE == 0){
      x += in1[(size_t)row*DIM + c];
      xres[(size_t)row*DIM + c] = x;
    }
    v[i] = x;
  }
  float s = v[0]+v[1]+v[2]+v[3];
  #pragma unroll
  for (int off = 1; off < 64; off <<= 1) s += __shfl_xor(s, off);
  __shared__ float red[4];
  if ((t & 63) == 0) red[t >> 6] = s;
  __syncthreads();
  const float mean = (red[0] + red[1]) * (1.f/512.f);
  float q = 0.f;
  #pragma unroll
  for (int i = 0; i < 4; ++i){ const float d = v[i]-mean; q += d*d; }
  #pragma unroll
  for (int off = 1; off < 64; off <<= 1) q += __shfl_xor(q, off);
  if ((t & 63) == 0) red[2 + (t >> 6)] = q;
  __syncthreads();
  const float var = (red[2] + red[3]) * (1.f/512.f);
  const float rs = rsqrtf(var + 1e-5f);
  const float tk = (MODE == 0) ? tkpm[row] : 1.f;
  #pragma unroll
  for (int i = 0; i < 4; ++i){
    const int c = t + i*128;
    const float y = (v[i] - mean) * rs * g[c] + bvec[c];
    outb[(size_t)row*DIM + c] = f2b(y * tk);
  }
}

// ---------------------------------------------------------------- transposes / misc
__global__ __launch_bounds__(256)
void transpose_f2b(const float* __restrict__ in, u16* __restrict__ out, int R, int C)
{
  __shared__ float tile[32][33];
  const int tx = threadIdx.x, ty = threadIdx.y;
  const int r0 = blockIdx.y*32, c0 = blockIdx.x*32;
  #pragma unroll
  for (int i = 0; i < 4; ++i)
    tile[ty + i*8][tx] = in[(size_t)(r0 + ty + i*8)*C + c0 + tx];
  __syncthreads();
  #pragma unroll
  for (int i = 0; i < 4; ++i)
    out[(size_t)(c0 + ty + i*8)*R + r0 + tx] = f2b(tile[tx][ty + i*8]);
}

__global__ __launch_bounds__(256)
void transpose8_f2b(const float* w0, const float* w1, const float* w2, const float* w3,
                    const float* w4, const float* w5, const float* w6, const float* w7,
                    u16* __restrict__ out)
{
  __shared__ float tile[32][33];
  const float* wp[8] = {w0,w1,w2,w3,w4,w5,w6,w7};
  const float* w = wp[blockIdx.z];
  u16* o = out + (size_t)blockIdx.z * 512 * 512;
  const int tx = threadIdx.x, ty = threadIdx.y;
  const int r0 = blockIdx.y*32, c0 = blockIdx.x*32;
  #pragma unroll
  for (int i = 0; i < 4; ++i)
    tile[ty + i*8][tx] = w[(size_t)(r0 + ty + i*8)*512 + c0 + tx];
  __syncthreads();
  #pragma unroll
  for (int i = 0; i < 4; ++i)
    o[(size_t)(c0 + ty + i*8)*512 + r0 + tx] = f2b(tile[tx][ty + i*8]);
}

// V [b][kv][512] -> Vt [b][d][slot(kv)] with the PV K-slot permutation folded in
__global__ __launch_bounds__(256)
void transpose_vperm(const u16* __restrict__ in, u16* __restrict__ out)
{
  __shared__ u16 tile[32][33];
  in  += (size_t)blockIdx.z * KLn * DIM;
  out += (size_t)blockIdx.z * KLn * DIM;
  const int tx = threadIdx.x, ty = threadIdx.y;
  const int r0 = blockIdx.y*32, c0 = blockIdx.x*32;   // r=kv, c=d
  #pragma unroll
  for (int i = 0; i < 4; ++i)
    tile[ty + i*8][tx] = in[(size_t)(r0 + ty + i*8)*DIM + c0 + tx];
  __syncthreads();
  const int kv = r0 + tx;
  const int slot = (kv & ~31) | (((kv>>2)&3)<<3) | (((kv>>4)&1)<<2) | (kv&3);
  #pragma unroll
  for (int i = 0; i < 4; ++i)
    out[(size_t)(c0 + ty + i*8)*KLn + slot] = tile[tx][ty + i*8];
}

__global__ void cvt_f2b(const float* __restrict__ in, u16* __restrict__ out, int n){
  const int i = blockIdx.x*blockDim.x + threadIdx.x;
  if (i < n) out[i] = f2b(in[i]);
}

__global__ void maskbias_k(const int* __restrict__ mkpm, float* __restrict__ bias, int n){
  const int i = blockIdx.x*blockDim.x + threadIdx.x;
  if (i < n) bias[i] = mkpm[i] ? 0.f : -1e30f;
}

__global__ void finalize_k(const float* __restrict__ xres, const float* __restrict__ tkpm,
                           float* __restrict__ out){
  const int i = blockIdx.x*blockDim.x + threadIdx.x;
  out[i] = xres[i] * tkpm[i >> 9];
}

// ---------------------------------------------------------------- launch
extern "C" void kernel_launch(void* const* d_in, const int* in_sizes, int n_in,
                              void* d_out, int out_size, void* d_ws, size_t ws_size,
                              hipStream_t stream)
{
  const float* tgt  = (const float*)d_in[1];
  const float* mem  = (const float*)d_in[2];
  const float* pos  = (const float*)d_in[3];
  const float* tkpm = (const float*)d_in[5];
  const int*   mkpm = (const int*)d_in[6];
  const float* saqw = (const float*)d_in[7];  const float* saqb = (const float*)d_in[8];
  const float* sakw = (const float*)d_in[9];  const float* sakb = (const float*)d_in[10];
  const float* savw = (const float*)d_in[11]; const float* savb = (const float*)d_in[12];
  const float* saow = (const float*)d_in[13]; const float* saob = (const float*)d_in[14];
  const float* caqw = (const float*)d_in[15]; const float* caqb = (const float*)d_in[16];
  const float* cakw = (const float*)d_in[17]; const float* cakb = (const float*)d_in[18];
  const float* cavw = (const float*)d_in[19]; const float* cavb = (const float*)d_in[20];
  const float* caow = (const float*)d_in[21]; const float* caob = (const float*)d_in[22];
  const float* l1w  = (const float*)d_in[23]; const float* l1b  = (const float*)d_in[24];
  const float* l2w  = (const float*)d_in[25]; const float* l2b  = (const float*)d_in[26];
  const float* n1g  = (const float*)d_in[27]; const float* n1b  = (const float*)d_in[28];
  const float* n2g  = (const float*)d_in[29]; const float* n2b  = (const float*)d_in[30];
  const float* n3g  = (const float*)d_in[31]; const float* n3b  = (const float*)d_in[32];

  if (ws_size < 58720256) return;  // 56 MB scratch

  char* ws = (char*)d_ws;
  float* xres = (float*)(ws);                      // 8 MB  f32 residual
  u16* t2n    = (u16*)(ws + (8u<<20));             // 4 MB  LN out / attn out (aliased)
  u16* qb     = (u16*)(ws + (12u<<20));            // 4 MB
  u16* kb     = (u16*)(ws + (16u<<20));            // 4 MB
  u16* vb     = (u16*)(ws + (20u<<20));            // 4 MB  (later reused for FF weightT)
  u16* vt     = (u16*)(ws + (24u<<20));            // 4 MB  permuted V^T
  float* bias = (float*)(ws + (28u<<20));          // 16 KB cross-attn additive mask
  u16* memb   = (u16*)(ws + (32u<<20));            // 4 MB  memory in bf16
  u16* ffh    = (u16*)(ws + (36u<<20));            // 16 MB FF hidden
  u16* wtA    = (u16*)(ws + (52u<<20));            // 4 MB  8x 512x512 attn weightT
  u16* l1wt   = vb;                                // 2 MB  (after cross vperm)
  u16* l2wt   = (u16*)(ws + (22u<<20));            // 2 MB

  float* out = (float*)d_out;
  const int W55 = 512*512;

  maskbias_k<<<dim3(NB*KLn/256), 256, 0, stream>>>(mkpm, bias, NB*KLn);
  cvt_f2b<<<dim3(MROWS*DIM/256), 256, 0, stream>>>(mem, memb, MROWS*DIM);
  ln_kernel<0><<<MROWS, 128, 0, stream>>>(tgt, pos, tkpm, n1g, n1b, xres, t2n);
  transpose8_f2b<<<dim3(16,16,8), dim3(32,8), 0, stream>>>(saqw, sakw, savw, saow,
                                                           caqw, cakw, cavw, caow, wtA);

  // ---- self attention
  gemm_bt<EPI_SCALEQ><<<dim3(4,32), 256, 0, stream>>>(t2n, wtA + 0*W55, saqb, qb, nullptr, 512, 512);
  gemm_bt<EPI_BIAS>  <<<dim3(4,32), 256, 0, stream>>>(t2n, wtA + 1*W55, sakb, kb, nullptr, 512, 512);
  gemm_bt<EPI_BIAS>  <<<dim3(4,32), 256, 0, stream>>>(t2n, wtA + 2*W55, savb, vb, nullptr, 512, 512);
  transpose_vperm<<<dim3(DIM/32, KLn/32, NB), dim3(32,8), 0, stream>>>(vb, vt);
  attn3<true><<<dim3(QL/16, NH, NB), 256, 0, stream>>>(qb, kb, vt, nullptr, t2n);
  gemm_bt<EPI_RES>   <<<dim3(4,32), 256, 0, stream>>>(t2n, wtA + 3*W55, saob, nullptr, xres, 512, 512);

  ln_kernel<1><<<MROWS, 128, 0, stream>>>(xres, nullptr, nullptr, n2g, n2b, nullptr, t2n);

  // ---- cross attention
  gemm_bt<EPI_SCALEQ><<<dim3(4,32), 256, 0, stream>>>(t2n,  wtA + 4*W55, caqb, qb, nullptr, 512, 512);
  gemm_bt<EPI_BIAS>  <<<dim3(4,32), 256, 0, stream>>>(memb, wtA + 5*W55, cakb, kb, nullptr, 512, 512);
  gemm_bt<EPI_BIAS>  <<<dim3(4,32), 256, 0, stream>>>(memb, wtA + 6*W55, cavb, vb, nullptr, 512, 512);
  transpose_vperm<<<dim3(DIM/32, KLn/32, NB), dim3(32,8), 0, stream>>>(vb, vt);
  transpose_f2b<<<dim3(FFD/32, 512/32), dim3(32,8), 0, stream>>>(l1w, l1wt, 512, FFD);
  transpose_f2b<<<dim3(512/32, FFD/32), dim3(32,8), 0, stream>>>(l2w, l2wt, FFD, 512);
  attn3<false><<<dim3(QL/16, NH, NB), 256, 0, stream>>>(qb, kb, vt, bias, t2n);
  gemm_bt<EPI_RES>   <<<dim3(4,32), 256, 0, stream>>>(t2n, wtA + 7*W55, caob, nullptr, xres, 512, 512);

  ln_kernel<1><<<MROWS, 128, 0, stream>>>(xres, nullptr, nullptr, n3g, n3b, nullptr, t2n);

  // ---- feed-forward
  gemm_bt<EPI_RELU><<<dim3(16,32), 256, 0, stream>>>(t2n, l1wt, l1b, ffh, nullptr, 512, FFD);
  gemm_bt<EPI_RES> <<<dim3(4,32),  256, 0, stream>>>(ffh, l2wt, l2b, nullptr, xres, FFD, 512);

  finalize_k<<<dim3(MROWS*DIM/256), 256, 0, stream>>>(xres, tkpm, out);
}

// Round 4
// 489.546 us; speedup vs baseline: 1.1089x; 1.1089x over previous
//
#include <hip/hip_runtime.h>
#include <hip/hip_bf16.h>
#include <stdint.h>

#define QL   2048
#define KLn  2048
#define DIM  512
#define NH   8
#define DH   64
#define NB   2
#define MROWS (NB*QL)   // 4096
#define FFD  2048

typedef unsigned short u16;
typedef unsigned int u32;
typedef __attribute__((ext_vector_type(8))) short short8;
typedef __attribute__((ext_vector_type(4))) float f32x4;

__device__ __forceinline__ u16 f2b(float f){
  union { float f; u32 i; } v; v.f = f;
  u32 r = v.i + 0x7FFFu + ((v.i >> 16) & 1u);
  return (u16)(r >> 16);
}
// pack two fp32 -> bf16x2 word (round-half-up; inputs are softmax probs >= 0)
__device__ __forceinline__ u32 pack2(float a, float b){
  union { float f; u32 i; } va, vb; va.f = a; vb.f = b;
  return ((va.i + 0x8000u) >> 16) | ((vb.i + 0x8000u) & 0xFFFF0000u);
}

typedef __attribute__((address_space(3))) void as3void;
typedef __attribute__((address_space(1))) void as1void;
__device__ __forceinline__ void gload_lds16(const void* g, void* l){
  __builtin_amdgcn_global_load_lds((as1void*)g, (as3void*)l, 16, 0, 0);
}

// ---------------------------------------------------------------- GEMM
#define BM 128
#define BN 128
#define BK 32
enum { EPI_BIAS=0, EPI_SCALEQ=1, EPI_RELU=2, EPI_RES=3 };
// 1/sqrt(64) * log2(e): folds softmax exp->exp2 conversion into Q scale
#define QSCALE 0.1803368801111244f

template<int EPI>
__global__ __launch_bounds__(256, 2)
void gemm_bt(const u16* __restrict__ A, const u16* __restrict__ Bt,
             const float* __restrict__ bias,
             u16* __restrict__ Obf, float* __restrict__ Ores,
             int K, int N)
{
  __shared__ __align__(16) u16 As[BM*BK];
  __shared__ __align__(16) u16 Bs[BN*BK];
  const int t  = threadIdx.x;
  const int l  = t & 63;
  const int lq = l & 15, lg = l >> 4;
  const int w  = t >> 6;
  const int wm = (w >> 1) * 64;
  const int wn = (w & 1) * 64;
  const int m0 = blockIdx.y * BM;
  const int n0 = blockIdx.x * BN;

  const int srow  = t >> 2;        // 0..63
  const int skseg = (t & 3) * 8;   // 0,8,16,24

  const u16* Ag = A  + (size_t)(m0 + srow) * K + skseg;
  const u16* Bg = Bt + (size_t)(n0 + srow) * K + skseg;
  u16* As0 = &As[srow*BK + skseg];
  u16* As1 = &As[(srow+64)*BK + skseg];
  u16* Bs0 = &Bs[srow*BK + skseg];
  u16* Bs1 = &Bs[(srow+64)*BK + skseg];
  const size_t rowhop = (size_t)64 * K;

  f32x4 acc[4][4];
  #pragma unroll
  for (int i=0;i<4;i++)
    #pragma unroll
    for (int j=0;j<4;j++) acc[i][j] = (f32x4){0.f,0.f,0.f,0.f};

  for (int k0 = 0; k0 < K; k0 += BK){
    gload_lds16(Ag + k0,          As0);
    gload_lds16(Ag + k0 + rowhop, As1);
    gload_lds16(Bg + k0,          Bs0);
    gload_lds16(Bg + k0 + rowhop, Bs1);
    __syncthreads();
    short8 af[4], bf[4];
    #pragma unroll
    for (int i=0;i<4;i++) af[i] = *(const short8*)&As[(wm + i*16 + lq)*BK + lg*8];
    #pragma unroll
    for (int j=0;j<4;j++) bf[j] = *(const short8*)&Bs[(wn + j*16 + lq)*BK + lg*8];
    #pragma unroll
    for (int i=0;i<4;i++)
      #pragma unroll
      for (int j=0;j<4;j++)
        acc[i][j] = __builtin_amdgcn_mfma_f32_16x16x32_bf16(af[i], bf[j], acc[i][j], 0,0,0);
    __syncthreads();
  }

  #pragma unroll
  for (int i=0;i<4;i++){
    #pragma unroll
    for (int j=0;j<4;j++){
      #pragma unroll
      for (int r=0;r<4;r++){
        const int row = m0 + wm + i*16 + lg*4 + r;
        const int col = n0 + wn + j*16 + lq;
        float v = acc[i][j][r] + bias[col];
        if (EPI == EPI_SCALEQ) v *= QSCALE;
        if (EPI == EPI_RELU)   v = fmaxf(v, 0.f);
        if (EPI == EPI_RES)    Ores[(size_t)row*N + col] += v;
        else                   Obf[(size_t)row*N + col] = f2b(v);
      }
    }
  }
}

// ---------------------------------------------------------------- attention v3b
// 4 waves per block, intra-block KV split (wave w takes tiles t%4==w) with
// per-wave online softmax and a final LDS merge. Swapped QK^T keeps each
// lane's q-row scores in-register; PV K-slot permutation (V pre-permuted)
// keeps P lane-local; exp2-domain softmax.
// launch_bounds(256,4): 128-VGPR cap — (256,8) forced a 64-VGPR cap and the
// allocator spilled the loop state to scratch (R3: FETCH 35->110MB, WRITE
// 4->51MB, VGPR_Count=32, zero speedup). Registers must hold all loop state.
template<bool CAUSAL>
__global__ __launch_bounds__(256, 4)
void attn3(const u16* __restrict__ Q, const u16* __restrict__ Kb,
           const u16* __restrict__ Vt, const float* __restrict__ bias,
           u16* __restrict__ O)
{
  const int tid = threadIdx.x;
  const int l  = tid & 63;
  const int w  = tid >> 6;         // kv-split index 0..3
  const int lq = l & 15, lg = l >> 4;
  const int q0 = blockIdx.x * 16;
  const int h  = blockIdx.y;
  const int b  = blockIdx.z;

  short8 aq[2];
  #pragma unroll
  for (int kc = 0; kc < 2; ++kc)
    aq[kc] = *(const short8*)(Q + (size_t)(b*QL + q0 + lq)*DIM + h*DH + kc*32 + lg*8);

  f32x4 ctx[4];
  #pragma unroll
  for (int d = 0; d < 4; ++d) ctx[d] = (f32x4){0.f,0.f,0.f,0.f};
  float m = -INFINITY, lsum = 0.f;

  const int ntiles = CAUSAL ? ((q0 + 16 + 63) >> 6) : (KLn >> 6);
  for (int t = w; t < ntiles; t += 4){
    const int kvs = t * 64;
    f32x4 s[4];
    #pragma unroll
    for (int sub = 0; sub < 4; ++sub) s[sub] = (f32x4){0.f,0.f,0.f,0.f};
    #pragma unroll
    for (int sub = 0; sub < 4; ++sub){
      const u16* kp = Kb + (size_t)(b*KLn + kvs + sub*16 + lq)*DIM + h*DH;
      #pragma unroll
      for (int kc = 0; kc < 2; ++kc){
        short8 bk = *(const short8*)(kp + kc*32 + lg*8);
        s[sub] = __builtin_amdgcn_mfma_f32_16x16x32_bf16(bk, aq[kc], s[sub], 0,0,0);
      }
    }
    // lane holds S[kv = kvs+sub*16+lg*4+r][q = q0+lq]
    if (CAUSAL){
      if (kvs + 63 > q0){
        #pragma unroll
        for (int sub = 0; sub < 4; ++sub)
          #pragma unroll
          for (int r = 0; r < 4; ++r)
            if (kvs + sub*16 + lg*4 + r > q0 + lq) s[sub][r] = -INFINITY;
      }
    } else {
      #pragma unroll
      for (int sub = 0; sub < 4; ++sub){
        f32x4 bv = *(const f32x4*)(bias + b*KLn + kvs + sub*16 + lg*4);
        s[sub] += bv;
      }
    }
    float pmax = s[0][0];
    #pragma unroll
    for (int sub = 0; sub < 4; ++sub)
      #pragma unroll
      for (int r = 0; r < 4; ++r) pmax = fmaxf(pmax, s[sub][r]);
    pmax = fmaxf(pmax, __shfl_xor(pmax, 16));
    pmax = fmaxf(pmax, __shfl_xor(pmax, 32));
    const float mnew = fmaxf(m, pmax);
    const float corr = exp2f(m - mnew);
    float psum = 0.f;
    u32 pk[4][2];
    #pragma unroll
    for (int sub = 0; sub < 4; ++sub){
      float p0 = exp2f(s[sub][0] - mnew);
      float p1 = exp2f(s[sub][1] - mnew);
      float p2 = exp2f(s[sub][2] - mnew);
      float p3 = exp2f(s[sub][3] - mnew);
      psum += (p0 + p1) + (p2 + p3);
      pk[sub][0] = pack2(p0, p1);
      pk[sub][1] = pack2(p2, p3);
    }
    psum += __shfl_xor(psum, 16);
    psum += __shfl_xor(psum, 32);
    lsum = lsum * corr + psum;
    m = mnew;
    float corr4[4];
    #pragma unroll
    for (int r = 0; r < 4; ++r) corr4[r] = __shfl(corr, lg*4 + r);
    #pragma unroll
    for (int d = 0; d < 4; ++d)
      #pragma unroll
      for (int r = 0; r < 4; ++r) ctx[d][r] *= corr4[r];
    union { u32 u[4]; short8 s8; } pa0, pa1;
    pa0.u[0] = pk[0][0]; pa0.u[1] = pk[0][1]; pa0.u[2] = pk[1][0]; pa0.u[3] = pk[1][1];
    pa1.u[0] = pk[2][0]; pa1.u[1] = pk[2][1]; pa1.u[2] = pk[3][0]; pa1.u[3] = pk[3][1];
    #pragma unroll
    for (int d0 = 0; d0 < 4; ++d0){
      const u16* vp = Vt + (size_t)(b*DIM + h*DH + d0*16 + lq)*KLn + kvs;
      short8 v0 = *(const short8*)(vp + lg*8);
      short8 v1 = *(const short8*)(vp + 32 + lg*8);
      ctx[d0] = __builtin_amdgcn_mfma_f32_16x16x32_bf16(pa0.s8, v0, ctx[d0], 0,0,0);
      ctx[d0] = __builtin_amdgcn_mfma_f32_16x16x32_bf16(pa1.s8, v1, ctx[d0], 0,0,0);
    }
  }

  // ---- merge the 4 KV-split partials
  __shared__ __align__(16) float ctx_lds[4][64][16];  // [wave][lane][elem]
  __shared__ float ml[4][2][16];                      // [wave][{m,l}][qrow]
  #pragma unroll
  for (int d0 = 0; d0 < 4; ++d0)
    *(f32x4*)&ctx_lds[w][l][d0*4] = ctx[d0];
  if (l < 16){ ml[w][0][l] = m; ml[w][1][l] = lsum; }
  __syncthreads();

  const int col = tid & 63;
  const int r0  = tid >> 6;
  #pragma unroll
  for (int i = 0; i < 4; ++i){
    const int row = i*4 + r0;
    const int srclane = ((row >> 2) << 4) | (col & 15);
    const int idx = (col >> 4)*4 + (row & 3);
    float mg = ml[0][0][row];
    #pragma unroll
    for (int w2 = 1; w2 < 4; ++w2) mg = fmaxf(mg, ml[w2][0][row]);
    float num = 0.f, den = 0.f;
    #pragma unroll
    for (int w2 = 0; w2 < 4; ++w2){
      const float sc = exp2f(ml[w2][0][row] - mg);
      den += ml[w2][1][row] * sc;
      num += ctx_lds[w2][srclane][idx] * sc;
    }
    O[(size_t)(b*QL + q0 + row)*DIM + h*DH + col] = f2b(num / den);
  }
}

// ---------------------------------------------------------------- layernorm
template<int MODE>
__global__ __launch_bounds__(128)
void ln_kernel(const float* __restrict__ in0, const float* __restrict__ in1,
               const float* __restrict__ tkpm,
               const float* __restrict__ g, const float* __restrict__ bvec,
               float* __restrict__ xres, u16* __restrict__ outb)
{
  const int row = blockIdx.x;
  const int t = threadIdx.x;
  float v[4];
  #pragma unroll
  for (int i = 0; i < 4; ++i){
    const int c = t + i*128;
    float x = in0[(size_t)row*DIM + c];
    if (MODE == 0){
      x += in1[(size_t)row*DIM + c];
      xres[(size_t)row*DIM + c] = x;
    }
    v[i] = x;
  }
  float s = v[0]+v[1]+v[2]+v[3];
  #pragma unroll
  for (int off = 1; off < 64; off <<= 1) s += __shfl_xor(s, off);
  __shared__ float red[4];
  if ((t & 63) == 0) red[t >> 6] = s;
  __syncthreads();
  const float mean = (red[0] + red[1]) * (1.f/512.f);
  float q = 0.f;
  #pragma unroll
  for (int i = 0; i < 4; ++i){ const float d = v[i]-mean; q += d*d; }
  #pragma unroll
  for (int off = 1; off < 64; off <<= 1) q += __shfl_xor(q, off);
  if ((t & 63) == 0) red[2 + (t >> 6)] = q;
  __syncthreads();
  const float var = (red[2] + red[3]) * (1.f/512.f);
  const float rs = rsqrtf(var + 1e-5f);
  const float tk = (MODE == 0) ? tkpm[row] : 1.f;
  #pragma unroll
  for (int i = 0; i < 4; ++i){
    const int c = t + i*128;
    const float y = (v[i] - mean) * rs * g[c] + bvec[c];
    outb[(size_t)row*DIM + c] = f2b(y * tk);
  }
}

// ---------------------------------------------------------------- transposes / misc
__global__ __launch_bounds__(256)
void transpose_f2b(const float* __restrict__ in, u16* __restrict__ out, int R, int C)
{
  __shared__ float tile[32][33];
  const int tx = threadIdx.x, ty = threadIdx.y;
  const int r0 = blockIdx.y*32, c0 = blockIdx.x*32;
  #pragma unroll
  for (int i = 0; i < 4; ++i)
    tile[ty + i*8][tx] = in[(size_t)(r0 + ty + i*8)*C + c0 + tx];
  __syncthreads();
  #pragma unroll
  for (int i = 0; i < 4; ++i)
    out[(size_t)(c0 + ty + i*8)*R + r0 + tx] = f2b(tile[tx][ty + i*8]);
}

__global__ __launch_bounds__(256)
void transpose8_f2b(const float* w0, const float* w1, const float* w2, const float* w3,
                    const float* w4, const float* w5, const float* w6, const float* w7,
                    u16* __restrict__ out)
{
  __shared__ float tile[32][33];
  const float* wp[8] = {w0,w1,w2,w3,w4,w5,w6,w7};
  const float* w = wp[blockIdx.z];
  u16* o = out + (size_t)blockIdx.z * 512 * 512;
  const int tx = threadIdx.x, ty = threadIdx.y;
  const int r0 = blockIdx.y*32, c0 = blockIdx.x*32;
  #pragma unroll
  for (int i = 0; i < 4; ++i)
    tile[ty + i*8][tx] = w[(size_t)(r0 + ty + i*8)*512 + c0 + tx];
  __syncthreads();
  #pragma unroll
  for (int i = 0; i < 4; ++i)
    o[(size_t)(c0 + ty + i*8)*512 + r0 + tx] = f2b(tile[tx][ty + i*8]);
}

// V [b][kv][512] -> Vt [b][d][slot(kv)] with the PV K-slot permutation folded in
__global__ __launch_bounds__(256)
void transpose_vperm(const u16* __restrict__ in, u16* __restrict__ out)
{
  __shared__ u16 tile[32][33];
  in  += (size_t)blockIdx.z * KLn * DIM;
  out += (size_t)blockIdx.z * KLn * DIM;
  const int tx = threadIdx.x, ty = threadIdx.y;
  const int r0 = blockIdx.y*32, c0 = blockIdx.x*32;   // r=kv, c=d
  #pragma unroll
  for (int i = 0; i < 4; ++i)
    tile[ty + i*8][tx] = in[(size_t)(r0 + ty + i*8)*DIM + c0 + tx];
  __syncthreads();
  const int kv = r0 + tx;
  const int slot = (kv & ~31) | (((kv>>2)&3)<<3) | (((kv>>4)&1)<<2) | (kv&3);
  #pragma unroll
  for (int i = 0; i < 4; ++i)
    out[(size_t)(c0 + ty + i*8)*KLn + slot] = tile[tx][ty + i*8];
}

__global__ void cvt_f2b(const float* __restrict__ in, u16* __restrict__ out, int n){
  const int i = blockIdx.x*blockDim.x + threadIdx.x;
  if (i < n) out[i] = f2b(in[i]);
}

__global__ void maskbias_k(const int* __restrict__ mkpm, float* __restrict__ bias, int n){
  const int i = blockIdx.x*blockDim.x + threadIdx.x;
  if (i < n) bias[i] = mkpm[i] ? 0.f : -1e30f;
}

__global__ void finalize_k(const float* __restrict__ xres, const float* __restrict__ tkpm,
                           float* __restrict__ out){
  const int i = blockIdx.x*blockDim.x + threadIdx.x;
  out[i] = xres[i] * tkpm[i >> 9];
}

// ---------------------------------------------------------------- launch
extern "C" void kernel_launch(void* const* d_in, const int* in_sizes, int n_in,
                              void* d_out, int out_size, void* d_ws, size_t ws_size,
                              hipStream_t stream)
{
  const float* tgt  = (const float*)d_in[1];
  const float* mem  = (const float*)d_in[2];
  const float* pos  = (const float*)d_in[3];
  const float* tkpm = (const float*)d_in[5];
  const int*   mkpm = (const int*)d_in[6];
  const float* saqw = (const float*)d_in[7];  const float* saqb = (const float*)d_in[8];
  const float* sakw = (const float*)d_in[9];  const float* sakb = (const float*)d_in[10];
  const float* savw = (const float*)d_in[11]; const float* savb = (const float*)d_in[12];
  const float* saow = (const float*)d_in[13]; const float* saob = (const float*)d_in[14];
  const float* caqw = (const float*)d_in[15]; const float* caqb = (const float*)d_in[16];
  const float* cakw = (const float*)d_in[17]; const float* cakb = (const float*)d_in[18];
  const float* cavw = (const float*)d_in[19]; const float* cavb = (const float*)d_in[20];
  const float* caow = (const float*)d_in[21]; const float* caob = (const float*)d_in[22];
  const float* l1w  = (const float*)d_in[23]; const float* l1b  = (const float*)d_in[24];
  const float* l2w  = (const float*)d_in[25]; const float* l2b  = (const float*)d_in[26];
  const float* n1g  = (const float*)d_in[27]; const float* n1b  = (const float*)d_in[28];
  const float* n2g  = (const float*)d_in[29]; const float* n2b  = (const float*)d_in[30];
  const float* n3g  = (const float*)d_in[31]; const float* n3b  = (const float*)d_in[32];

  if (ws_size < 58720256) return;  // 56 MB scratch

  char* ws = (char*)d_ws;
  float* xres = (float*)(ws);                      // 8 MB  f32 residual
  u16* t2n    = (u16*)(ws + (8u<<20));             // 4 MB  LN out / attn out (aliased)
  u16* qb     = (u16*)(ws + (12u<<20));            // 4 MB
  u16* kb     = (u16*)(ws + (16u<<20));            // 4 MB
  u16* vb     = (u16*)(ws + (20u<<20));            // 4 MB  (later reused for FF weightT)
  u16* vt     = (u16*)(ws + (24u<<20));            // 4 MB  permuted V^T
  float* bias = (float*)(ws + (28u<<20));          // 16 KB cross-attn additive mask
  u16* memb   = (u16*)(ws + (32u<<20));            // 4 MB  memory in bf16
  u16* ffh    = (u16*)(ws + (36u<<20));            // 16 MB FF hidden
  u16* wtA    = (u16*)(ws + (52u<<20));            // 4 MB  8x 512x512 attn weightT
  u16* l1wt   = vb;                                // 2 MB  (after cross vperm)
  u16* l2wt   = (u16*)(ws + (22u<<20));            // 2 MB

  float* out = (float*)d_out;
  const int W55 = 512*512;

  maskbias_k<<<dim3(NB*KLn/256), 256, 0, stream>>>(mkpm, bias, NB*KLn);
  cvt_f2b<<<dim3(MROWS*DIM/256), 256, 0, stream>>>(mem, memb, MROWS*DIM);
  ln_kernel<0><<<MROWS, 128, 0, stream>>>(tgt, pos, tkpm, n1g, n1b, xres, t2n);
  transpose8_f2b<<<dim3(16,16,8), dim3(32,8), 0, stream>>>(saqw, sakw, savw, saow,
                                                           caqw, cakw, cavw, caow, wtA);

  // ---- self attention
  gemm_bt<EPI_SCALEQ><<<dim3(4,32), 256, 0, stream>>>(t2n, wtA + 0*W55, saqb, qb, nullptr, 512, 512);
  gemm_bt<EPI_BIAS>  <<<dim3(4,32), 256, 0, stream>>>(t2n, wtA + 1*W55, sakb, kb, nullptr, 512, 512);
  gemm_bt<EPI_BIAS>  <<<dim3(4,32), 256, 0, stream>>>(t2n, wtA + 2*W55, savb, vb, nullptr, 512, 512);
  transpose_vperm<<<dim3(DIM/32, KLn/32, NB), dim3(32,8), 0, stream>>>(vb, vt);
  attn3<true><<<dim3(QL/16, NH, NB), 256, 0, stream>>>(qb, kb, vt, nullptr, t2n);
  gemm_bt<EPI_RES>   <<<dim3(4,32), 256, 0, stream>>>(t2n, wtA + 3*W55, saob, nullptr, xres, 512, 512);

  ln_kernel<1><<<MROWS, 128, 0, stream>>>(xres, nullptr, nullptr, n2g, n2b, nullptr, t2n);

  // ---- cross attention
  gemm_bt<EPI_SCALEQ><<<dim3(4,32), 256, 0, stream>>>(t2n,  wtA + 4*W55, caqb, qb, nullptr, 512, 512);
  gemm_bt<EPI_BIAS>  <<<dim3(4,32), 256, 0, stream>>>(memb, wtA + 5*W55, cakb, kb, nullptr, 512, 512);
  gemm_bt<EPI_BIAS>  <<<dim3(4,32), 256, 0, stream>>>(memb, wtA + 6*W55, cavb, vb, nullptr, 512, 512);
  transpose_vperm<<<dim3(DIM/32, KLn/32, NB), dim3(32,8), 0, stream>>>(vb, vt);
  transpose_f2b<<<dim3(FFD/32, 512/32), dim3(32,8), 0, stream>>>(l1w, l1wt, 512, FFD);
  transpose_f2b<<<dim3(512/32, FFD/32), dim3(32,8), 0, stream>>>(l2w, l2wt, FFD, 512);
  attn3<false><<<dim3(QL/16, NH, NB), 256, 0, stream>>>(qb, kb, vt, bias, t2n);
  gemm_bt<EPI_RES>   <<<dim3(4,32), 256, 0, stream>>>(t2n, wtA + 7*W55, caob, nullptr, xres, 512, 512);

  ln_kernel<1><<<MROWS, 128, 0, stream>>>(xres, nullptr, nullptr, n3g, n3b, nullptr, t2n);

  // ---- feed-forward
  gemm_bt<EPI_RELU><<<dim3(16,32), 256, 0, stream>>>(t2n, l1wt, l1b, ffh, nullptr, 512, FFD);
  gemm_bt<EPI_RES> <<<dim3(4,32),  256, 0, stream>>>(ffh, l2wt, l2b, nullptr, xres, FFD, 512);

  finalize_k<<<dim3(MROWS*DIM/256), 256, 0, stream>>>(xres, tkpm, out);
}

// Round 5
// 356.634 us; speedup vs baseline: 1.5221x; 1.3727x over previous
//
#include <hip/hip_runtime.h>
#include <hip/hip_bf16.h>
#include <stdint.h>

#define QL   2048
#define KLn  2048
#define DIM  512
#define NH   8
#define DH   64
#define NB   2
#define MROWS (NB*QL)   // 4096
#define FFD  2048

typedef unsigned short u16;
typedef unsigned int u32;
typedef __attribute__((ext_vector_type(8))) short short8;
typedef __attribute__((ext_vector_type(4))) float f32x4;

__device__ __forceinline__ u16 f2b(float f){
  union { float f; u32 i; } v; v.f = f;
  u32 r = v.i + 0x7FFFu + ((v.i >> 16) & 1u);
  return (u16)(r >> 16);
}
// pack two fp32 -> bf16x2 word (round-half-up; inputs are softmax probs >= 0)
__device__ __forceinline__ u32 pack2(float a, float b){
  union { float f; u32 i; } va, vb; va.f = a; vb.f = b;
  return ((va.i + 0x8000u) >> 16) | ((vb.i + 0x8000u) & 0xFFFF0000u);
}

typedef __attribute__((address_space(3))) void as3void;
typedef __attribute__((address_space(1))) void as1void;
__device__ __forceinline__ void gload_lds16(const void* g, void* l){
  __builtin_amdgcn_global_load_lds((as1void*)g, (as3void*)l, 16, 0, 0);
}

// ---------------------------------------------------------------- GEMM
#define BM 128
#define BN 128
#define BK 32
enum { EPI_BIAS=0, EPI_SCALEQ=1, EPI_RELU=2, EPI_RES=3, EPI_KSWZ=4 };
// 1/sqrt(64) * log2(e): folds softmax exp->exp2 conversion into Q scale
#define QSCALE 0.1803368801111244f

template<int EPI>
__global__ __launch_bounds__(256, 2)
void gemm_bt(const u16* __restrict__ A, const u16* __restrict__ Bt,
             const float* __restrict__ bias,
             u16* __restrict__ Obf, float* __restrict__ Ores,
             int K, int N)
{
  __shared__ __align__(16) u16 As[BM*BK];
  __shared__ __align__(16) u16 Bs[BN*BK];
  const int t  = threadIdx.x;
  const int l  = t & 63;
  const int lq = l & 15, lg = l >> 4;
  const int w  = t >> 6;
  const int wm = (w >> 1) * 64;
  const int wn = (w & 1) * 64;
  const int m0 = blockIdx.y * BM;
  const int n0 = blockIdx.x * BN;

  const int srow  = t >> 2;        // 0..63
  const int skseg = (t & 3) * 8;   // 0,8,16,24

  const u16* Ag = A  + (size_t)(m0 + srow) * K + skseg;
  const u16* Bg = Bt + (size_t)(n0 + srow) * K + skseg;
  u16* As0 = &As[srow*BK + skseg];
  u16* As1 = &As[(srow+64)*BK + skseg];
  u16* Bs0 = &Bs[srow*BK + skseg];
  u16* Bs1 = &Bs[(srow+64)*BK + skseg];
  const size_t rowhop = (size_t)64 * K;

  f32x4 acc[4][4];
  #pragma unroll
  for (int i=0;i<4;i++)
    #pragma unroll
    for (int j=0;j<4;j++) acc[i][j] = (f32x4){0.f,0.f,0.f,0.f};

  for (int k0 = 0; k0 < K; k0 += BK){
    gload_lds16(Ag + k0,          As0);
    gload_lds16(Ag + k0 + rowhop, As1);
    gload_lds16(Bg + k0,          Bs0);
    gload_lds16(Bg + k0 + rowhop, Bs1);
    __syncthreads();
    short8 af[4], bf[4];
    #pragma unroll
    for (int i=0;i<4;i++) af[i] = *(const short8*)&As[(wm + i*16 + lq)*BK + lg*8];
    #pragma unroll
    for (int j=0;j<4;j++) bf[j] = *(const short8*)&Bs[(wn + j*16 + lq)*BK + lg*8];
    #pragma unroll
    for (int i=0;i<4;i++)
      #pragma unroll
      for (int j=0;j<4;j++)
        acc[i][j] = __builtin_amdgcn_mfma_f32_16x16x32_bf16(af[i], bf[j], acc[i][j], 0,0,0);
    __syncthreads();
  }

  #pragma unroll
  for (int i=0;i<4;i++){
    #pragma unroll
    for (int j=0;j<4;j++){
      #pragma unroll
      for (int rr=0;rr<4;rr++){
        const int row = m0 + wm + i*16 + lg*4 + rr;
        const int col = n0 + wn + j*16 + lq;
        float v = acc[i][j][rr] + bias[col];
        if (EPI == EPI_SCALEQ) v *= QSCALE;
        if (EPI == EPI_RELU)   v = fmaxf(v, 0.f);
        if (EPI == EPI_RES)    Ores[(size_t)row*N + col] += v;
        else if (EPI == EPI_KSWZ){
          // head-major swizzled K: [b][h][kv][dh ^ ((kv&7)<<3)]
          const int bb = row >> 11, kv = row & 2047;
          const int hh = col >> 6,  dh = col & 63;
          Obf[((((size_t)(bb*NH + hh) << 11) + kv) << 6) + (dh ^ ((kv & 7) << 3))] = f2b(v);
        }
        else                   Obf[(size_t)row*N + col] = f2b(v);
      }
    }
  }
}

// ---------------------------------------------------------------- attention v4
// Block = 4 waves x 16 q-rows (QBLK=64) for one (head, batch); KVBLK=64.
// K and V^T tiles staged once per block into double-buffered LDS via
// global_load_lds (T3 2-phase: prefetch next tile, one barrier per tile).
// XOR bank-swizzle (T2) baked into the GLOBAL K/V^T layouts so linear
// global_load_lds produces swizzled LDS; ds_read applies the XOR.
// Swapped QK^T keeps each lane's q-row scores in-register; PV K-slot
// permutation keeps P lane-local; exp2-domain softmax.
template<bool CAUSAL>
__global__ __launch_bounds__(256, 4)
void attn4(const u16* __restrict__ Q, const u16* __restrict__ Kbh,
           const u16* __restrict__ Vth, const float* __restrict__ bias,
           u16* __restrict__ O)
{
  __shared__ __align__(16) u16 Kl[2][64*64];
  __shared__ __align__(16) u16 Vl[2][64*64];
  const int tid = threadIdx.x;
  const int l  = tid & 63;
  const int w  = tid >> 6;
  const int lq = l & 15, lg = l >> 4;
  const int h  = blockIdx.y;
  const int b  = blockIdx.z;
  // causal: flip q-tile order by batch parity so co-resident blocks balance
  const int qtile = CAUSAL ? ((b & 1) ? (31 - (int)blockIdx.x) : (int)blockIdx.x)
                           : (int)blockIdx.x;
  const int q0w = qtile*64 + w*16;

  const u16* kg = Kbh + ((size_t)(b*NH + h) << 17);   // [2048][64]
  const u16* vg = Vth + ((size_t)(b*NH + h) << 17);   // [64][2048]

  short8 aq[2];
  #pragma unroll
  for (int kc = 0; kc < 2; ++kc)
    aq[kc] = *(const short8*)(Q + (size_t)(b*QL + q0w + lq)*DIM + h*DH + kc*32 + lg*8);

  f32x4 ctx[4];
  #pragma unroll
  for (int d = 0; d < 4; ++d) ctx[d] = (f32x4){0.f,0.f,0.f,0.f};
  float m = -INFINITY, lsum = 0.f;

  const int ntiles = CAUSAL ? (qtile + 1) : (KLn >> 6);

  auto stage = [&](int buf, int t){
    const int kvs = t*64;
    #pragma unroll
    for (int i = 0; i < 2; ++i){
      gload_lds16(kg + (size_t)kvs*64 + w*1024 + i*512 + l*8,
                  &Kl[buf][w*1024 + i*512 + l*8]);
      gload_lds16(vg + (size_t)(w*16 + i*8 + (l>>3))*KLn + kvs + (l&7)*8,
                  &Vl[buf][w*1024 + i*512 + l*8]);
    }
  };

  stage(0, 0);
  __syncthreads();
  int cur = 0;

  for (int t = 0; t < ntiles; ++t){
    if (t + 1 < ntiles) stage(cur ^ 1, t + 1);
    const int kvs = t*64;
    // ---- QK^T (A-frag = K rows from LDS, B-frag = Q in regs)
    f32x4 s[4];
    #pragma unroll
    for (int sub = 0; sub < 4; ++sub) s[sub] = (f32x4){0.f,0.f,0.f,0.f};
    #pragma unroll
    for (int sub = 0; sub < 4; ++sub){
      const int r = sub*16 + lq;
      #pragma unroll
      for (int kc = 0; kc < 2; ++kc){
        short8 bk = *(const short8*)&Kl[cur][r*64 + (((kc*4 + lg) ^ (r & 7)) << 3)];
        s[sub] = __builtin_amdgcn_mfma_f32_16x16x32_bf16(bk, aq[kc], s[sub], 0,0,0);
      }
    }
    // lane holds S[kv = kvs+sub*16+lg*4+rr][q = q0w+lq]
    if (CAUSAL){
      if (kvs + 63 > q0w){
        #pragma unroll
        for (int sub = 0; sub < 4; ++sub)
          #pragma unroll
          for (int rr = 0; rr < 4; ++rr)
            if (kvs + sub*16 + lg*4 + rr > q0w + lq) s[sub][rr] = -INFINITY;
      }
    } else {
      #pragma unroll
      for (int sub = 0; sub < 4; ++sub){
        f32x4 bv = *(const f32x4*)(bias + b*KLn + kvs + sub*16 + lg*4);
        s[sub] += bv;
      }
    }
    // ---- online softmax (scores for q=q0w+lq are in-lane)
    float pmax = s[0][0];
    #pragma unroll
    for (int sub = 0; sub < 4; ++sub)
      #pragma unroll
      for (int rr = 0; rr < 4; ++rr) pmax = fmaxf(pmax, s[sub][rr]);
    pmax = fmaxf(pmax, __shfl_xor(pmax, 16));
    pmax = fmaxf(pmax, __shfl_xor(pmax, 32));
    const float mnew = fmaxf(m, pmax);
    const float corr = exp2f(m - mnew);
    float psum = 0.f;
    u32 pk[4][2];
    #pragma unroll
    for (int sub = 0; sub < 4; ++sub){
      float p0 = exp2f(s[sub][0] - mnew);
      float p1 = exp2f(s[sub][1] - mnew);
      float p2 = exp2f(s[sub][2] - mnew);
      float p3 = exp2f(s[sub][3] - mnew);
      psum += (p0 + p1) + (p2 + p3);
      pk[sub][0] = pack2(p0, p1);
      pk[sub][1] = pack2(p2, p3);
    }
    psum += __shfl_xor(psum, 16);
    psum += __shfl_xor(psum, 32);
    lsum = lsum * corr + psum;
    m = mnew;
    float corr4[4];
    #pragma unroll
    for (int rr = 0; rr < 4; ++rr) corr4[rr] = __shfl(corr, lg*4 + rr);
    #pragma unroll
    for (int d = 0; d < 4; ++d)
      #pragma unroll
      for (int rr = 0; rr < 4; ++rr) ctx[d][rr] *= corr4[rr];
    // ---- PV (A-frag = lane-local P regs, B-frag = V^T rows from LDS)
    union { u32 u[4]; short8 s8; } pa0, pa1;
    pa0.u[0] = pk[0][0]; pa0.u[1] = pk[0][1]; pa0.u[2] = pk[1][0]; pa0.u[3] = pk[1][1];
    pa1.u[0] = pk[2][0]; pa1.u[1] = pk[2][1]; pa1.u[2] = pk[3][0]; pa1.u[3] = pk[3][1];
    #pragma unroll
    for (int d0 = 0; d0 < 4; ++d0){
      const int dl = d0*16 + lq;
      short8 v0 = *(const short8*)&Vl[cur][dl*64 + ((lg       ^ (dl & 7)) << 3)];
      short8 v1 = *(const short8*)&Vl[cur][dl*64 + (((4 + lg) ^ (dl & 7)) << 3)];
      ctx[d0] = __builtin_amdgcn_mfma_f32_16x16x32_bf16(pa0.s8, v0, ctx[d0], 0,0,0);
      ctx[d0] = __builtin_amdgcn_mfma_f32_16x16x32_bf16(pa1.s8, v1, ctx[d0], 0,0,0);
    }
    __syncthreads();   // drains vmcnt(0): prefetch landed; buffers safe to swap
    cur ^= 1;
  }

  float inv4[4];
  #pragma unroll
  for (int rr = 0; rr < 4; ++rr) inv4[rr] = 1.f / __shfl(lsum, lg*4 + rr);
  #pragma unroll
  for (int d0 = 0; d0 < 4; ++d0)
    #pragma unroll
    for (int rr = 0; rr < 4; ++rr)
      O[(size_t)(b*QL + q0w + lg*4 + rr)*DIM + h*DH + d0*16 + lq] = f2b(ctx[d0][rr] * inv4[rr]);
}

// ---------------------------------------------------------------- layernorm
template<int MODE>
__global__ __launch_bounds__(128)
void ln_kernel(const float* __restrict__ in0, const float* __restrict__ in1,
               const float* __restrict__ tkpm,
               const float* __restrict__ g, const float* __restrict__ bvec,
               float* __restrict__ xres, u16* __restrict__ outb)
{
  const int row = blockIdx.x;
  const int t = threadIdx.x;
  float v[4];
  #pragma unroll
  for (int i = 0; i < 4; ++i){
    const int c = t + i*128;
    float x = in0[(size_t)row*DIM + c];
    if (MODE == 0){
      x += in1[(size_t)row*DIM + c];
      xres[(size_t)row*DIM + c] = x;
    }
    v[i] = x;
  }
  float s = v[0]+v[1]+v[2]+v[3];
  #pragma unroll
  for (int off = 1; off < 64; off <<= 1) s += __shfl_xor(s, off);
  __shared__ float red[4];
  if ((t & 63) == 0) red[t >> 6] = s;
  __syncthreads();
  const float mean = (red[0] + red[1]) * (1.f/512.f);
  float q = 0.f;
  #pragma unroll
  for (int i = 0; i < 4; ++i){ const float d = v[i]-mean; q += d*d; }
  #pragma unroll
  for (int off = 1; off < 64; off <<= 1) q += __shfl_xor(q, off);
  if ((t & 63) == 0) red[2 + (t >> 6)] = q;
  __syncthreads();
  const float var = (red[2] + red[3]) * (1.f/512.f);
  const float rs = rsqrtf(var + 1e-5f);
  const float tk = (MODE == 0) ? tkpm[row] : 1.f;
  #pragma unroll
  for (int i = 0; i < 4; ++i){
    const int c = t + i*128;
    const float y = (v[i] - mean) * rs * g[c] + bvec[c];
    outb[(size_t)row*DIM + c] = f2b(y * tk);
  }
}

// ---------------------------------------------------------------- transposes / misc
__global__ __launch_bounds__(256)
void transpose_f2b(const float* __restrict__ in, u16* __restrict__ out, int R, int C)
{
  __shared__ float tile[32][33];
  const int tx = threadIdx.x, ty = threadIdx.y;
  const int r0 = blockIdx.y*32, c0 = blockIdx.x*32;
  #pragma unroll
  for (int i = 0; i < 4; ++i)
    tile[ty + i*8][tx] = in[(size_t)(r0 + ty + i*8)*C + c0 + tx];
  __syncthreads();
  #pragma unroll
  for (int i = 0; i < 4; ++i)
    out[(size_t)(c0 + ty + i*8)*R + r0 + tx] = f2b(tile[tx][ty + i*8]);
}

__global__ __launch_bounds__(256)
void transpose8_f2b(const float* w0, const float* w1, const float* w2, const float* w3,
                    const float* w4, const float* w5, const float* w6, const float* w7,
                    u16* __restrict__ out)
{
  __shared__ float tile[32][33];
  const float* wp[8] = {w0,w1,w2,w3,w4,w5,w6,w7};
  const float* w = wp[blockIdx.z];
  u16* o = out + (size_t)blockIdx.z * 512 * 512;
  const int tx = threadIdx.x, ty = threadIdx.y;
  const int r0 = blockIdx.y*32, c0 = blockIdx.x*32;
  #pragma unroll
  for (int i = 0; i < 4; ++i)
    tile[ty + i*8][tx] = w[(size_t)(r0 + ty + i*8)*512 + c0 + tx];
  __syncthreads();
  #pragma unroll
  for (int i = 0; i < 4; ++i)
    o[(size_t)(c0 + ty + i*8)*512 + r0 + tx] = f2b(tile[tx][ty + i*8]);
}

// V [b][kv][512] -> Vth [b][h][dh][kv'] with PV K-slot permutation AND
// bank XOR-swizzle (chunk ^= dh&7) folded into the kv index.
__global__ __launch_bounds__(256)
void transpose_vperm(const u16* __restrict__ in, u16* __restrict__ out)
{
  __shared__ u16 tile[32][33];
  in  += (size_t)blockIdx.z * KLn * DIM;
  out += (size_t)blockIdx.z * NH * DH * KLn;
  const int tx = threadIdx.x, ty = threadIdx.y;
  const int r0 = blockIdx.y*32, c0 = blockIdx.x*32;   // r=kv, c=dcol
  #pragma unroll
  for (int i = 0; i < 4; ++i)
    tile[ty + i*8][tx] = in[(size_t)(r0 + ty + i*8)*DIM + c0 + tx];
  __syncthreads();
  const int kv = r0 + tx;
  const int s  = (kv & ~31) | (((kv>>2)&3)<<3) | (((kv>>4)&1)<<2) | (kv&3);
  #pragma unroll
  for (int i = 0; i < 4; ++i){
    const int dcol = c0 + ty + i*8;
    const int hh = dcol >> 6, dh = dcol & 63;
    const int kvpos = (s & ~63) | (((((s>>3)&7) ^ (dh&7)) << 3)) | (s & 7);
    out[((size_t)(hh*DH + dh))*KLn + kvpos] = tile[tx][ty + i*8];
  }
}

__global__ void cvt_f2b(const float* __restrict__ in, u16* __restrict__ out, int n){
  const int i = blockIdx.x*blockDim.x + threadIdx.x;
  if (i < n) out[i] = f2b(in[i]);
}

__global__ void maskbias_k(const int* __restrict__ mkpm, float* __restrict__ bias, int n){
  const int i = blockIdx.x*blockDim.x + threadIdx.x;
  if (i < n) bias[i] = mkpm[i] ? 0.f : -1e30f;
}

__global__ void finalize_k(const float* __restrict__ xres, const float* __restrict__ tkpm,
                           float* __restrict__ out){
  const int i = blockIdx.x*blockDim.x + threadIdx.x;
  out[i] = xres[i] * tkpm[i >> 9];
}

// ---------------------------------------------------------------- launch
extern "C" void kernel_launch(void* const* d_in, const int* in_sizes, int n_in,
                              void* d_out, int out_size, void* d_ws, size_t ws_size,
                              hipStream_t stream)
{
  const float* tgt  = (const float*)d_in[1];
  const float* mem  = (const float*)d_in[2];
  const float* pos  = (const float*)d_in[3];
  const float* tkpm = (const float*)d_in[5];
  const int*   mkpm = (const int*)d_in[6];
  const float* saqw = (const float*)d_in[7];  const float* saqb = (const float*)d_in[8];
  const float* sakw = (const float*)d_in[9];  const float* sakb = (const float*)d_in[10];
  const float* savw = (const float*)d_in[11]; const float* savb = (const float*)d_in[12];
  const float* saow = (const float*)d_in[13]; const float* saob = (const float*)d_in[14];
  const float* caqw = (const float*)d_in[15]; const float* caqb = (const float*)d_in[16];
  const float* cakw = (const float*)d_in[17]; const float* cakb = (const float*)d_in[18];
  const float* cavw = (const float*)d_in[19]; const float* cavb = (const float*)d_in[20];
  const float* caow = (const float*)d_in[21]; const float* caob = (const float*)d_in[22];
  const float* l1w  = (const float*)d_in[23]; const float* l1b  = (const float*)d_in[24];
  const float* l2w  = (const float*)d_in[25]; const float* l2b  = (const float*)d_in[26];
  const float* n1g  = (const float*)d_in[27]; const float* n1b  = (const float*)d_in[28];
  const float* n2g  = (const float*)d_in[29]; const float* n2b  = (const float*)d_in[30];
  const float* n3g  = (const float*)d_in[31]; const float* n3b  = (const float*)d_in[32];

  if (ws_size < 58720256) return;  // 56 MB scratch

  char* ws = (char*)d_ws;
  float* xres = (float*)(ws);                      // 8 MB  f32 residual
  u16* t2n    = (u16*)(ws + (8u<<20));             // 4 MB  LN out / attn out (aliased)
  u16* qb     = (u16*)(ws + (12u<<20));            // 4 MB
  u16* kb     = (u16*)(ws + (16u<<20));            // 4 MB  head-major swizzled K
  u16* vb     = (u16*)(ws + (20u<<20));            // 4 MB  (later reused for FF weightT)
  u16* vt     = (u16*)(ws + (24u<<20));            // 4 MB  head-major swizzled V^T
  float* bias = (float*)(ws + (28u<<20));          // 16 KB cross-attn additive mask
  u16* memb   = (u16*)(ws + (32u<<20));            // 4 MB  memory in bf16
  u16* ffh    = (u16*)(ws + (36u<<20));            // 16 MB FF hidden
  u16* wtA    = (u16*)(ws + (52u<<20));            // 4 MB  8x 512x512 attn weightT
  u16* l1wt   = vb;                                // 2 MB  (after cross vperm)
  u16* l2wt   = (u16*)(ws + (22u<<20));            // 2 MB

  float* out = (float*)d_out;
  const int W55 = 512*512;

  maskbias_k<<<dim3(NB*KLn/256), 256, 0, stream>>>(mkpm, bias, NB*KLn);
  cvt_f2b<<<dim3(MROWS*DIM/256), 256, 0, stream>>>(mem, memb, MROWS*DIM);
  ln_kernel<0><<<MROWS, 128, 0, stream>>>(tgt, pos, tkpm, n1g, n1b, xres, t2n);
  transpose8_f2b<<<dim3(16,16,8), dim3(32,8), 0, stream>>>(saqw, sakw, savw, saow,
                                                           caqw, cakw, cavw, caow, wtA);

  // ---- self attention
  gemm_bt<EPI_SCALEQ><<<dim3(4,32), 256, 0, stream>>>(t2n, wtA + 0*W55, saqb, qb, nullptr, 512, 512);
  gemm_bt<EPI_KSWZ>  <<<dim3(4,32), 256, 0, stream>>>(t2n, wtA + 1*W55, sakb, kb, nullptr, 512, 512);
  gemm_bt<EPI_BIAS>  <<<dim3(4,32), 256, 0, stream>>>(t2n, wtA + 2*W55, savb, vb, nullptr, 512, 512);
  transpose_vperm<<<dim3(DIM/32, KLn/32, NB), dim3(32,8), 0, stream>>>(vb, vt);
  attn4<true><<<dim3(QL/64, NH, NB), 256, 0, stream>>>(qb, kb, vt, nullptr, t2n);
  gemm_bt<EPI_RES>   <<<dim3(4,32), 256, 0, stream>>>(t2n, wtA + 3*W55, saob, nullptr, xres, 512, 512);

  ln_kernel<1><<<MROWS, 128, 0, stream>>>(xres, nullptr, nullptr, n2g, n2b, nullptr, t2n);

  // ---- cross attention
  gemm_bt<EPI_SCALEQ><<<dim3(4,32), 256, 0, stream>>>(t2n,  wtA + 4*W55, caqb, qb, nullptr, 512, 512);
  gemm_bt<EPI_KSWZ>  <<<dim3(4,32), 256, 0, stream>>>(memb, wtA + 5*W55, cakb, kb, nullptr, 512, 512);
  gemm_bt<EPI_BIAS>  <<<dim3(4,32), 256, 0, stream>>>(memb, wtA + 6*W55, cavb, vb, nullptr, 512, 512);
  transpose_vperm<<<dim3(DIM/32, KLn/32, NB), dim3(32,8), 0, stream>>>(vb, vt);
  transpose_f2b<<<dim3(FFD/32, 512/32), dim3(32,8), 0, stream>>>(l1w, l1wt, 512, FFD);
  transpose_f2b<<<dim3(512/32, FFD/32), dim3(32,8), 0, stream>>>(l2w, l2wt, FFD, 512);
  attn4<false><<<dim3(QL/64, NH, NB), 256, 0, stream>>>(qb, kb, vt, bias, t2n);
  gemm_bt<EPI_RES>   <<<dim3(4,32), 256, 0, stream>>>(t2n, wtA + 7*W55, caob, nullptr, xres, 512, 512);

  ln_kernel<1><<<MROWS, 128, 0, stream>>>(xres, nullptr, nullptr, n3g, n3b, nullptr, t2n);

  // ---- feed-forward
  gemm_bt<EPI_RELU><<<dim3(16,32), 256, 0, stream>>>(t2n, l1wt, l1b, ffh, nullptr, 512, FFD);
  gemm_bt<EPI_RES> <<<dim3(4,32),  256, 0, stream>>>(ffh, l2wt, l2b, nullptr, xres, FFD, 512);

  finalize_k<<<dim3(MROWS*DIM/256), 256, 0, stream>>>(xres, tkpm, out);
}

// Round 6
// 294.994 us; speedup vs baseline: 1.8402x; 1.2090x over previous
//
#include <hip/hip_runtime.h>
#include <hip/hip_bf16.h>
#include <stdint.h>

#define QL   2048
#define KLn  2048
#define DIM  512
#define NH   8
#define DH   64
#define NB   2
#define MROWS (NB*QL)   // 4096
#define FFD  2048

typedef unsigned short u16;
typedef unsigned int u32;
typedef __attribute__((ext_vector_type(8))) short short8;
typedef __attribute__((ext_vector_type(4))) float f32x4;

__device__ __forceinline__ u16 f2b(float f){
  union { float f; u32 i; } v; v.f = f;
  u32 r = v.i + 0x7FFFu + ((v.i >> 16) & 1u);
  return (u16)(r >> 16);
}
// pack two fp32 -> bf16x2 word (round-half-up; inputs are softmax probs >= 0)
__device__ __forceinline__ u32 pack2(float a, float b){
  union { float f; u32 i; } va, vb; va.f = a; vb.f = b;
  return ((va.i + 0x8000u) >> 16) | ((vb.i + 0x8000u) & 0xFFFF0000u);
}

typedef __attribute__((address_space(3))) void as3void;
typedef __attribute__((address_space(1))) void as1void;
__device__ __forceinline__ void gload_lds16(const void* g, void* l){
  __builtin_amdgcn_global_load_lds((as1void*)g, (as3void*)l, 16, 0, 0);
}

// ---------------------------------------------------------------- GEMM
// HN=false: 128x128 tile (4 waves of 64x64). HN=true: 128x64 tile (4 waves of
// 32x64) -> 2x the blocks for N=512 outputs (R5: (4,32)=128 blocks left half
// the 256 CUs idle).
#define BK 32
enum { EPI_BIAS=0, EPI_SCALEQ=1, EPI_RELU=2, EPI_RES=3, EPI_KSWZ=4, EPI_FIN=5 };
// 1/sqrt(64) * log2(e): folds softmax exp->exp2 conversion into Q scale
#define QSCALE 0.1803368801111244f

template<int EPI, bool HN>
__global__ __launch_bounds__(256, 2)
void gemm_bt(const u16* __restrict__ A, const u16* __restrict__ Bt,
             const float* __restrict__ bias,
             u16* __restrict__ Obf, float* __restrict__ Ores,
             const float* __restrict__ tk, float* __restrict__ fout,
             int K, int N)
{
  constexpr int BNv = HN ? 64 : 128;
  constexpr int MI  = HN ? 2 : 4;
  __shared__ __align__(16) u16 As[128*BK];
  __shared__ __align__(16) u16 Bs[BNv*BK];
  const int t  = threadIdx.x;
  const int l  = t & 63;
  const int lq = l & 15, lg = l >> 4;
  const int w  = t >> 6;
  const int wm = HN ? w*32 : (w >> 1)*64;
  const int wn = HN ? 0    : (w & 1)*64;
  const int m0 = blockIdx.y * 128;
  const int n0 = blockIdx.x * BNv;

  const int srow  = t >> 2;        // 0..63
  const int skseg = (t & 3) * 8;   // 0,8,16,24

  const u16* Ag = A  + (size_t)(m0 + srow) * K + skseg;
  const u16* Bg = Bt + (size_t)(n0 + srow) * K + skseg;
  u16* As0 = &As[srow*BK + skseg];
  u16* As1 = &As[(srow+64)*BK + skseg];
  u16* Bs0 = &Bs[srow*BK + skseg];
  u16* Bs1 = HN ? nullptr : &Bs[(srow+64)*BK + skseg];
  const size_t rowhop = (size_t)64 * K;

  f32x4 acc[MI][4];
  #pragma unroll
  for (int i=0;i<MI;i++)
    #pragma unroll
    for (int j=0;j<4;j++) acc[i][j] = (f32x4){0.f,0.f,0.f,0.f};

  for (int k0 = 0; k0 < K; k0 += BK){
    gload_lds16(Ag + k0,          As0);
    gload_lds16(Ag + k0 + rowhop, As1);
    gload_lds16(Bg + k0,          Bs0);
    if (!HN) gload_lds16(Bg + k0 + rowhop, Bs1);
    __syncthreads();
    short8 af[MI], bf[4];
    #pragma unroll
    for (int i=0;i<MI;i++) af[i] = *(const short8*)&As[(wm + i*16 + lq)*BK + lg*8];
    #pragma unroll
    for (int j=0;j<4;j++) bf[j] = *(const short8*)&Bs[(wn + j*16 + lq)*BK + lg*8];
    #pragma unroll
    for (int i=0;i<MI;i++)
      #pragma unroll
      for (int j=0;j<4;j++)
        acc[i][j] = __builtin_amdgcn_mfma_f32_16x16x32_bf16(af[i], bf[j], acc[i][j], 0,0,0);
    __syncthreads();
  }

  #pragma unroll
  for (int i=0;i<MI;i++){
    #pragma unroll
    for (int j=0;j<4;j++){
      #pragma unroll
      for (int rr=0;rr<4;rr++){
        const int row = m0 + wm + i*16 + lg*4 + rr;
        const int col = n0 + wn + j*16 + lq;
        float v = acc[i][j][rr] + bias[col];
        if (EPI == EPI_SCALEQ) v *= QSCALE;
        if (EPI == EPI_RELU)   v = fmaxf(v, 0.f);
        if (EPI == EPI_RES)    Ores[(size_t)row*N + col] += v;
        else if (EPI == EPI_FIN){
          const size_t idx = (size_t)row*N + col;
          fout[idx] = (Ores[idx] + v) * tk[row];
        }
        else if (EPI == EPI_KSWZ){
          // head-major swizzled K: [b][h][kv][dh ^ ((kv&7)<<3)]
          const int bb = row >> 11, kv = row & 2047;
          const int hh = col >> 6,  dh = col & 63;
          Obf[((((size_t)(bb*NH + hh) << 11) + kv) << 6) + (dh ^ ((kv & 7) << 3))] = f2b(v);
        }
        else                   Obf[(size_t)row*N + col] = f2b(v);
      }
    }
  }
}

// ---------------------------------------------------------------- attention v5
// attn4 structure (4 waves x 16 q-rows, KVBLK=64, dbuf LDS via global_load_lds,
// XOR swizzle baked into global K/V^T, swapped QK^T, lane-local P) plus:
//  - T13 defer-max: __all(pmax <= m+8) skips the cross-lane max reduce,
//    corr broadcast and ctx rescale in steady state (scores span ~1 here).
//  - in-lane lsum: per-lane partial sum, reduced across lanes ONCE after the
//    loop -> per-tile psum shfl chain eliminated.
//  - T5 s_setprio around MFMA clusters.
template<bool CAUSAL>
__global__ __launch_bounds__(256, 4)
void attn5(const u16* __restrict__ Q, const u16* __restrict__ Kbh,
           const u16* __restrict__ Vth, const float* __restrict__ bias,
           u16* __restrict__ O)
{
  __shared__ __align__(16) u16 Kl[2][64*64];
  __shared__ __align__(16) u16 Vl[2][64*64];
  const int tid = threadIdx.x;
  const int l  = tid & 63;
  const int w  = tid >> 6;
  const int lq = l & 15, lg = l >> 4;
  const int h  = blockIdx.y;
  const int b  = blockIdx.z;
  const int qtile = CAUSAL ? ((b & 1) ? (31 - (int)blockIdx.x) : (int)blockIdx.x)
                           : (int)blockIdx.x;
  const int q0w = qtile*64 + w*16;

  const u16* kg = Kbh + ((size_t)(b*NH + h) << 17);   // [2048][64]
  const u16* vg = Vth + ((size_t)(b*NH + h) << 17);   // [64][2048]

  short8 aq[2];
  #pragma unroll
  for (int kc = 0; kc < 2; ++kc)
    aq[kc] = *(const short8*)(Q + (size_t)(b*QL + q0w + lq)*DIM + h*DH + kc*32 + lg*8);

  f32x4 ctx[4];
  #pragma unroll
  for (int d = 0; d < 4; ++d) ctx[d] = (f32x4){0.f,0.f,0.f,0.f};
  float m = -INFINITY, lsum = 0.f;   // lsum: per-LANE partial

  const int ntiles = CAUSAL ? (qtile + 1) : (KLn >> 6);

  auto stage = [&](int buf, int t){
    const int kvs = t*64;
    #pragma unroll
    for (int i = 0; i < 2; ++i){
      gload_lds16(kg + (size_t)kvs*64 + w*1024 + i*512 + l*8,
                  &Kl[buf][w*1024 + i*512 + l*8]);
      gload_lds16(vg + (size_t)(w*16 + i*8 + (l>>3))*KLn + kvs + (l&7)*8,
                  &Vl[buf][w*1024 + i*512 + l*8]);
    }
  };

  stage(0, 0);
  __syncthreads();
  int cur = 0;

  for (int t = 0; t < ntiles; ++t){
    if (t + 1 < ntiles) stage(cur ^ 1, t + 1);
    const int kvs = t*64;
    // ---- QK^T (A-frag = K rows from LDS, B-frag = Q in regs)
    f32x4 s[4];
    #pragma unroll
    for (int sub = 0; sub < 4; ++sub) s[sub] = (f32x4){0.f,0.f,0.f,0.f};
    __builtin_amdgcn_s_setprio(1);
    #pragma unroll
    for (int sub = 0; sub < 4; ++sub){
      const int r = sub*16 + lq;
      #pragma unroll
      for (int kc = 0; kc < 2; ++kc){
        short8 bk = *(const short8*)&Kl[cur][r*64 + (((kc*4 + lg) ^ (r & 7)) << 3)];
        s[sub] = __builtin_amdgcn_mfma_f32_16x16x32_bf16(bk, aq[kc], s[sub], 0,0,0);
      }
    }
    __builtin_amdgcn_s_setprio(0);
    // lane holds S[kv = kvs+sub*16+lg*4+rr][q = q0w+lq]
    if (CAUSAL){
      if (kvs + 63 > q0w){
        #pragma unroll
        for (int sub = 0; sub < 4; ++sub)
          #pragma unroll
          for (int rr = 0; rr < 4; ++rr)
            if (kvs + sub*16 + lg*4 + rr > q0w + lq) s[sub][rr] = -INFINITY;
      }
    } else {
      #pragma unroll
      for (int sub = 0; sub < 4; ++sub){
        f32x4 bv = *(const f32x4*)(bias + b*KLn + kvs + sub*16 + lg*4);
        s[sub] += bv;
      }
    }
    // ---- online softmax, defer-max
    float mx[4];
    #pragma unroll
    for (int sub = 0; sub < 4; ++sub)
      mx[sub] = fmaxf(fmaxf(s[sub][0], s[sub][1]), fmaxf(s[sub][2], s[sub][3]));
    float pmax = fmaxf(fmaxf(mx[0], mx[1]), fmaxf(mx[2], mx[3]));
    if (!__all(pmax <= m + 8.0f)){
      pmax = fmaxf(pmax, __shfl_xor(pmax, 16));
      pmax = fmaxf(pmax, __shfl_xor(pmax, 32));
      const float mnew = fmaxf(m, pmax);
      const float corr = exp2f(m - mnew);
      lsum *= corr;
      float corr4[4];
      #pragma unroll
      for (int rr = 0; rr < 4; ++rr) corr4[rr] = __shfl(corr, lg*4 + rr);
      #pragma unroll
      for (int d = 0; d < 4; ++d)
        #pragma unroll
        for (int rr = 0; rr < 4; ++rr) ctx[d][rr] *= corr4[rr];
      m = mnew;
    }
    float psum = 0.f;
    u32 pk[4][2];
    #pragma unroll
    for (int sub = 0; sub < 4; ++sub){
      float p0 = exp2f(s[sub][0] - m);
      float p1 = exp2f(s[sub][1] - m);
      float p2 = exp2f(s[sub][2] - m);
      float p3 = exp2f(s[sub][3] - m);
      psum += (p0 + p1) + (p2 + p3);
      pk[sub][0] = pack2(p0, p1);
      pk[sub][1] = pack2(p2, p3);
    }
    lsum += psum;
    // ---- PV (A-frag = lane-local P regs, B-frag = V^T rows from LDS)
    union { u32 u[4]; short8 s8; } pa0, pa1;
    pa0.u[0] = pk[0][0]; pa0.u[1] = pk[0][1]; pa0.u[2] = pk[1][0]; pa0.u[3] = pk[1][1];
    pa1.u[0] = pk[2][0]; pa1.u[1] = pk[2][1]; pa1.u[2] = pk[3][0]; pa1.u[3] = pk[3][1];
    __builtin_amdgcn_s_setprio(1);
    #pragma unroll
    for (int d0 = 0; d0 < 4; ++d0){
      const int dl = d0*16 + lq;
      short8 v0 = *(const short8*)&Vl[cur][dl*64 + ((lg       ^ (dl & 7)) << 3)];
      short8 v1 = *(const short8*)&Vl[cur][dl*64 + (((4 + lg) ^ (dl & 7)) << 3)];
      ctx[d0] = __builtin_amdgcn_mfma_f32_16x16x32_bf16(pa0.s8, v0, ctx[d0], 0,0,0);
      ctx[d0] = __builtin_amdgcn_mfma_f32_16x16x32_bf16(pa1.s8, v1, ctx[d0], 0,0,0);
    }
    __builtin_amdgcn_s_setprio(0);
    __syncthreads();   // drains vmcnt(0): prefetch landed; buffers safe to swap
    cur ^= 1;
  }

  // reduce the per-lane lsum partials across the row's 4 lanes (once)
  lsum += __shfl_xor(lsum, 16);
  lsum += __shfl_xor(lsum, 32);
  float inv4[4];
  #pragma unroll
  for (int rr = 0; rr < 4; ++rr) inv4[rr] = 1.f / __shfl(lsum, lg*4 + rr);
  #pragma unroll
  for (int d0 = 0; d0 < 4; ++d0)
    #pragma unroll
    for (int rr = 0; rr < 4; ++rr)
      O[(size_t)(b*QL + q0w + lg*4 + rr)*DIM + h*DH + d0*16 + lq] = f2b(ctx[d0][rr] * inv4[rr]);
}

// ---------------------------------------------------------------- layernorm
template<int MODE>
__global__ __launch_bounds__(128)
void ln_kernel(const float* __restrict__ in0, const float* __restrict__ in1,
               const float* __restrict__ tkpm,
               const float* __restrict__ g, const float* __restrict__ bvec,
               float* __restrict__ xres, u16* __restrict__ outb)
{
  const int row = blockIdx.x;
  const int t = threadIdx.x;
  float v[4];
  #pragma unroll
  for (int i = 0; i < 4; ++i){
    const int c = t + i*128;
    float x = in0[(size_t)row*DIM + c];
    if (MODE == 0){
      x += in1[(size_t)row*DIM + c];
      xres[(size_t)row*DIM + c] = x;
    }
    v[i] = x;
  }
  float s = v[0]+v[1]+v[2]+v[3];
  #pragma unroll
  for (int off = 1; off < 64; off <<= 1) s += __shfl_xor(s, off);
  __shared__ float red[4];
  if ((t & 63) == 0) red[t >> 6] = s;
  __syncthreads();
  const float mean = (red[0] + red[1]) * (1.f/512.f);
  float q = 0.f;
  #pragma unroll
  for (int i = 0; i < 4; ++i){ const float d = v[i]-mean; q += d*d; }
  #pragma unroll
  for (int off = 1; off < 64; off <<= 1) q += __shfl_xor(q, off);
  if ((t & 63) == 0) red[2 + (t >> 6)] = q;
  __syncthreads();
  const float var = (red[2] + red[3]) * (1.f/512.f);
  const float rs = rsqrtf(var + 1e-5f);
  const float tk = (MODE == 0) ? tkpm[row] : 1.f;
  #pragma unroll
  for (int i = 0; i < 4; ++i){
    const int c = t + i*128;
    const float y = (v[i] - mean) * rs * g[c] + bvec[c];
    outb[(size_t)row*DIM + c] = f2b(y * tk);
  }
}

// ---------------------------------------------------------------- transposes / misc
__global__ __launch_bounds__(256)
void transpose_f2b(const float* __restrict__ in, u16* __restrict__ out, int R, int C)
{
  __shared__ float tile[32][33];
  const int tx = threadIdx.x, ty = threadIdx.y;
  const int r0 = blockIdx.y*32, c0 = blockIdx.x*32;
  #pragma unroll
  for (int i = 0; i < 4; ++i)
    tile[ty + i*8][tx] = in[(size_t)(r0 + ty + i*8)*C + c0 + tx];
  __syncthreads();
  #pragma unroll
  for (int i = 0; i < 4; ++i)
    out[(size_t)(c0 + ty + i*8)*R + r0 + tx] = f2b(tile[tx][ty + i*8]);
}

__global__ __launch_bounds__(256)
void transpose8_f2b(const float* w0, const float* w1, const float* w2, const float* w3,
                    const float* w4, const float* w5, const float* w6, const float* w7,
                    u16* __restrict__ out)
{
  __shared__ float tile[32][33];
  const float* wp[8] = {w0,w1,w2,w3,w4,w5,w6,w7};
  const float* w = wp[blockIdx.z];
  u16* o = out + (size_t)blockIdx.z * 512 * 512;
  const int tx = threadIdx.x, ty = threadIdx.y;
  const int r0 = blockIdx.y*32, c0 = blockIdx.x*32;
  #pragma unroll
  for (int i = 0; i < 4; ++i)
    tile[ty + i*8][tx] = w[(size_t)(r0 + ty + i*8)*512 + c0 + tx];
  __syncthreads();
  #pragma unroll
  for (int i = 0; i < 4; ++i)
    o[(size_t)(c0 + ty + i*8)*512 + r0 + tx] = f2b(tile[tx][ty + i*8]);
}

// V [b][kv][512] -> Vth [b][h][dh][kv'] with PV K-slot permutation AND
// bank XOR-swizzle (chunk ^= dh&7) folded into the kv index.
__global__ __launch_bounds__(256)
void transpose_vperm(const u16* __restrict__ in, u16* __restrict__ out)
{
  __shared__ u16 tile[32][33];
  in  += (size_t)blockIdx.z * KLn * DIM;
  out += (size_t)blockIdx.z * NH * DH * KLn;
  const int tx = threadIdx.x, ty = threadIdx.y;
  const int r0 = blockIdx.y*32, c0 = blockIdx.x*32;   // r=kv, c=dcol
  #pragma unroll
  for (int i = 0; i < 4; ++i)
    tile[ty + i*8][tx] = in[(size_t)(r0 + ty + i*8)*DIM + c0 + tx];
  __syncthreads();
  const int kv = r0 + tx;
  const int s  = (kv & ~31) | (((kv>>2)&3)<<3) | (((kv>>4)&1)<<2) | (kv&3);
  #pragma unroll
  for (int i = 0; i < 4; ++i){
    const int dcol = c0 + ty + i*8;
    const int hh = dcol >> 6, dh = dcol & 63;
    const int kvpos = (s & ~63) | (((((s>>3)&7) ^ (dh&7)) << 3)) | (s & 7);
    out[((size_t)(hh*DH + dh))*KLn + kvpos] = tile[tx][ty + i*8];
  }
}

__global__ void cvt_f2b(const float* __restrict__ in, u16* __restrict__ out, int n){
  const int i = blockIdx.x*blockDim.x + threadIdx.x;
  if (i < n) out[i] = f2b(in[i]);
}

__global__ void maskbias_k(const int* __restrict__ mkpm, float* __restrict__ bias, int n){
  const int i = blockIdx.x*blockDim.x + threadIdx.x;
  if (i < n) bias[i] = mkpm[i] ? 0.f : -1e30f;
}

// ---------------------------------------------------------------- launch
extern "C" void kernel_launch(void* const* d_in, const int* in_sizes, int n_in,
                              void* d_out, int out_size, void* d_ws, size_t ws_size,
                              hipStream_t stream)
{
  const float* tgt  = (const float*)d_in[1];
  const float* mem  = (const float*)d_in[2];
  const float* pos  = (const float*)d_in[3];
  const float* tkpm = (const float*)d_in[5];
  const int*   mkpm = (const int*)d_in[6];
  const float* saqw = (const float*)d_in[7];  const float* saqb = (const float*)d_in[8];
  const float* sakw = (const float*)d_in[9];  const float* sakb = (const float*)d_in[10];
  const float* savw = (const float*)d_in[11]; const float* savb = (const float*)d_in[12];
  const float* saow = (const float*)d_in[13]; const float* saob = (const float*)d_in[14];
  const float* caqw = (const float*)d_in[15]; const float* caqb = (const float*)d_in[16];
  const float* cakw = (const float*)d_in[17]; const float* cakb = (const float*)d_in[18];
  const float* cavw = (const float*)d_in[19]; const float* cavb = (const float*)d_in[20];
  const float* caow = (const float*)d_in[21]; const float* caob = (const float*)d_in[22];
  const float* l1w  = (const float*)d_in[23]; const float* l1b  = (const float*)d_in[24];
  const float* l2w  = (const float*)d_in[25]; const float* l2b  = (const float*)d_in[26];
  const float* n1g  = (const float*)d_in[27]; const float* n1b  = (const float*)d_in[28];
  const float* n2g  = (const float*)d_in[29]; const float* n2b  = (const float*)d_in[30];
  const float* n3g  = (const float*)d_in[31]; const float* n3b  = (const float*)d_in[32];

  if (ws_size < 58720256) return;  // 56 MB scratch

  char* ws = (char*)d_ws;
  float* xres = (float*)(ws);                      // 8 MB  f32 residual
  u16* t2n    = (u16*)(ws + (8u<<20));             // 4 MB  LN out / attn out (aliased)
  u16* qb     = (u16*)(ws + (12u<<20));            // 4 MB
  u16* kb     = (u16*)(ws + (16u<<20));            // 4 MB  head-major swizzled K
  u16* vb     = (u16*)(ws + (20u<<20));            // 4 MB  (later reused for FF weightT)
  u16* vt     = (u16*)(ws + (24u<<20));            // 4 MB  head-major swizzled V^T
  float* bias = (float*)(ws + (28u<<20));          // 16 KB cross-attn additive mask
  u16* memb   = (u16*)(ws + (32u<<20));            // 4 MB  memory in bf16
  u16* ffh    = (u16*)(ws + (36u<<20));            // 16 MB FF hidden
  u16* wtA    = (u16*)(ws + (52u<<20));            // 4 MB  8x 512x512 attn weightT
  u16* l1wt   = vb;                                // 2 MB  (after cross vperm)
  u16* l2wt   = (u16*)(ws + (22u<<20));            // 2 MB

  float* out = (float*)d_out;
  const int W55 = 512*512;

  maskbias_k<<<dim3(NB*KLn/256), 256, 0, stream>>>(mkpm, bias, NB*KLn);
  cvt_f2b<<<dim3(MROWS*DIM/256), 256, 0, stream>>>(mem, memb, MROWS*DIM);
  ln_kernel<0><<<MROWS, 128, 0, stream>>>(tgt, pos, tkpm, n1g, n1b, xres, t2n);
  transpose8_f2b<<<dim3(16,16,8), dim3(32,8), 0, stream>>>(saqw, sakw, savw, saow,
                                                           caqw, cakw, cavw, caow, wtA);

  #define G64(EP)  gemm_bt<EP,true><<<dim3(8,32), 256, 0, stream>>>
  #define G128(EP) gemm_bt<EP,false><<<dim3(16,32), 256, 0, stream>>>

  // ---- self attention
  G64(EPI_SCALEQ)(t2n, wtA + 0*W55, saqb, qb, nullptr, nullptr, nullptr, 512, 512);
  G64(EPI_KSWZ)  (t2n, wtA + 1*W55, sakb, kb, nullptr, nullptr, nullptr, 512, 512);
  G64(EPI_BIAS)  (t2n, wtA + 2*W55, savb, vb, nullptr, nullptr, nullptr, 512, 512);
  transpose_vperm<<<dim3(DIM/32, KLn/32, NB), dim3(32,8), 0, stream>>>(vb, vt);
  attn5<true><<<dim3(QL/64, NH, NB), 256, 0, stream>>>(qb, kb, vt, nullptr, t2n);
  G64(EPI_RES)   (t2n, wtA + 3*W55, saob, nullptr, xres, nullptr, nullptr, 512, 512);

  ln_kernel<1><<<MROWS, 128, 0, stream>>>(xres, nullptr, nullptr, n2g, n2b, nullptr, t2n);

  // ---- cross attention
  G64(EPI_SCALEQ)(t2n,  wtA + 4*W55, caqb, qb, nullptr, nullptr, nullptr, 512, 512);
  G64(EPI_KSWZ)  (memb, wtA + 5*W55, cakb, kb, nullptr, nullptr, nullptr, 512, 512);
  G64(EPI_BIAS)  (memb, wtA + 6*W55, cavb, vb, nullptr, nullptr, nullptr, 512, 512);
  transpose_vperm<<<dim3(DIM/32, KLn/32, NB), dim3(32,8), 0, stream>>>(vb, vt);
  transpose_f2b<<<dim3(FFD/32, 512/32), dim3(32,8), 0, stream>>>(l1w, l1wt, 512, FFD);
  transpose_f2b<<<dim3(512/32, FFD/32), dim3(32,8), 0, stream>>>(l2w, l2wt, FFD, 512);
  attn5<false><<<dim3(QL/64, NH, NB), 256, 0, stream>>>(qb, kb, vt, bias, t2n);
  G64(EPI_RES)   (t2n, wtA + 7*W55, caob, nullptr, xres, nullptr, nullptr, 512, 512);

  ln_kernel<1><<<MROWS, 128, 0, stream>>>(xres, nullptr, nullptr, n3g, n3b, nullptr, t2n);

  // ---- feed-forward (FF2 epilogue fuses residual add + tkpm scale + f32 out)
  G128(EPI_RELU)(t2n, l1wt, l1b, ffh, nullptr, nullptr, nullptr, 512, FFD);
  G64(EPI_FIN)  (ffh, l2wt, l2b, nullptr, xres, tkpm, out, FFD, 512);

  #undef G64
  #undef G128
}

// Round 7
// 280.986 us; speedup vs baseline: 1.9319x; 1.0499x over previous
//
#include <hip/hip_runtime.h>
#include <hip/hip_bf16.h>
#include <stdint.h>

#define QL   2048
#define KLn  2048
#define DIM  512
#define NH   8
#define DH   64
#define NB   2
#define MROWS (NB*QL)   // 4096
#define FFD  2048

typedef unsigned short u16;
typedef unsigned int u32;
typedef __attribute__((ext_vector_type(8))) short short8;
typedef __attribute__((ext_vector_type(4))) float f32x4;

__device__ __forceinline__ u16 f2b(float f){
  union { float f; u32 i; } v; v.f = f;
  u32 r = v.i + 0x7FFFu + ((v.i >> 16) & 1u);
  return (u16)(r >> 16);
}
// pack two fp32 -> bf16x2 word (round-half-up; inputs are softmax probs >= 0)
__device__ __forceinline__ u32 pack2(float a, float b){
  union { float f; u32 i; } va, vb; va.f = a; vb.f = b;
  return ((va.i + 0x8000u) >> 16) | ((vb.i + 0x8000u) & 0xFFFF0000u);
}

typedef __attribute__((address_space(3))) void as3void;
typedef __attribute__((address_space(1))) void as1void;
__device__ __forceinline__ void gload_lds16(const void* g, void* l){
  __builtin_amdgcn_global_load_lds((as1void*)g, (as3void*)l, 16, 0, 0);
}

// ---------------------------------------------------------------- GEMM
// HN=false: 128x128 tile (4 waves of 64x64). HN=true: 128x64 tile (4 waves of
// 32x64) -> 2x the blocks for N=512 outputs.
#define BK 32
enum { EPI_BIAS=0, EPI_SCALEQ=1, EPI_RELU=2, EPI_RES=3, EPI_KSWZ=4, EPI_FIN=5 };
// 1/sqrt(64) * log2(e): folds softmax exp->exp2 conversion into Q scale
#define QSCALE 0.1803368801111244f

template<int EPI, bool HN>
__global__ __launch_bounds__(256, 2)
void gemm_bt(const u16* __restrict__ A, const u16* __restrict__ Bt,
             const float* __restrict__ bias,
             u16* __restrict__ Obf, float* __restrict__ Ores,
             const float* __restrict__ tk, float* __restrict__ fout,
             int K, int N)
{
  constexpr int BNv = HN ? 64 : 128;
  constexpr int MI  = HN ? 2 : 4;
  __shared__ __align__(16) u16 As[128*BK];
  __shared__ __align__(16) u16 Bs[BNv*BK];
  const int t  = threadIdx.x;
  const int l  = t & 63;
  const int lq = l & 15, lg = l >> 4;
  const int w  = t >> 6;
  const int wm = HN ? w*32 : (w >> 1)*64;
  const int wn = HN ? 0    : (w & 1)*64;
  const int m0 = blockIdx.y * 128;
  const int n0 = blockIdx.x * BNv;

  const int srow  = t >> 2;        // 0..63
  const int skseg = (t & 3) * 8;   // 0,8,16,24

  const u16* Ag = A  + (size_t)(m0 + srow) * K + skseg;
  const u16* Bg = Bt + (size_t)(n0 + srow) * K + skseg;
  u16* As0 = &As[srow*BK + skseg];
  u16* As1 = &As[(srow+64)*BK + skseg];
  u16* Bs0 = &Bs[srow*BK + skseg];
  u16* Bs1 = HN ? nullptr : &Bs[(srow+64)*BK + skseg];
  const size_t rowhop = (size_t)64 * K;

  f32x4 acc[MI][4];
  #pragma unroll
  for (int i=0;i<MI;i++)
    #pragma unroll
    for (int j=0;j<4;j++) acc[i][j] = (f32x4){0.f,0.f,0.f,0.f};

  for (int k0 = 0; k0 < K; k0 += BK){
    gload_lds16(Ag + k0,          As0);
    gload_lds16(Ag + k0 + rowhop, As1);
    gload_lds16(Bg + k0,          Bs0);
    if (!HN) gload_lds16(Bg + k0 + rowhop, Bs1);
    __syncthreads();
    short8 af[MI], bf[4];
    #pragma unroll
    for (int i=0;i<MI;i++) af[i] = *(const short8*)&As[(wm + i*16 + lq)*BK + lg*8];
    #pragma unroll
    for (int j=0;j<4;j++) bf[j] = *(const short8*)&Bs[(wn + j*16 + lq)*BK + lg*8];
    #pragma unroll
    for (int i=0;i<MI;i++)
      #pragma unroll
      for (int j=0;j<4;j++)
        acc[i][j] = __builtin_amdgcn_mfma_f32_16x16x32_bf16(af[i], bf[j], acc[i][j], 0,0,0);
    __syncthreads();
  }

  #pragma unroll
  for (int i=0;i<MI;i++){
    #pragma unroll
    for (int j=0;j<4;j++){
      #pragma unroll
      for (int rr=0;rr<4;rr++){
        const int row = m0 + wm + i*16 + lg*4 + rr;
        const int col = n0 + wn + j*16 + lq;
        float v = acc[i][j][rr] + bias[col];
        if (EPI == EPI_SCALEQ) v *= QSCALE;
        if (EPI == EPI_RELU)   v = fmaxf(v, 0.f);
        if (EPI == EPI_RES)    Ores[(size_t)row*N + col] += v;
        else if (EPI == EPI_FIN){
          const size_t idx = (size_t)row*N + col;
          fout[idx] = (Ores[idx] + v) * tk[row];
        }
        else if (EPI == EPI_KSWZ){
          // head-major swizzled K: [b][h][kv][dh ^ ((kv&7)<<3)]
          const int bb = row >> 11, kv = row & 2047;
          const int hh = col >> 6,  dh = col & 63;
          Obf[((((size_t)(bb*NH + hh) << 11) + kv) << 6) + (dh ^ ((kv & 7) << 3))] = f2b(v);
        }
        else                   Obf[(size_t)row*N + col] = f2b(v);
      }
    }
  }
}

// ---------------------------------------------------------------- attention v6
// R6 showed attn at its TLP ceiling: 512 blocks = 2 waves/SIMD (occ 19%),
// VALU 42% / MFMA 11%. Wave count is fixed by q-split (2048 waves); the only
// remaining axis is KV. v6: cross-block KV-split x2 (flash-decoding) -- block
// (qtile, h, b, half) processes tiles t%2==half with private online (m,l,ctx),
// writes f32 partials + (m,l); a merge kernel combines the two halves.
// Interleaved halves keep causal work balanced. Everything else = v5
// (dbuf LDS via global_load_lds, baked XOR swizzle, swapped QK^T, lane-local
// P, defer-max, T5 setprio). lsum is a f32x4 in-lane accumulator (4 adds/tile).
template<bool CAUSAL>
__global__ __launch_bounds__(256, 4)
void attn6(const u16* __restrict__ Q, const u16* __restrict__ Kbh,
           const u16* __restrict__ Vth, const float* __restrict__ bias,
           float* __restrict__ ctxp, float2* __restrict__ mlb)
{
  __shared__ __align__(16) u16 Kl[2][64*64];
  __shared__ __align__(16) u16 Vl[2][64*64];
  const int tid = threadIdx.x;
  const int l  = tid & 63;
  const int w  = tid >> 6;
  const int lq = l & 15, lg = l >> 4;
  const int h    = blockIdx.y;
  const int b    = blockIdx.z >> 1;
  const int half = blockIdx.z & 1;
  const int qtile = CAUSAL ? ((b & 1) ? (31 - (int)blockIdx.x) : (int)blockIdx.x)
                           : (int)blockIdx.x;
  const int q0w = qtile*64 + w*16;

  const u16* kg = Kbh + ((size_t)(b*NH + h) << 17);   // [2048][64]
  const u16* vg = Vth + ((size_t)(b*NH + h) << 17);   // [64][2048]

  short8 aq[2];
  #pragma unroll
  for (int kc = 0; kc < 2; ++kc)
    aq[kc] = *(const short8*)(Q + (size_t)(b*QL + q0w + lq)*DIM + h*DH + kc*32 + lg*8);

  f32x4 ctx[4];
  #pragma unroll
  for (int d = 0; d < 4; ++d) ctx[d] = (f32x4){0.f,0.f,0.f,0.f};
  f32x4 lsum4 = (f32x4){0.f,0.f,0.f,0.f};
  float m = -INFINITY;

  const int ntiles = CAUSAL ? (qtile + 1) : (KLn >> 6);

  auto stage = [&](int buf, int t){
    const int kvs = t*64;
    #pragma unroll
    for (int i = 0; i < 2; ++i){
      gload_lds16(kg + (size_t)kvs*64 + w*1024 + i*512 + l*8,
                  &Kl[buf][w*1024 + i*512 + l*8]);
      gload_lds16(vg + (size_t)(w*16 + i*8 + (l>>3))*KLn + kvs + (l&7)*8,
                  &Vl[buf][w*1024 + i*512 + l*8]);
    }
  };

  stage(0, half);   // if half >= ntiles the loop is empty; load is still in-bounds
  __syncthreads();
  int cur = 0;

  for (int t = half; t < ntiles; t += 2){
    if (t + 2 < ntiles) stage(cur ^ 1, t + 2);
    const int kvs = t*64;
    // ---- QK^T (A-frag = K rows from LDS, B-frag = Q in regs)
    f32x4 s[4];
    #pragma unroll
    for (int sub = 0; sub < 4; ++sub) s[sub] = (f32x4){0.f,0.f,0.f,0.f};
    __builtin_amdgcn_s_setprio(1);
    #pragma unroll
    for (int sub = 0; sub < 4; ++sub){
      const int r = sub*16 + lq;
      #pragma unroll
      for (int kc = 0; kc < 2; ++kc){
        short8 bk = *(const short8*)&Kl[cur][r*64 + (((kc*4 + lg) ^ (r & 7)) << 3)];
        s[sub] = __builtin_amdgcn_mfma_f32_16x16x32_bf16(bk, aq[kc], s[sub], 0,0,0);
      }
    }
    __builtin_amdgcn_s_setprio(0);
    // lane holds S[kv = kvs+sub*16+lg*4+rr][q = q0w+lq]
    if (CAUSAL){
      if (kvs + 63 > q0w){
        #pragma unroll
        for (int sub = 0; sub < 4; ++sub)
          #pragma unroll
          for (int rr = 0; rr < 4; ++rr)
            if (kvs + sub*16 + lg*4 + rr > q0w + lq) s[sub][rr] = -INFINITY;
      }
    } else {
      #pragma unroll
      for (int sub = 0; sub < 4; ++sub){
        f32x4 bv = *(const f32x4*)(bias + b*KLn + kvs + sub*16 + lg*4);
        s[sub] += bv;
      }
    }
    // ---- online softmax, defer-max
    float mx[4];
    #pragma unroll
    for (int sub = 0; sub < 4; ++sub)
      mx[sub] = fmaxf(fmaxf(s[sub][0], s[sub][1]), fmaxf(s[sub][2], s[sub][3]));
    float pmax = fmaxf(fmaxf(mx[0], mx[1]), fmaxf(mx[2], mx[3]));
    if (!__all(pmax <= m + 8.0f)){
      pmax = fmaxf(pmax, __shfl_xor(pmax, 16));
      pmax = fmaxf(pmax, __shfl_xor(pmax, 32));
      const float mnew = fmaxf(m, pmax);
      const float corr = exp2f(m - mnew);
      lsum4 *= corr;
      float corr4[4];
      #pragma unroll
      for (int rr = 0; rr < 4; ++rr) corr4[rr] = __shfl(corr, lg*4 + rr);
      #pragma unroll
      for (int d = 0; d < 4; ++d)
        #pragma unroll
        for (int rr = 0; rr < 4; ++rr) ctx[d][rr] *= corr4[rr];
      m = mnew;
    }
    u32 pk[4][2];
    #pragma unroll
    for (int sub = 0; sub < 4; ++sub){
      float p0 = exp2f(s[sub][0] - m);
      float p1 = exp2f(s[sub][1] - m);
      float p2 = exp2f(s[sub][2] - m);
      float p3 = exp2f(s[sub][3] - m);
      lsum4 += (f32x4){p0, p1, p2, p3};
      pk[sub][0] = pack2(p0, p1);
      pk[sub][1] = pack2(p2, p3);
    }
    // ---- PV (A-frag = lane-local P regs, B-frag = V^T rows from LDS)
    union { u32 u[4]; short8 s8; } pa0, pa1;
    pa0.u[0] = pk[0][0]; pa0.u[1] = pk[0][1]; pa0.u[2] = pk[1][0]; pa0.u[3] = pk[1][1];
    pa1.u[0] = pk[2][0]; pa1.u[1] = pk[2][1]; pa1.u[2] = pk[3][0]; pa1.u[3] = pk[3][1];
    __builtin_amdgcn_s_setprio(1);
    #pragma unroll
    for (int d0 = 0; d0 < 4; ++d0){
      const int dl = d0*16 + lq;
      short8 v0 = *(const short8*)&Vl[cur][dl*64 + ((lg       ^ (dl & 7)) << 3)];
      short8 v1 = *(const short8*)&Vl[cur][dl*64 + (((4 + lg) ^ (dl & 7)) << 3)];
      ctx[d0] = __builtin_amdgcn_mfma_f32_16x16x32_bf16(pa0.s8, v0, ctx[d0], 0,0,0);
      ctx[d0] = __builtin_amdgcn_mfma_f32_16x16x32_bf16(pa1.s8, v1, ctx[d0], 0,0,0);
    }
    __builtin_amdgcn_s_setprio(0);
    __syncthreads();   // drains vmcnt(0): prefetch landed; buffers safe to swap
    cur ^= 1;
  }

  // ---- write partials (no normalization here; merge kernel does it)
  float hs = (lsum4[0] + lsum4[1]) + (lsum4[2] + lsum4[3]);
  hs += __shfl_xor(hs, 16);
  hs += __shfl_xor(hs, 32);
  if (lg == 0)
    mlb[((size_t)((half*NB + b)*NH + h) << 11) + q0w + lq] = make_float2(m, hs);
  float* cp = ctxp + (size_t)half*MROWS*DIM;
  #pragma unroll
  for (int d0 = 0; d0 < 4; ++d0)
    #pragma unroll
    for (int rr = 0; rr < 4; ++rr)
      cp[(size_t)(b*QL + q0w + lg*4 + rr)*DIM + h*DH + d0*16 + lq] = ctx[d0][rr];
}

// merge the two KV-half partials: out = sum(ctx_k*w_k)/sum(l_k*w_k), w_k=exp2(m_k-mg)
__global__ __launch_bounds__(256)
void attn_merge(const float* __restrict__ ctxp, const float2* __restrict__ mlb,
                u16* __restrict__ O)
{
  const int idx = blockIdx.x*256 + threadIdx.x;
  const int row = idx >> 7;          // 0..4095
  const int col = (idx & 127) * 4;   // 0..508
  const int b = row >> 11, qr = row & 2047, h = col >> 6;
  const float2 a0 = mlb[((size_t)((      b)*NH + h) << 11) + qr];
  const float2 a1 = mlb[((size_t)((NB  + b)*NH + h) << 11) + qr];
  const float mg = fmaxf(a0.x, a1.x);
  const float w0 = exp2f(a0.x - mg), w1 = exp2f(a1.x - mg);
  const float rden = 1.f / (a0.y*w0 + a1.y*w1);
  const f32x4 c0 = *(const f32x4*)&ctxp[(size_t)row*DIM + col];
  const f32x4 c1 = *(const f32x4*)&ctxp[(size_t)MROWS*DIM + (size_t)row*DIM + col];
  u16 o[4];
  #pragma unroll
  for (int i = 0; i < 4; ++i) o[i] = f2b((c0[i]*w0 + c1[i]*w1) * rden);
  *(uint2*)&O[(size_t)row*DIM + col] = *(const uint2*)o;
}

// ---------------------------------------------------------------- layernorm
template<int MODE>
__global__ __launch_bounds__(128)
void ln_kernel(const float* __restrict__ in0, const float* __restrict__ in1,
               const float* __restrict__ tkpm,
               const float* __restrict__ g, const float* __restrict__ bvec,
               float* __restrict__ xres, u16* __restrict__ outb)
{
  const int row = blockIdx.x;
  const int t = threadIdx.x;
  float v[4];
  #pragma unroll
  for (int i = 0; i < 4; ++i){
    const int c = t + i*128;
    float x = in0[(size_t)row*DIM + c];
    if (MODE == 0){
      x += in1[(size_t)row*DIM + c];
      xres[(size_t)row*DIM + c] = x;
    }
    v[i] = x;
  }
  float s = v[0]+v[1]+v[2]+v[3];
  #pragma unroll
  for (int off = 1; off < 64; off <<= 1) s += __shfl_xor(s, off);
  __shared__ float red[4];
  if ((t & 63) == 0) red[t >> 6] = s;
  __syncthreads();
  const float mean = (red[0] + red[1]) * (1.f/512.f);
  float q = 0.f;
  #pragma unroll
  for (int i = 0; i < 4; ++i){ const float d = v[i]-mean; q += d*d; }
  #pragma unroll
  for (int off = 1; off < 64; off <<= 1) q += __shfl_xor(q, off);
  if ((t & 63) == 0) red[2 + (t >> 6)] = q;
  __syncthreads();
  const float var = (red[2] + red[3]) * (1.f/512.f);
  const float rs = rsqrtf(var + 1e-5f);
  const float tk = (MODE == 0) ? tkpm[row] : 1.f;
  #pragma unroll
  for (int i = 0; i < 4; ++i){
    const int c = t + i*128;
    const float y = (v[i] - mean) * rs * g[c] + bvec[c];
    outb[(size_t)row*DIM + c] = f2b(y * tk);
  }
}

// ---------------------------------------------------------------- transposes / misc
__global__ __launch_bounds__(256)
void transpose_f2b(const float* __restrict__ in, u16* __restrict__ out, int R, int C)
{
  __shared__ float tile[32][33];
  const int tx = threadIdx.x, ty = threadIdx.y;
  const int r0 = blockIdx.y*32, c0 = blockIdx.x*32;
  #pragma unroll
  for (int i = 0; i < 4; ++i)
    tile[ty + i*8][tx] = in[(size_t)(r0 + ty + i*8)*C + c0 + tx];
  __syncthreads();
  #pragma unroll
  for (int i = 0; i < 4; ++i)
    out[(size_t)(c0 + ty + i*8)*R + r0 + tx] = f2b(tile[tx][ty + i*8]);
}

__global__ __launch_bounds__(256)
void transpose8_f2b(const float* w0, const float* w1, const float* w2, const float* w3,
                    const float* w4, const float* w5, const float* w6, const float* w7,
                    u16* __restrict__ out)
{
  __shared__ float tile[32][33];
  const float* wp[8] = {w0,w1,w2,w3,w4,w5,w6,w7};
  const float* w = wp[blockIdx.z];
  u16* o = out + (size_t)blockIdx.z * 512 * 512;
  const int tx = threadIdx.x, ty = threadIdx.y;
  const int r0 = blockIdx.y*32, c0 = blockIdx.x*32;
  #pragma unroll
  for (int i = 0; i < 4; ++i)
    tile[ty + i*8][tx] = w[(size_t)(r0 + ty + i*8)*512 + c0 + tx];
  __syncthreads();
  #pragma unroll
  for (int i = 0; i < 4; ++i)
    o[(size_t)(c0 + ty + i*8)*512 + r0 + tx] = f2b(tile[tx][ty + i*8]);
}

// V [b][kv][512] -> Vth [b][h][dh][kv'] with PV K-slot permutation AND
// bank XOR-swizzle (chunk ^= dh&7) folded into the kv index.
__global__ __launch_bounds__(256)
void transpose_vperm(const u16* __restrict__ in, u16* __restrict__ out)
{
  __shared__ u16 tile[32][33];
  in  += (size_t)blockIdx.z * KLn * DIM;
  out += (size_t)blockIdx.z * NH * DH * KLn;
  const int tx = threadIdx.x, ty = threadIdx.y;
  const int r0 = blockIdx.y*32, c0 = blockIdx.x*32;   // r=kv, c=dcol
  #pragma unroll
  for (int i = 0; i < 4; ++i)
    tile[ty + i*8][tx] = in[(size_t)(r0 + ty + i*8)*DIM + c0 + tx];
  __syncthreads();
  const int kv = r0 + tx;
  const int s  = (kv & ~31) | (((kv>>2)&3)<<3) | (((kv>>4)&1)<<2) | (kv&3);
  #pragma unroll
  for (int i = 0; i < 4; ++i){
    const int dcol = c0 + ty + i*8;
    const int hh = dcol >> 6, dh = dcol & 63;
    const int kvpos = (s & ~63) | (((((s>>3)&7) ^ (dh&7)) << 3)) | (s & 7);
    out[((size_t)(hh*DH + dh))*KLn + kvpos] = tile[tx][ty + i*8];
  }
}

__global__ void cvt_f2b(const float* __restrict__ in, u16* __restrict__ out, int n){
  const int i = blockIdx.x*blockDim.x + threadIdx.x;
  if (i < n) out[i] = f2b(in[i]);
}

__global__ void maskbias_k(const int* __restrict__ mkpm, float* __restrict__ bias, int n){
  const int i = blockIdx.x*blockDim.x + threadIdx.x;
  if (i < n) bias[i] = mkpm[i] ? 0.f : -1e30f;
}

// ---------------------------------------------------------------- launch
extern "C" void kernel_launch(void* const* d_in, const int* in_sizes, int n_in,
                              void* d_out, int out_size, void* d_ws, size_t ws_size,
                              hipStream_t stream)
{
  const float* tgt  = (const float*)d_in[1];
  const float* mem  = (const float*)d_in[2];
  const float* pos  = (const float*)d_in[3];
  const float* tkpm = (const float*)d_in[5];
  const int*   mkpm = (const int*)d_in[6];
  const float* saqw = (const float*)d_in[7];  const float* saqb = (const float*)d_in[8];
  const float* sakw = (const float*)d_in[9];  const float* sakb = (const float*)d_in[10];
  const float* savw = (const float*)d_in[11]; const float* savb = (const float*)d_in[12];
  const float* saow = (const float*)d_in[13]; const float* saob = (const float*)d_in[14];
  const float* caqw = (const float*)d_in[15]; const float* caqb = (const float*)d_in[16];
  const float* cakw = (const float*)d_in[17]; const float* cakb = (const float*)d_in[18];
  const float* cavw = (const float*)d_in[19]; const float* cavb = (const float*)d_in[20];
  const float* caow = (const float*)d_in[21]; const float* caob = (const float*)d_in[22];
  const float* l1w  = (const float*)d_in[23]; const float* l1b  = (const float*)d_in[24];
  const float* l2w  = (const float*)d_in[25]; const float* l2b  = (const float*)d_in[26];
  const float* n1g  = (const float*)d_in[27]; const float* n1b  = (const float*)d_in[28];
  const float* n2g  = (const float*)d_in[29]; const float* n2b  = (const float*)d_in[30];
  const float* n3g  = (const float*)d_in[31]; const float* n3b  = (const float*)d_in[32];

  if (ws_size < 58720256) return;  // 56 MB scratch

  char* ws = (char*)d_ws;
  float* xres = (float*)(ws);                      // 8 MB  f32 residual
  u16* t2n    = (u16*)(ws + (8u<<20));             // 4 MB  LN out / attn out (aliased)
  u16* qb     = (u16*)(ws + (12u<<20));            // 4 MB
  u16* kb     = (u16*)(ws + (16u<<20));            // 4 MB  head-major swizzled K
  u16* vb     = (u16*)(ws + (20u<<20));            // 4 MB  (later reused for FF weightT)
  u16* vt     = (u16*)(ws + (24u<<20));            // 4 MB  head-major swizzled V^T
  float* bias = (float*)(ws + (28u<<20));          // 16 KB cross-attn additive mask
  float2* mlb = (float2*)(ws + (30u<<20));         // 512 KB attn (m,l) partials
  u16* memb   = (u16*)(ws + (32u<<20));            // 4 MB  memory in bf16
  float* ctxp = (float*)(ws + (36u<<20));          // 16 MB attn ctx partials (2 halves)
  u16* ffh    = (u16*)(ws + (36u<<20));            // 16 MB FF hidden (reuses ctxp region)
  u16* wtA    = (u16*)(ws + (52u<<20));            // 4 MB  8x 512x512 attn weightT
  u16* l1wt   = vb;                                // 2 MB  (after cross vperm)
  u16* l2wt   = (u16*)(ws + (22u<<20));            // 2 MB

  float* out = (float*)d_out;
  const int W55 = 512*512;

  maskbias_k<<<dim3(NB*KLn/256), 256, 0, stream>>>(mkpm, bias, NB*KLn);
  cvt_f2b<<<dim3(MROWS*DIM/256), 256, 0, stream>>>(mem, memb, MROWS*DIM);
  ln_kernel<0><<<MROWS, 128, 0, stream>>>(tgt, pos, tkpm, n1g, n1b, xres, t2n);
  transpose8_f2b<<<dim3(16,16,8), dim3(32,8), 0, stream>>>(saqw, sakw, savw, saow,
                                                           caqw, cakw, cavw, caow, wtA);

  #define G64(EP)  gemm_bt<EP,true><<<dim3(8,32), 256, 0, stream>>>
  #define G128(EP) gemm_bt<EP,false><<<dim3(16,32), 256, 0, stream>>>

  // ---- self attention
  G64(EPI_SCALEQ)(t2n, wtA + 0*W55, saqb, qb, nullptr, nullptr, nullptr, 512, 512);
  G64(EPI_KSWZ)  (t2n, wtA + 1*W55, sakb, kb, nullptr, nullptr, nullptr, 512, 512);
  G64(EPI_BIAS)  (t2n, wtA + 2*W55, savb, vb, nullptr, nullptr, nullptr, 512, 512);
  transpose_vperm<<<dim3(DIM/32, KLn/32, NB), dim3(32,8), 0, stream>>>(vb, vt);
  attn6<true><<<dim3(QL/64, NH, NB*2), 256, 0, stream>>>(qb, kb, vt, nullptr, ctxp, mlb);
  attn_merge<<<dim3(MROWS*DIM/1024), 256, 0, stream>>>(ctxp, mlb, t2n);
  G64(EPI_RES)   (t2n, wtA + 3*W55, saob, nullptr, xres, nullptr, nullptr, 512, 512);

  ln_kernel<1><<<MROWS, 128, 0, stream>>>(xres, nullptr, nullptr, n2g, n2b, nullptr, t2n);

  // ---- cross attention
  G64(EPI_SCALEQ)(t2n,  wtA + 4*W55, caqb, qb, nullptr, nullptr, nullptr, 512, 512);
  G64(EPI_KSWZ)  (memb, wtA + 5*W55, cakb, kb, nullptr, nullptr, nullptr, 512, 512);
  G64(EPI_BIAS)  (memb, wtA + 6*W55, cavb, vb, nullptr, nullptr, nullptr, 512, 512);
  transpose_vperm<<<dim3(DIM/32, KLn/32, NB), dim3(32,8), 0, stream>>>(vb, vt);
  transpose_f2b<<<dim3(FFD/32, 512/32), dim3(32,8), 0, stream>>>(l1w, l1wt, 512, FFD);
  transpose_f2b<<<dim3(512/32, FFD/32), dim3(32,8), 0, stream>>>(l2w, l2wt, FFD, 512);
  attn6<false><<<dim3(QL/64, NH, NB*2), 256, 0, stream>>>(qb, kb, vt, bias, ctxp, mlb);
  attn_merge<<<dim3(MROWS*DIM/1024), 256, 0, stream>>>(ctxp, mlb, t2n);
  G64(EPI_RES)   (t2n, wtA + 7*W55, caob, nullptr, xres, nullptr, nullptr, 512, 512);

  ln_kernel<1><<<MROWS, 128, 0, stream>>>(xres, nullptr, nullptr, n3g, n3b, nullptr, t2n);

  // ---- feed-forward (FF2 epilogue fuses residual add + tkpm scale + f32 out)
  G128(EPI_RELU)(t2n, l1wt, l1b, ffh, nullptr, nullptr, nullptr, 512, FFD);
  G64(EPI_FIN)  (ffh, l2wt, l2b, nullptr, xres, tkpm, out, FFD, 512);

  #undef G64
  #undef G128
}

// Round 8
// 248.016 us; speedup vs baseline: 2.1887x; 1.1329x over previous
//
#include <hip/hip_runtime.h>
#include <hip/hip_bf16.h>
#include <stdint.h>

#define QL   2048
#define KLn  2048
#define DIM  512
#define NH   8
#define DH   64
#define NB   2
#define MROWS (NB*QL)   // 4096
#define FFD  2048

typedef unsigned short u16;
typedef unsigned int u32;
typedef __attribute__((ext_vector_type(8))) short short8;
typedef __attribute__((ext_vector_type(4))) float f32x4;

__device__ __forceinline__ u16 f2b(float f){
  union { float f; u32 i; } v; v.f = f;
  u32 r = v.i + 0x7FFFu + ((v.i >> 16) & 1u);
  return (u16)(r >> 16);
}
// two f32 -> packed bf16x2 in one instruction (lo=a, hi=b, RNE)
__device__ __forceinline__ u32 cvtpk(float a, float b){
  u32 r;
  asm("v_cvt_pk_bf16_f32 %0, %1, %2" : "=v"(r) : "v"(a), "v"(b));
  return r;
}

typedef __attribute__((address_space(3))) void as3void;
typedef __attribute__((address_space(1))) void as1void;
__device__ __forceinline__ void gload_lds16(const void* g, void* l){
  __builtin_amdgcn_global_load_lds((as1void*)g, (as3void*)l, 16, 0, 0);
}

// ---------------------------------------------------------------- GEMM v2
// BK=64, chunk-XOR bank swizzle (chunk ^= row&7, both-sides involution:
// pre-swizzled global source for the linear global_load_lds dest + swizzled
// ds_read), prefetch-style single-buffer loop (stage(k+1) after read-barrier
// overlaps MFMA). BNv=128: 4 waves of 64x64. BNv=64: 4 waves of 32x64.
#define BK 64
enum { EPI_BIAS=0, EPI_SCALEQ=1, EPI_RELU=2, EPI_RES=3, EPI_FIN=5, EPI_QKV=6, EPI_KV=7 };
// 1/sqrt(64) * log2(e): folds softmax exp->exp2 conversion into Q scale
#define QSCALE 0.1803368801111244f

template<int EPI, int BNv>
__global__ __launch_bounds__(256, 2)
void gemm_bt(const u16* __restrict__ A, const u16* __restrict__ Bt,
             const float* __restrict__ bias,
             u16* __restrict__ Obf, float* __restrict__ Ores,
             const float* __restrict__ tk, float* __restrict__ fout,
             int K, int N)
{
  constexpr int MI = (BNv == 64) ? 2 : 4;
  __shared__ __align__(16) u16 As[128*BK];
  __shared__ __align__(16) u16 Bs[BNv*BK];
  const int t  = threadIdx.x;
  const int l  = t & 63;
  const int lq = l & 15, lg = l >> 4;
  const int w  = t >> 6;
  const int wm = (BNv == 64) ? w*32 : (w >> 1)*64;
  const int wn = (BNv == 64) ? 0    : (w & 1)*64;
  const int m0 = blockIdx.y * 128;
  const int n0 = blockIdx.x * BNv;

  const int srow8 = t >> 3;   // 0..31
  const int scs   = t & 7;    // 16B chunk within a 128B row

  auto stage = [&](int k0){
    #pragma unroll
    for (int i = 0; i < 4; ++i){
      const int row = i*32 + srow8;
      gload_lds16(A + (size_t)(m0 + row)*K + k0 + ((scs ^ (row & 7)) << 3),
                  &As[row*BK + scs*8]);
    }
    #pragma unroll
    for (int i = 0; i < BNv/32; ++i){
      const int row = i*32 + srow8;
      gload_lds16(Bt + (size_t)(n0 + row)*K + k0 + ((scs ^ (row & 7)) << 3),
                  &Bs[row*BK + scs*8]);
    }
  };

  f32x4 acc[MI][4];
  #pragma unroll
  for (int i=0;i<MI;i++)
    #pragma unroll
    for (int j=0;j<4;j++) acc[i][j] = (f32x4){0.f,0.f,0.f,0.f};

  stage(0);
  for (int k0 = 0; k0 < K; k0 += BK){
    __syncthreads();                     // staged data visible (drains vmcnt)
    short8 af[MI][2], bf[4][2];
    #pragma unroll
    for (int kc = 0; kc < 2; ++kc){
      #pragma unroll
      for (int i=0;i<MI;i++){
        const int row = wm + i*16 + lq;
        af[i][kc] = *(const short8*)&As[row*BK + (((kc*4 + lg) ^ (lq & 7)) << 3)];
      }
      #pragma unroll
      for (int j=0;j<4;j++){
        const int row = wn + j*16 + lq;
        bf[j][kc] = *(const short8*)&Bs[row*BK + (((kc*4 + lg) ^ (lq & 7)) << 3)];
      }
    }
    __syncthreads();                     // all waves done reading LDS
    if (k0 + BK < K) stage(k0 + BK);     // async staging overlaps MFMA
    __builtin_amdgcn_s_setprio(1);
    #pragma unroll
    for (int kc = 0; kc < 2; ++kc)
      #pragma unroll
      for (int i=0;i<MI;i++)
        #pragma unroll
        for (int j=0;j<4;j++)
          acc[i][j] = __builtin_amdgcn_mfma_f32_16x16x32_bf16(af[i][kc], bf[j][kc], acc[i][j], 0,0,0);
    __builtin_amdgcn_s_setprio(0);
  }

  #pragma unroll
  for (int i=0;i<MI;i++){
    #pragma unroll
    for (int j=0;j<4;j++){
      #pragma unroll
      for (int rr=0;rr<4;rr++){
        const int row = m0 + wm + i*16 + lg*4 + rr;
        const int col = n0 + wn + j*16 + lq;
        float v = acc[i][j][rr] + bias[col];
        if (EPI == EPI_SCALEQ) v *= QSCALE;
        if (EPI == EPI_RELU)   v = fmaxf(v, 0.f);
        if (EPI == EPI_RES)    Ores[(size_t)row*N + col] += v;
        else if (EPI == EPI_FIN){
          const size_t idx = (size_t)row*N + col;
          fout[idx] = (Ores[idx] + v) * tk[row];
        }
        else if (EPI == EPI_QKV){
          // contiguous q|k|v buffers (2M u16 each). seg uniform per j.
          const int seg = col >> 9, c = col & 511;
          if (seg == 0)      Obf[(size_t)row*512 + c] = f2b(v * QSCALE);
          else if (seg == 1){
            const int bb = row >> 11, kv = row & 2047;
            const int hh = c >> 6,  dh = c & 63;
            Obf[(2u<<20) + ((((size_t)(bb*NH + hh) << 11) + kv) << 6) + (dh ^ ((kv & 7) << 3))] = f2b(v);
          }
          else               Obf[(4u<<20) + (size_t)row*512 + c] = f2b(v);
        }
        else if (EPI == EPI_KV){
          const int seg = col >> 9, c = col & 511;
          if (seg == 0){
            const int bb = row >> 11, kv = row & 2047;
            const int hh = c >> 6,  dh = c & 63;
            Obf[((((size_t)(bb*NH + hh) << 11) + kv) << 6) + (dh ^ ((kv & 7) << 3))] = f2b(v);
          }
          else               Obf[(2u<<20) + (size_t)row*512 + c] = f2b(v);
        }
        else                   Obf[(size_t)row*N + col] = f2b(v);
      }
    }
  }
}

// ---------------------------------------------------------------- attention v6b
// = v6 (4 waves x 16 q-rows, KVBLK=64, cross-block KV-split x2, dbuf LDS via
// global_load_lds with baked XOR swizzle, swapped QK^T, lane-local P,
// defer-max, setprio) with v_cvt_pk_bf16_f32 replacing the manual 3-op pack.
template<bool CAUSAL>
__global__ __launch_bounds__(256, 4)
void attn6(const u16* __restrict__ Q, const u16* __restrict__ Kbh,
           const u16* __restrict__ Vth, const float* __restrict__ bias,
           float* __restrict__ ctxp, float2* __restrict__ mlb)
{
  __shared__ __align__(16) u16 Kl[2][64*64];
  __shared__ __align__(16) u16 Vl[2][64*64];
  const int tid = threadIdx.x;
  const int l  = tid & 63;
  const int w  = tid >> 6;
  const int lq = l & 15, lg = l >> 4;
  const int h    = blockIdx.y;
  const int b    = blockIdx.z >> 1;
  const int half = blockIdx.z & 1;
  const int qtile = CAUSAL ? ((b & 1) ? (31 - (int)blockIdx.x) : (int)blockIdx.x)
                           : (int)blockIdx.x;
  const int q0w = qtile*64 + w*16;

  const u16* kg = Kbh + ((size_t)(b*NH + h) << 17);   // [2048][64]
  const u16* vg = Vth + ((size_t)(b*NH + h) << 17);   // [64][2048]

  short8 aq[2];
  #pragma unroll
  for (int kc = 0; kc < 2; ++kc)
    aq[kc] = *(const short8*)(Q + (size_t)(b*QL + q0w + lq)*DIM + h*DH + kc*32 + lg*8);

  f32x4 ctx[4];
  #pragma unroll
  for (int d = 0; d < 4; ++d) ctx[d] = (f32x4){0.f,0.f,0.f,0.f};
  f32x4 lsum4 = (f32x4){0.f,0.f,0.f,0.f};
  float m = -INFINITY;

  const int ntiles = CAUSAL ? (qtile + 1) : (KLn >> 6);

  auto stage = [&](int buf, int t){
    const int kvs = t*64;
    #pragma unroll
    for (int i = 0; i < 2; ++i){
      gload_lds16(kg + (size_t)kvs*64 + w*1024 + i*512 + l*8,
                  &Kl[buf][w*1024 + i*512 + l*8]);
      gload_lds16(vg + (size_t)(w*16 + i*8 + (l>>3))*KLn + kvs + (l&7)*8,
                  &Vl[buf][w*1024 + i*512 + l*8]);
    }
  };

  stage(0, half);   // if half >= ntiles the loop is empty; load is still in-bounds
  __syncthreads();
  int cur = 0;

  for (int t = half; t < ntiles; t += 2){
    if (t + 2 < ntiles) stage(cur ^ 1, t + 2);
    const int kvs = t*64;
    // ---- QK^T (A-frag = K rows from LDS, B-frag = Q in regs)
    f32x4 s[4];
    #pragma unroll
    for (int sub = 0; sub < 4; ++sub) s[sub] = (f32x4){0.f,0.f,0.f,0.f};
    __builtin_amdgcn_s_setprio(1);
    #pragma unroll
    for (int sub = 0; sub < 4; ++sub){
      const int r = sub*16 + lq;
      #pragma unroll
      for (int kc = 0; kc < 2; ++kc){
        short8 bk = *(const short8*)&Kl[cur][r*64 + (((kc*4 + lg) ^ (r & 7)) << 3)];
        s[sub] = __builtin_amdgcn_mfma_f32_16x16x32_bf16(bk, aq[kc], s[sub], 0,0,0);
      }
    }
    __builtin_amdgcn_s_setprio(0);
    // lane holds S[kv = kvs+sub*16+lg*4+rr][q = q0w+lq]
    if (CAUSAL){
      if (kvs + 63 > q0w){
        #pragma unroll
        for (int sub = 0; sub < 4; ++sub)
          #pragma unroll
          for (int rr = 0; rr < 4; ++rr)
            if (kvs + sub*16 + lg*4 + rr > q0w + lq) s[sub][rr] = -INFINITY;
      }
    } else {
      #pragma unroll
      for (int sub = 0; sub < 4; ++sub){
        f32x4 bv = *(const f32x4*)(bias + b*KLn + kvs + sub*16 + lg*4);
        s[sub] += bv;
      }
    }
    // ---- online softmax, defer-max
    float mx[4];
    #pragma unroll
    for (int sub = 0; sub < 4; ++sub)
      mx[sub] = fmaxf(fmaxf(s[sub][0], s[sub][1]), fmaxf(s[sub][2], s[sub][3]));
    float pmax = fmaxf(fmaxf(mx[0], mx[1]), fmaxf(mx[2], mx[3]));
    if (!__all(pmax <= m + 8.0f)){
      pmax = fmaxf(pmax, __shfl_xor(pmax, 16));
      pmax = fmaxf(pmax, __shfl_xor(pmax, 32));
      const float mnew = fmaxf(m, pmax);
      const float corr = exp2f(m - mnew);
      lsum4 *= corr;
      float corr4[4];
      #pragma unroll
      for (int rr = 0; rr < 4; ++rr) corr4[rr] = __shfl(corr, lg*4 + rr);
      #pragma unroll
      for (int d = 0; d < 4; ++d)
        #pragma unroll
        for (int rr = 0; rr < 4; ++rr) ctx[d][rr] *= corr4[rr];
      m = mnew;
    }
    u32 pk[4][2];
    #pragma unroll
    for (int sub = 0; sub < 4; ++sub){
      float p0 = exp2f(s[sub][0] - m);
      float p1 = exp2f(s[sub][1] - m);
      float p2 = exp2f(s[sub][2] - m);
      float p3 = exp2f(s[sub][3] - m);
      lsum4 += (f32x4){p0, p1, p2, p3};
      pk[sub][0] = cvtpk(p0, p1);
      pk[sub][1] = cvtpk(p2, p3);
    }
    // ---- PV (A-frag = lane-local P regs, B-frag = V^T rows from LDS)
    union { u32 u[4]; short8 s8; } pa0, pa1;
    pa0.u[0] = pk[0][0]; pa0.u[1] = pk[0][1]; pa0.u[2] = pk[1][0]; pa0.u[3] = pk[1][1];
    pa1.u[0] = pk[2][0]; pa1.u[1] = pk[2][1]; pa1.u[2] = pk[3][0]; pa1.u[3] = pk[3][1];
    __builtin_amdgcn_s_setprio(1);
    #pragma unroll
    for (int d0 = 0; d0 < 4; ++d0){
      const int dl = d0*16 + lq;
      short8 v0 = *(const short8*)&Vl[cur][dl*64 + ((lg       ^ (dl & 7)) << 3)];
      short8 v1 = *(const short8*)&Vl[cur][dl*64 + (((4 + lg) ^ (dl & 7)) << 3)];
      ctx[d0] = __builtin_amdgcn_mfma_f32_16x16x32_bf16(pa0.s8, v0, ctx[d0], 0,0,0);
      ctx[d0] = __builtin_amdgcn_mfma_f32_16x16x32_bf16(pa1.s8, v1, ctx[d0], 0,0,0);
    }
    __builtin_amdgcn_s_setprio(0);
    __syncthreads();   // drains vmcnt(0): prefetch landed; buffers safe to swap
    cur ^= 1;
  }

  // ---- write partials (no normalization here; merge kernel does it)
  float hs = (lsum4[0] + lsum4[1]) + (lsum4[2] + lsum4[3]);
  hs += __shfl_xor(hs, 16);
  hs += __shfl_xor(hs, 32);
  if (lg == 0)
    mlb[((size_t)((half*NB + b)*NH + h) << 11) + q0w + lq] = make_float2(m, hs);
  float* cp = ctxp + (size_t)half*MROWS*DIM;
  #pragma unroll
  for (int d0 = 0; d0 < 4; ++d0)
    #pragma unroll
    for (int rr = 0; rr < 4; ++rr)
      cp[(size_t)(b*QL + q0w + lg*4 + rr)*DIM + h*DH + d0*16 + lq] = ctx[d0][rr];
}

// merge the two KV-half partials: out = sum(ctx_k*w_k)/sum(l_k*w_k), w_k=exp2(m_k-mg)
__global__ __launch_bounds__(256)
void attn_merge(const float* __restrict__ ctxp, const float2* __restrict__ mlb,
                u16* __restrict__ O)
{
  const int idx = blockIdx.x*256 + threadIdx.x;
  const int row = idx >> 7;          // 0..4095
  const int col = (idx & 127) * 4;   // 0..508
  const int b = row >> 11, qr = row & 2047, h = col >> 6;
  const float2 a0 = mlb[((size_t)((      b)*NH + h) << 11) + qr];
  const float2 a1 = mlb[((size_t)((NB  + b)*NH + h) << 11) + qr];
  const float mg = fmaxf(a0.x, a1.x);
  const float w0 = exp2f(a0.x - mg), w1 = exp2f(a1.x - mg);
  const float rden = 1.f / (a0.y*w0 + a1.y*w1);
  const f32x4 c0 = *(const f32x4*)&ctxp[(size_t)row*DIM + col];
  const f32x4 c1 = *(const f32x4*)&ctxp[(size_t)MROWS*DIM + (size_t)row*DIM + col];
  u16 o[4];
  #pragma unroll
  for (int i = 0; i < 4; ++i) o[i] = f2b((c0[i]*w0 + c1[i]*w1) * rden);
  *(uint2*)&O[(size_t)row*DIM + col] = *(const uint2*)o;
}

// ---------------------------------------------------------------- layernorm
template<int MODE>
__global__ __launch_bounds__(128)
void ln_kernel(const float* __restrict__ in0, const float* __restrict__ in1,
               const float* __restrict__ tkpm,
               const float* __restrict__ g, const float* __restrict__ bvec,
               float* __restrict__ xres, u16* __restrict__ outb)
{
  const int row = blockIdx.x;
  const int t = threadIdx.x;
  float v[4];
  #pragma unroll
  for (int i = 0; i < 4; ++i){
    const int c = t + i*128;
    float x = in0[(size_t)row*DIM + c];
    if (MODE == 0){
      x += in1[(size_t)row*DIM + c];
      xres[(size_t)row*DIM + c] = x;
    }
    v[i] = x;
  }
  float s = v[0]+v[1]+v[2]+v[3];
  #pragma unroll
  for (int off = 1; off < 64; off <<= 1) s += __shfl_xor(s, off);
  __shared__ float red[4];
  if ((t & 63) == 0) red[t >> 6] = s;
  __syncthreads();
  const float mean = (red[0] + red[1]) * (1.f/512.f);
  float q = 0.f;
  #pragma unroll
  for (int i = 0; i < 4; ++i){ const float d = v[i]-mean; q += d*d; }
  #pragma unroll
  for (int off = 1; off < 64; off <<= 1) q += __shfl_xor(q, off);
  if ((t & 63) == 0) red[2 + (t >> 6)] = q;
  __syncthreads();
  const float var = (red[2] + red[3]) * (1.f/512.f);
  const float rs = rsqrtf(var + 1e-5f);
  const float tk = (MODE == 0) ? tkpm[row] : 1.f;
  #pragma unroll
  for (int i = 0; i < 4; ++i){
    const int c = t + i*128;
    const float y = (v[i] - mean) * rs * g[c] + bvec[c];
    outb[(size_t)row*DIM + c] = f2b(y * tk);
  }
}

// ---------------------------------------------------------------- transposes / misc
__global__ __launch_bounds__(256)
void transpose_f2b(const float* __restrict__ in, u16* __restrict__ out, int R, int C)
{
  __shared__ float tile[32][33];
  const int tx = threadIdx.x, ty = threadIdx.y;
  const int r0 = blockIdx.y*32, c0 = blockIdx.x*32;
  #pragma unroll
  for (int i = 0; i < 4; ++i)
    tile[ty + i*8][tx] = in[(size_t)(r0 + ty + i*8)*C + c0 + tx];
  __syncthreads();
  #pragma unroll
  for (int i = 0; i < 4; ++i)
    out[(size_t)(c0 + ty + i*8)*R + r0 + tx] = f2b(tile[tx][ty + i*8]);
}

__global__ __launch_bounds__(256)
void transpose8_f2b(const float* w0, const float* w1, const float* w2, const float* w3,
                    const float* w4, const float* w5, const float* w6, const float* w7,
                    u16* __restrict__ out)
{
  __shared__ float tile[32][33];
  const float* wp[8] = {w0,w1,w2,w3,w4,w5,w6,w7};
  const float* w = wp[blockIdx.z];
  u16* o = out + (size_t)blockIdx.z * 512 * 512;
  const int tx = threadIdx.x, ty = threadIdx.y;
  const int r0 = blockIdx.y*32, c0 = blockIdx.x*32;
  #pragma unroll
  for (int i = 0; i < 4; ++i)
    tile[ty + i*8][tx] = w[(size_t)(r0 + ty + i*8)*512 + c0 + tx];
  __syncthreads();
  #pragma unroll
  for (int i = 0; i < 4; ++i)
    o[(size_t)(c0 + ty + i*8)*512 + r0 + tx] = f2b(tile[tx][ty + i*8]);
}

// V [b][kv][512] -> Vth [b][h][dh][kv'] with PV K-slot permutation AND
// bank XOR-swizzle (chunk ^= dh&7) folded into the kv index.
__global__ __launch_bounds__(256)
void transpose_vperm(const u16* __restrict__ in, u16* __restrict__ out)
{
  __shared__ u16 tile[32][33];
  in  += (size_t)blockIdx.z * KLn * DIM;
  out += (size_t)blockIdx.z * NH * DH * KLn;
  const int tx = threadIdx.x, ty = threadIdx.y;
  const int r0 = blockIdx.y*32, c0 = blockIdx.x*32;   // r=kv, c=dcol
  #pragma unroll
  for (int i = 0; i < 4; ++i)
    tile[ty + i*8][tx] = in[(size_t)(r0 + ty + i*8)*DIM + c0 + tx];
  __syncthreads();
  const int kv = r0 + tx;
  const int s  = (kv & ~31) | (((kv>>2)&3)<<3) | (((kv>>4)&1)<<2) | (kv&3);
  #pragma unroll
  for (int i = 0; i < 4; ++i){
    const int dcol = c0 + ty + i*8;
    const int hh = dcol >> 6, dh = dcol & 63;
    const int kvpos = (s & ~63) | (((((s>>3)&7) ^ (dh&7)) << 3)) | (s & 7);
    out[((size_t)(hh*DH + dh))*KLn + kvpos] = tile[tx][ty + i*8];
  }
}

__global__ void cvt_f2b(const float* __restrict__ in, u16* __restrict__ out, int n){
  const int i = blockIdx.x*blockDim.x + threadIdx.x;
  if (i < n) out[i] = f2b(in[i]);
}

__global__ void maskbias_k(const int* __restrict__ mkpm, float* __restrict__ bias, int n){
  const int i = blockIdx.x*blockDim.x + threadIdx.x;
  if (i < n) bias[i] = mkpm[i] ? 0.f : -1e30f;
}

// concat up to 3 512-float bias vectors
__global__ void cat3(const float* a, const float* b, const float* c, float* o){
  const int i = blockIdx.x*256 + threadIdx.x;
  const float* p[3] = {a, b, c};
  o[i] = p[i >> 9][i & 511];
}

// ---------------------------------------------------------------- launch
extern "C" void kernel_launch(void* const* d_in, const int* in_sizes, int n_in,
                              void* d_out, int out_size, void* d_ws, size_t ws_size,
                              hipStream_t stream)
{
  const float* tgt  = (const float*)d_in[1];
  const float* mem  = (const float*)d_in[2];
  const float* pos  = (const float*)d_in[3];
  const float* tkpm = (const float*)d_in[5];
  const int*   mkpm = (const int*)d_in[6];
  const float* saqw = (const float*)d_in[7];  const float* saqb = (const float*)d_in[8];
  const float* sakw = (const float*)d_in[9];  const float* sakb = (const float*)d_in[10];
  const float* savw = (const float*)d_in[11]; const float* savb = (const float*)d_in[12];
  const float* saow = (const float*)d_in[13]; const float* saob = (const float*)d_in[14];
  const float* caqw = (const float*)d_in[15]; const float* caqb = (const float*)d_in[16];
  const float* cakw = (const float*)d_in[17]; const float* cakb = (const float*)d_in[18];
  const float* cavw = (const float*)d_in[19]; const float* cavb = (const float*)d_in[20];
  const float* caow = (const float*)d_in[21]; const float* caob = (const float*)d_in[22];
  const float* l1w  = (const float*)d_in[23]; const float* l1b  = (const float*)d_in[24];
  const float* l2w  = (const float*)d_in[25]; const float* l2b  = (const float*)d_in[26];
  const float* n1g  = (const float*)d_in[27]; const float* n1b  = (const float*)d_in[28];
  const float* n2g  = (const float*)d_in[29]; const float* n2b  = (const float*)d_in[30];
  const float* n3g  = (const float*)d_in[31]; const float* n3b  = (const float*)d_in[32];

  if (ws_size < 58720256) return;  // 56 MB scratch

  char* ws = (char*)d_ws;
  float* xres = (float*)(ws);                      // 8 MB  f32 residual
  u16* t2n    = (u16*)(ws + (8u<<20));             // 4 MB  LN out / attn out (aliased)
  u16* qb     = (u16*)(ws + (12u<<20));            // 4 MB  | contiguous q|k|v
  u16* kb     = (u16*)(ws + (16u<<20));            // 4 MB  | head-major swizzled K
  u16* vb     = (u16*)(ws + (20u<<20));            // 4 MB  | (later reused for FF weightT)
  u16* vt     = (u16*)(ws + (24u<<20));            // 4 MB  head-major swizzled V^T
  float* bias = (float*)(ws + (28u<<20));          // 16 KB cross-attn additive mask
  float* bc0  = (float*)(ws + (29u<<20));          // 6 KB  qkv bias concat
  float* bc1  = (float*)(ws + (29u<<20) + 8192);   // 4 KB  kv bias concat
  float2* mlb = (float2*)(ws + (30u<<20));         // 512 KB attn (m,l) partials
  u16* memb   = (u16*)(ws + (32u<<20));            // 4 MB  memory in bf16
  float* ctxp = (float*)(ws + (36u<<20));          // 16 MB attn ctx partials (2 halves)
  u16* ffh    = (u16*)(ws + (36u<<20));            // 16 MB FF hidden (reuses ctxp region)
  u16* wtA    = (u16*)(ws + (52u<<20));            // 4 MB  8x 512x512 attn weightT (stacked)
  u16* l1wt   = vb;                                // 2 MB  (after cross vperm)
  u16* l2wt   = (u16*)(ws + (22u<<20));            // 2 MB

  float* out = (float*)d_out;
  const int W55 = 512*512;

  maskbias_k<<<dim3(NB*KLn/256), 256, 0, stream>>>(mkpm, bias, NB*KLn);
  cvt_f2b<<<dim3(MROWS*DIM/256), 256, 0, stream>>>(mem, memb, MROWS*DIM);
  ln_kernel<0><<<MROWS, 128, 0, stream>>>(tgt, pos, tkpm, n1g, n1b, xres, t2n);
  transpose8_f2b<<<dim3(16,16,8), dim3(32,8), 0, stream>>>(saqw, sakw, savw, saow,
                                                           caqw, cakw, cavw, caow, wtA);
  cat3<<<6, 256, 0, stream>>>(saqb, sakb, savb, bc0);
  cat3<<<4, 256, 0, stream>>>(cakb, cavb, cavb, bc1);

  #define G64(EP)  gemm_bt<EP,64> <<<dim3(8,32),  256, 0, stream>>>
  #define G128(EP, NB128) gemm_bt<EP,128><<<dim3(NB128,32), 256, 0, stream>>>

  // ---- self attention (fused QKV: N=1536, wtA rows 0..1535 are Wq|Wk|Wv ^T)
  G128(EPI_QKV, 12)(t2n, wtA, bc0, qb, nullptr, nullptr, nullptr, 512, 1536);
  transpose_vperm<<<dim3(DIM/32, KLn/32, NB), dim3(32,8), 0, stream>>>(vb, vt);
  attn6<true><<<dim3(QL/64, NH, NB*2), 256, 0, stream>>>(qb, kb, vt, nullptr, ctxp, mlb);
  attn_merge<<<dim3(MROWS*DIM/1024), 256, 0, stream>>>(ctxp, mlb, t2n);
  G64(EPI_RES)   (t2n, wtA + 3*W55, saob, nullptr, xres, nullptr, nullptr, 512, 512);

  ln_kernel<1><<<MROWS, 128, 0, stream>>>(xres, nullptr, nullptr, n2g, n2b, nullptr, t2n);

  // ---- cross attention (fused KV: N=1024)
  G64(EPI_SCALEQ)(t2n,  wtA + 4*W55, caqb, qb, nullptr, nullptr, nullptr, 512, 512);
  G128(EPI_KV, 8)(memb, wtA + 5*W55, bc1, kb, nullptr, nullptr, nullptr, 512, 1024);
  transpose_vperm<<<dim3(DIM/32, KLn/32, NB), dim3(32,8), 0, stream>>>(vb, vt);
  transpose_f2b<<<dim3(FFD/32, 512/32), dim3(32,8), 0, stream>>>(l1w, l1wt, 512, FFD);
  transpose_f2b<<<dim3(512/32, FFD/32), dim3(32,8), 0, stream>>>(l2w, l2wt, FFD, 512);
  attn6<false><<<dim3(QL/64, NH, NB*2), 256, 0, stream>>>(qb, kb, vt, bias, ctxp, mlb);
  attn_merge<<<dim3(MROWS*DIM/1024), 256, 0, stream>>>(ctxp, mlb, t2n);
  G64(EPI_RES)   (t2n, wtA + 7*W55, caob, nullptr, xres, nullptr, nullptr, 512, 512);

  ln_kernel<1><<<MROWS, 128, 0, stream>>>(xres, nullptr, nullptr, n3g, n3b, nullptr, t2n);

  // ---- feed-forward (FF2 epilogue fuses residual add + tkpm scale + f32 out)
  G128(EPI_RELU, 16)(t2n, l1wt, l1b, ffh, nullptr, nullptr, nullptr, 512, FFD);
  G64(EPI_FIN)  (ffh, l2wt, l2b, nullptr, xres, tkpm, out, FFD, 512);

  #undef G64
  #undef G128
}

// Round 9
// 226.655 us; speedup vs baseline: 2.3950x; 1.0942x over previous
//
#include <hip/hip_runtime.h>
#include <hip/hip_bf16.h>
#include <stdint.h>

#define QL   2048
#define KLn  2048
#define DIM  512
#define NH   8
#define DH   64
#define NB   2
#define MROWS (NB*QL)   // 4096
#define FFD  2048

typedef unsigned short u16;
typedef unsigned int u32;
typedef __attribute__((ext_vector_type(8))) short short8;
typedef __attribute__((ext_vector_type(4))) float f32x4;

__device__ __forceinline__ u16 f2b(float f){
  union { float f; u32 i; } v; v.f = f;
  u32 r = v.i + 0x7FFFu + ((v.i >> 16) & 1u);
  return (u16)(r >> 16);
}
// two f32 -> packed bf16x2 in one instruction (lo=a, hi=b, RNE)
__device__ __forceinline__ u32 cvtpk(float a, float b){
  u32 r;
  asm("v_cvt_pk_bf16_f32 %0, %1, %2" : "=v"(r) : "v"(a), "v"(b));
  return r;
}

typedef __attribute__((address_space(3))) void as3void;
typedef __attribute__((address_space(1))) void as1void;
__device__ __forceinline__ void gload_lds16(const void* g, void* l){
  __builtin_amdgcn_global_load_lds((as1void*)g, (as3void*)l, 16, 0, 0);
}

// ---------------------------------------------------------------- GEMM v2
// BK=64, chunk-XOR bank swizzle (chunk ^= row&7, both-sides involution),
// prefetch-style single-buffer loop. gemm_bt: 128xBNv tiles. gemm64: 64x64
// tiles for N=512 outputs (R8: 128x64 grids = 256 blocks = 1 block/CU = zero
// TLP for a barrier-synced loop; 64x64 doubles the grid to 2 blocks/CU).
#define BK 64
enum { EPI_BIAS=0, EPI_SCALEQ=1, EPI_RELU=2, EPI_RES=3, EPI_FIN=5, EPI_QKV=6, EPI_KV=7 };
// 1/sqrt(64) * log2(e): folds softmax exp->exp2 conversion into Q scale
#define QSCALE 0.1803368801111244f

template<int EPI, int BNv>
__global__ __launch_bounds__(256, 2)
void gemm_bt(const u16* __restrict__ A, const u16* __restrict__ Bt,
             const float* __restrict__ bias,
             u16* __restrict__ Obf, float* __restrict__ Ores,
             const float* __restrict__ tk, float* __restrict__ fout,
             int K, int N)
{
  constexpr int MI = (BNv == 64) ? 2 : 4;
  __shared__ __align__(16) u16 As[128*BK];
  __shared__ __align__(16) u16 Bs[BNv*BK];
  const int t  = threadIdx.x;
  const int l  = t & 63;
  const int lq = l & 15, lg = l >> 4;
  const int w  = t >> 6;
  const int wm = (BNv == 64) ? w*32 : (w >> 1)*64;
  const int wn = (BNv == 64) ? 0    : (w & 1)*64;
  const int m0 = blockIdx.y * 128;
  const int n0 = blockIdx.x * BNv;

  const int srow8 = t >> 3;   // 0..31
  const int scs   = t & 7;    // 16B chunk within a 128B row

  auto stage = [&](int k0){
    #pragma unroll
    for (int i = 0; i < 4; ++i){
      const int row = i*32 + srow8;
      gload_lds16(A + (size_t)(m0 + row)*K + k0 + ((scs ^ (row & 7)) << 3),
                  &As[row*BK + scs*8]);
    }
    #pragma unroll
    for (int i = 0; i < BNv/32; ++i){
      const int row = i*32 + srow8;
      gload_lds16(Bt + (size_t)(n0 + row)*K + k0 + ((scs ^ (row & 7)) << 3),
                  &Bs[row*BK + scs*8]);
    }
  };

  f32x4 acc[MI][4];
  #pragma unroll
  for (int i=0;i<MI;i++)
    #pragma unroll
    for (int j=0;j<4;j++) acc[i][j] = (f32x4){0.f,0.f,0.f,0.f};

  stage(0);
  for (int k0 = 0; k0 < K; k0 += BK){
    __syncthreads();                     // staged data visible (drains vmcnt)
    short8 af[MI][2], bf[4][2];
    #pragma unroll
    for (int kc = 0; kc < 2; ++kc){
      #pragma unroll
      for (int i=0;i<MI;i++){
        const int row = wm + i*16 + lq;
        af[i][kc] = *(const short8*)&As[row*BK + (((kc*4 + lg) ^ (lq & 7)) << 3)];
      }
      #pragma unroll
      for (int j=0;j<4;j++){
        const int row = wn + j*16 + lq;
        bf[j][kc] = *(const short8*)&Bs[row*BK + (((kc*4 + lg) ^ (lq & 7)) << 3)];
      }
    }
    __syncthreads();                     // all waves done reading LDS
    if (k0 + BK < K) stage(k0 + BK);     // async staging overlaps MFMA
    __builtin_amdgcn_s_setprio(1);
    #pragma unroll
    for (int kc = 0; kc < 2; ++kc)
      #pragma unroll
      for (int i=0;i<MI;i++)
        #pragma unroll
        for (int j=0;j<4;j++)
          acc[i][j] = __builtin_amdgcn_mfma_f32_16x16x32_bf16(af[i][kc], bf[j][kc], acc[i][j], 0,0,0);
    __builtin_amdgcn_s_setprio(0);
  }

  #pragma unroll
  for (int i=0;i<MI;i++){
    #pragma unroll
    for (int j=0;j<4;j++){
      #pragma unroll
      for (int rr=0;rr<4;rr++){
        const int row = m0 + wm + i*16 + lg*4 + rr;
        const int col = n0 + wn + j*16 + lq;
        float v = acc[i][j][rr] + bias[col];
        if (EPI == EPI_SCALEQ) v *= QSCALE;
        if (EPI == EPI_RELU)   v = fmaxf(v, 0.f);
        if (EPI == EPI_RES)    Ores[(size_t)row*N + col] += v;
        else if (EPI == EPI_FIN){
          const size_t idx = (size_t)row*N + col;
          fout[idx] = (Ores[idx] + v) * tk[row];
        }
        else if (EPI == EPI_QKV){
          // contiguous q|k|v buffers (2M u16 each). seg uniform per j.
          const int seg = col >> 9, c = col & 511;
          if (seg == 0)      Obf[(size_t)row*512 + c] = f2b(v * QSCALE);
          else if (seg == 1){
            const int bb = row >> 11, kv = row & 2047;
            const int hh = c >> 6,  dh = c & 63;
            Obf[(2u<<20) + ((((size_t)(bb*NH + hh) << 11) + kv) << 6) + (dh ^ ((kv & 7) << 3))] = f2b(v);
          }
          else               Obf[(4u<<20) + (size_t)row*512 + c] = f2b(v);
        }
        else if (EPI == EPI_KV){
          const int seg = col >> 9, c = col & 511;
          if (seg == 0){
            const int bb = row >> 11, kv = row & 2047;
            const int hh = c >> 6,  dh = c & 63;
            Obf[((((size_t)(bb*NH + hh) << 11) + kv) << 6) + (dh ^ ((kv & 7) << 3))] = f2b(v);
          }
          else               Obf[(2u<<20) + (size_t)row*512 + c] = f2b(v);
        }
        else                   Obf[(size_t)row*N + col] = f2b(v);
      }
    }
  }
}

// 64x64-tile GEMM for N=512 outputs: grid (8,64)=512 blocks = 2 blocks/CU.
// Same swizzle + prefetch loop; 4 waves of 32x32; LDS 16 KB.
template<int EPI>
__global__ __launch_bounds__(256, 4)
void gemm64(const u16* __restrict__ A, const u16* __restrict__ Bt,
            const float* __restrict__ bias,
            u16* __restrict__ Obf, float* __restrict__ Ores,
            const float* __restrict__ tk, float* __restrict__ fout,
            int K, int N)
{
  __shared__ __align__(16) u16 As[64*BK];
  __shared__ __align__(16) u16 Bs[64*BK];
  const int t  = threadIdx.x;
  const int l  = t & 63;
  const int lq = l & 15, lg = l >> 4;
  const int w  = t >> 6;
  const int wm = (w >> 1) * 32;
  const int wn = (w & 1) * 32;
  const int m0 = blockIdx.y * 64;
  const int n0 = blockIdx.x * 64;

  const int srow = t >> 3;   // 0..31
  const int scs  = t & 7;

  auto stage = [&](int k0){
    #pragma unroll
    for (int i = 0; i < 2; ++i){
      const int row = i*32 + srow;
      gload_lds16(A  + (size_t)(m0 + row)*K + k0 + ((scs ^ (row & 7)) << 3),
                  &As[row*BK + scs*8]);
      gload_lds16(Bt + (size_t)(n0 + row)*K + k0 + ((scs ^ (row & 7)) << 3),
                  &Bs[row*BK + scs*8]);
    }
  };

  f32x4 acc[2][2];
  #pragma unroll
  for (int i=0;i<2;i++)
    #pragma unroll
    for (int j=0;j<2;j++) acc[i][j] = (f32x4){0.f,0.f,0.f,0.f};

  stage(0);
  for (int k0 = 0; k0 < K; k0 += BK){
    __syncthreads();
    short8 af[2][2], bf[2][2];
    #pragma unroll
    for (int kc = 0; kc < 2; ++kc){
      #pragma unroll
      for (int i=0;i<2;i++){
        af[i][kc] = *(const short8*)&As[(wm + i*16 + lq)*BK + (((kc*4 + lg) ^ (lq & 7)) << 3)];
        bf[i][kc] = *(const short8*)&Bs[(wn + i*16 + lq)*BK + (((kc*4 + lg) ^ (lq & 7)) << 3)];
      }
    }
    __syncthreads();
    if (k0 + BK < K) stage(k0 + BK);
    __builtin_amdgcn_s_setprio(1);
    #pragma unroll
    for (int kc = 0; kc < 2; ++kc)
      #pragma unroll
      for (int i=0;i<2;i++)
        #pragma unroll
        for (int j=0;j<2;j++)
          acc[i][j] = __builtin_amdgcn_mfma_f32_16x16x32_bf16(af[i][kc], bf[j][kc], acc[i][j], 0,0,0);
    __builtin_amdgcn_s_setprio(0);
  }

  #pragma unroll
  for (int i=0;i<2;i++){
    #pragma unroll
    for (int j=0;j<2;j++){
      #pragma unroll
      for (int rr=0;rr<4;rr++){
        const int row = m0 + wm + i*16 + lg*4 + rr;
        const int col = n0 + wn + j*16 + lq;
        float v = acc[i][j][rr] + bias[col];
        if (EPI == EPI_SCALEQ) v *= QSCALE;
        if (EPI == EPI_RES)    Ores[(size_t)row*N + col] += v;
        else if (EPI == EPI_FIN){
          const size_t idx = (size_t)row*N + col;
          fout[idx] = (Ores[idx] + v) * tk[row];
        }
        else                   Obf[(size_t)row*N + col] = f2b(v);
      }
    }
  }
}

// ---------------------------------------------------------------- attention v6b
// 4 waves x 16 q-rows, KVBLK=64, cross-block KV-split x2, dbuf LDS via
// global_load_lds with baked XOR swizzle, swapped QK^T, lane-local P,
// defer-max, setprio, v_cvt_pk_bf16_f32 pack.
template<bool CAUSAL>
__global__ __launch_bounds__(256, 4)
void attn6(const u16* __restrict__ Q, const u16* __restrict__ Kbh,
           const u16* __restrict__ Vth, const float* __restrict__ bias,
           float* __restrict__ ctxp, float2* __restrict__ mlb)
{
  __shared__ __align__(16) u16 Kl[2][64*64];
  __shared__ __align__(16) u16 Vl[2][64*64];
  const int tid = threadIdx.x;
  const int l  = tid & 63;
  const int w  = tid >> 6;
  const int lq = l & 15, lg = l >> 4;
  const int h    = blockIdx.y;
  const int b    = blockIdx.z >> 1;
  const int half = blockIdx.z & 1;
  const int qtile = CAUSAL ? ((b & 1) ? (31 - (int)blockIdx.x) : (int)blockIdx.x)
                           : (int)blockIdx.x;
  const int q0w = qtile*64 + w*16;

  const u16* kg = Kbh + ((size_t)(b*NH + h) << 17);   // [2048][64]
  const u16* vg = Vth + ((size_t)(b*NH + h) << 17);   // [64][2048]

  short8 aq[2];
  #pragma unroll
  for (int kc = 0; kc < 2; ++kc)
    aq[kc] = *(const short8*)(Q + (size_t)(b*QL + q0w + lq)*DIM + h*DH + kc*32 + lg*8);

  f32x4 ctx[4];
  #pragma unroll
  for (int d = 0; d < 4; ++d) ctx[d] = (f32x4){0.f,0.f,0.f,0.f};
  f32x4 lsum4 = (f32x4){0.f,0.f,0.f,0.f};
  float m = -INFINITY;

  const int ntiles = CAUSAL ? (qtile + 1) : (KLn >> 6);

  auto stage = [&](int buf, int t){
    const int kvs = t*64;
    #pragma unroll
    for (int i = 0; i < 2; ++i){
      gload_lds16(kg + (size_t)kvs*64 + w*1024 + i*512 + l*8,
                  &Kl[buf][w*1024 + i*512 + l*8]);
      gload_lds16(vg + (size_t)(w*16 + i*8 + (l>>3))*KLn + kvs + (l&7)*8,
                  &Vl[buf][w*1024 + i*512 + l*8]);
    }
  };

  stage(0, half);
  __syncthreads();
  int cur = 0;

  for (int t = half; t < ntiles; t += 2){
    if (t + 2 < ntiles) stage(cur ^ 1, t + 2);
    const int kvs = t*64;
    // ---- QK^T (A-frag = K rows from LDS, B-frag = Q in regs)
    f32x4 s[4];
    #pragma unroll
    for (int sub = 0; sub < 4; ++sub) s[sub] = (f32x4){0.f,0.f,0.f,0.f};
    __builtin_amdgcn_s_setprio(1);
    #pragma unroll
    for (int sub = 0; sub < 4; ++sub){
      const int r = sub*16 + lq;
      #pragma unroll
      for (int kc = 0; kc < 2; ++kc){
        short8 bk = *(const short8*)&Kl[cur][r*64 + (((kc*4 + lg) ^ (r & 7)) << 3)];
        s[sub] = __builtin_amdgcn_mfma_f32_16x16x32_bf16(bk, aq[kc], s[sub], 0,0,0);
      }
    }
    __builtin_amdgcn_s_setprio(0);
    // lane holds S[kv = kvs+sub*16+lg*4+rr][q = q0w+lq]
    if (CAUSAL){
      if (kvs + 63 > q0w){
        #pragma unroll
        for (int sub = 0; sub < 4; ++sub)
          #pragma unroll
          for (int rr = 0; rr < 4; ++rr)
            if (kvs + sub*16 + lg*4 + rr > q0w + lq) s[sub][rr] = -INFINITY;
      }
    } else {
      #pragma unroll
      for (int sub = 0; sub < 4; ++sub){
        f32x4 bv = *(const f32x4*)(bias + b*KLn + kvs + sub*16 + lg*4);
        s[sub] += bv;
      }
    }
    // ---- online softmax, defer-max
    float mx[4];
    #pragma unroll
    for (int sub = 0; sub < 4; ++sub)
      mx[sub] = fmaxf(fmaxf(s[sub][0], s[sub][1]), fmaxf(s[sub][2], s[sub][3]));
    float pmax = fmaxf(fmaxf(mx[0], mx[1]), fmaxf(mx[2], mx[3]));
    if (!__all(pmax <= m + 8.0f)){
      pmax = fmaxf(pmax, __shfl_xor(pmax, 16));
      pmax = fmaxf(pmax, __shfl_xor(pmax, 32));
      const float mnew = fmaxf(m, pmax);
      const float corr = exp2f(m - mnew);
      lsum4 *= corr;
      float corr4[4];
      #pragma unroll
      for (int rr = 0; rr < 4; ++rr) corr4[rr] = __shfl(corr, lg*4 + rr);
      #pragma unroll
      for (int d = 0; d < 4; ++d)
        #pragma unroll
        for (int rr = 0; rr < 4; ++rr) ctx[d][rr] *= corr4[rr];
      m = mnew;
    }
    u32 pk[4][2];
    #pragma unroll
    for (int sub = 0; sub < 4; ++sub){
      float p0 = exp2f(s[sub][0] - m);
      float p1 = exp2f(s[sub][1] - m);
      float p2 = exp2f(s[sub][2] - m);
      float p3 = exp2f(s[sub][3] - m);
      lsum4 += (f32x4){p0, p1, p2, p3};
      pk[sub][0] = cvtpk(p0, p1);
      pk[sub][1] = cvtpk(p2, p3);
    }
    // ---- PV (A-frag = lane-local P regs, B-frag = V^T rows from LDS)
    union { u32 u[4]; short8 s8; } pa0, pa1;
    pa0.u[0] = pk[0][0]; pa0.u[1] = pk[0][1]; pa0.u[2] = pk[1][0]; pa0.u[3] = pk[1][1];
    pa1.u[0] = pk[2][0]; pa1.u[1] = pk[2][1]; pa1.u[2] = pk[3][0]; pa1.u[3] = pk[3][1];
    __builtin_amdgcn_s_setprio(1);
    #pragma unroll
    for (int d0 = 0; d0 < 4; ++d0){
      const int dl = d0*16 + lq;
      short8 v0 = *(const short8*)&Vl[cur][dl*64 + ((lg       ^ (dl & 7)) << 3)];
      short8 v1 = *(const short8*)&Vl[cur][dl*64 + (((4 + lg) ^ (dl & 7)) << 3)];
      ctx[d0] = __builtin_amdgcn_mfma_f32_16x16x32_bf16(pa0.s8, v0, ctx[d0], 0,0,0);
      ctx[d0] = __builtin_amdgcn_mfma_f32_16x16x32_bf16(pa1.s8, v1, ctx[d0], 0,0,0);
    }
    __builtin_amdgcn_s_setprio(0);
    __syncthreads();   // drains vmcnt(0): prefetch landed; buffers safe to swap
    cur ^= 1;
  }

  // ---- write partials (no normalization here; merge kernel does it)
  float hs = (lsum4[0] + lsum4[1]) + (lsum4[2] + lsum4[3]);
  hs += __shfl_xor(hs, 16);
  hs += __shfl_xor(hs, 32);
  if (lg == 0)
    mlb[((size_t)((half*NB + b)*NH + h) << 11) + q0w + lq] = make_float2(m, hs);
  float* cp = ctxp + (size_t)half*MROWS*DIM;
  #pragma unroll
  for (int d0 = 0; d0 < 4; ++d0)
    #pragma unroll
    for (int rr = 0; rr < 4; ++rr)
      cp[(size_t)(b*QL + q0w + lg*4 + rr)*DIM + h*DH + d0*16 + lq] = ctx[d0][rr];
}

// merge the two KV-half partials: out = sum(ctx_k*w_k)/sum(l_k*w_k), w_k=exp2(m_k-mg)
__global__ __launch_bounds__(256)
void attn_merge(const float* __restrict__ ctxp, const float2* __restrict__ mlb,
                u16* __restrict__ O)
{
  const int idx = blockIdx.x*256 + threadIdx.x;
  const int row = idx >> 7;          // 0..4095
  const int col = (idx & 127) * 4;   // 0..508
  const int b = row >> 11, qr = row & 2047, h = col >> 6;
  const float2 a0 = mlb[((size_t)((      b)*NH + h) << 11) + qr];
  const float2 a1 = mlb[((size_t)((NB  + b)*NH + h) << 11) + qr];
  const float mg = fmaxf(a0.x, a1.x);
  const float w0 = exp2f(a0.x - mg), w1 = exp2f(a1.x - mg);
  const float rden = 1.f / (a0.y*w0 + a1.y*w1);
  const f32x4 c0 = *(const f32x4*)&ctxp[(size_t)row*DIM + col];
  const f32x4 c1 = *(const f32x4*)&ctxp[(size_t)MROWS*DIM + (size_t)row*DIM + col];
  u16 o[4];
  #pragma unroll
  for (int i = 0; i < 4; ++i) o[i] = f2b((c0[i]*w0 + c1[i]*w1) * rden);
  *(uint2*)&O[(size_t)row*DIM + col] = *(const uint2*)o;
}

// ---------------------------------------------------------------- layernorm
template<int MODE>
__global__ __launch_bounds__(128)
void ln_kernel(const float* __restrict__ in0, const float* __restrict__ in1,
               const float* __restrict__ tkpm,
               const float* __restrict__ g, const float* __restrict__ bvec,
               float* __restrict__ xres, u16* __restrict__ outb)
{
  const int row = blockIdx.x;
  const int t = threadIdx.x;
  float v[4];
  #pragma unroll
  for (int i = 0; i < 4; ++i){
    const int c = t + i*128;
    float x = in0[(size_t)row*DIM + c];
    if (MODE == 0){
      x += in1[(size_t)row*DIM + c];
      xres[(size_t)row*DIM + c] = x;
    }
    v[i] = x;
  }
  float s = v[0]+v[1]+v[2]+v[3];
  #pragma unroll
  for (int off = 1; off < 64; off <<= 1) s += __shfl_xor(s, off);
  __shared__ float red[4];
  if ((t & 63) == 0) red[t >> 6] = s;
  __syncthreads();
  const float mean = (red[0] + red[1]) * (1.f/512.f);
  float q = 0.f;
  #pragma unroll
  for (int i = 0; i < 4; ++i){ const float d = v[i]-mean; q += d*d; }
  #pragma unroll
  for (int off = 1; off < 64; off <<= 1) q += __shfl_xor(q, off);
  if ((t & 63) == 0) red[2 + (t >> 6)] = q;
  __syncthreads();
  const float var = (red[2] + red[3]) * (1.f/512.f);
  const float rs = rsqrtf(var + 1e-5f);
  const float tk = (MODE == 0) ? tkpm[row] : 1.f;
  #pragma unroll
  for (int i = 0; i < 4; ++i){
    const int c = t + i*128;
    const float y = (v[i] - mean) * rs * g[c] + bvec[c];
    outb[(size_t)row*DIM + c] = f2b(y * tk);
  }
}

// ---------------------------------------------------------------- transposes / misc
__global__ __launch_bounds__(256)
void transpose_f2b(const float* __restrict__ in, u16* __restrict__ out, int R, int C)
{
  __shared__ float tile[32][33];
  const int tx = threadIdx.x, ty = threadIdx.y;
  const int r0 = blockIdx.y*32, c0 = blockIdx.x*32;
  #pragma unroll
  for (int i = 0; i < 4; ++i)
    tile[ty + i*8][tx] = in[(size_t)(r0 + ty + i*8)*C + c0 + tx];
  __syncthreads();
  #pragma unroll
  for (int i = 0; i < 4; ++i)
    out[(size_t)(c0 + ty + i*8)*R + r0 + tx] = f2b(tile[tx][ty + i*8]);
}

__global__ __launch_bounds__(256)
void transpose8_f2b(const float* w0, const float* w1, const float* w2, const float* w3,
                    const float* w4, const float* w5, const float* w6, const float* w7,
                    u16* __restrict__ out)
{
  __shared__ float tile[32][33];
  const float* wp[8] = {w0,w1,w2,w3,w4,w5,w6,w7};
  const float* w = wp[blockIdx.z];
  u16* o = out + (size_t)blockIdx.z * 512 * 512;
  const int tx = threadIdx.x, ty = threadIdx.y;
  const int r0 = blockIdx.y*32, c0 = blockIdx.x*32;
  #pragma unroll
  for (int i = 0; i < 4; ++i)
    tile[ty + i*8][tx] = w[(size_t)(r0 + ty + i*8)*512 + c0 + tx];
  __syncthreads();
  #pragma unroll
  for (int i = 0; i < 4; ++i)
    o[(size_t)(c0 + ty + i*8)*512 + r0 + tx] = f2b(tile[tx][ty + i*8]);
}

// V [b][kv][512] -> Vth [b][h][dh][kv'] with PV K-slot permutation AND
// bank XOR-swizzle (chunk ^= dh&7) folded into the kv index.
__global__ __launch_bounds__(256)
void transpose_vperm(const u16* __restrict__ in, u16* __restrict__ out)
{
  __shared__ u16 tile[32][33];
  in  += (size_t)blockIdx.z * KLn * DIM;
  out += (size_t)blockIdx.z * NH * DH * KLn;
  const int tx = threadIdx.x, ty = threadIdx.y;
  const int r0 = blockIdx.y*32, c0 = blockIdx.x*32;   // r=kv, c=dcol
  #pragma unroll
  for (int i = 0; i < 4; ++i)
    tile[ty + i*8][tx] = in[(size_t)(r0 + ty + i*8)*DIM + c0 + tx];
  __syncthreads();
  const int kv = r0 + tx;
  const int s  = (kv & ~31) | (((kv>>2)&3)<<3) | (((kv>>4)&1)<<2) | (kv&3);
  #pragma unroll
  for (int i = 0; i < 4; ++i){
    const int dcol = c0 + ty + i*8;
    const int hh = dcol >> 6, dh = dcol & 63;
    const int kvpos = (s & ~63) | (((((s>>3)&7) ^ (dh&7)) << 3)) | (s & 7);
    out[((size_t)(hh*DH + dh))*KLn + kvpos] = tile[tx][ty + i*8];
  }
}

__global__ void cvt_f2b(const float* __restrict__ in, u16* __restrict__ out, int n){
  const int i = blockIdx.x*blockDim.x + threadIdx.x;
  if (i < n) out[i] = f2b(in[i]);
}

// fused prep: cross-attn mask bias + qkv/kv bias concats
__global__ void prep_k(const int* __restrict__ mkpm,
                       const float* saqb, const float* sakb, const float* savb,
                       const float* cakb, const float* cavb,
                       float* __restrict__ bias, float* __restrict__ bc0,
                       float* __restrict__ bc1)
{
  const int i = blockIdx.x*256 + threadIdx.x;   // 0..4095
  bias[i] = mkpm[i] ? 0.f : -1e30f;
  if (i < 1536) bc0[i] = (i < 512) ? saqb[i] : (i < 1024) ? sakb[i-512] : savb[i-1024];
  if (i < 1024) bc1[i] = (i < 512) ? cakb[i] : cavb[i-512];
}

// ---------------------------------------------------------------- launch
extern "C" void kernel_launch(void* const* d_in, const int* in_sizes, int n_in,
                              void* d_out, int out_size, void* d_ws, size_t ws_size,
                              hipStream_t stream)
{
  const float* tgt  = (const float*)d_in[1];
  const float* mem  = (const float*)d_in[2];
  const float* pos  = (const float*)d_in[3];
  const float* tkpm = (const float*)d_in[5];
  const int*   mkpm = (const int*)d_in[6];
  const float* saqb = (const float*)d_in[8];
  const float* sakb = (const float*)d_in[10];
  const float* savb = (const float*)d_in[12];
  const float* saow = (const float*)d_in[13]; const float* saob = (const float*)d_in[14];
  const float* caqb = (const float*)d_in[16];
  const float* cakb = (const float*)d_in[18];
  const float* cavb = (const float*)d_in[20];
  const float* caob = (const float*)d_in[22];
  const float* saqw = (const float*)d_in[7];
  const float* sakw = (const float*)d_in[9];
  const float* savw = (const float*)d_in[11];
  const float* caqw = (const float*)d_in[15];
  const float* cakw = (const float*)d_in[17];
  const float* cavw = (const float*)d_in[19];
  const float* caow = (const float*)d_in[21];
  const float* l1w  = (const float*)d_in[23]; const float* l1b  = (const float*)d_in[24];
  const float* l2w  = (const float*)d_in[25]; const float* l2b  = (const float*)d_in[26];
  const float* n1g  = (const float*)d_in[27]; const float* n1b  = (const float*)d_in[28];
  const float* n2g  = (const float*)d_in[29]; const float* n2b  = (const float*)d_in[30];
  const float* n3g  = (const float*)d_in[31]; const float* n3b  = (const float*)d_in[32];

  if (ws_size < 58720256) return;  // 56 MB scratch

  char* ws = (char*)d_ws;
  float* xres = (float*)(ws);                      // 8 MB  f32 residual
  u16* t2n    = (u16*)(ws + (8u<<20));             // 4 MB  LN out / attn out (aliased)
  u16* qb     = (u16*)(ws + (12u<<20));            // 4 MB  | contiguous q|k|v
  u16* kb     = (u16*)(ws + (16u<<20));            // 4 MB  | head-major swizzled K
  u16* vb     = (u16*)(ws + (20u<<20));            // 4 MB  | (later reused for FF weightT)
  u16* vt     = (u16*)(ws + (24u<<20));            // 4 MB  head-major swizzled V^T
  float* bias = (float*)(ws + (28u<<20));          // 16 KB cross-attn additive mask
  float* bc0  = (float*)(ws + (29u<<20));          // 6 KB  qkv bias concat
  float* bc1  = (float*)(ws + (29u<<20) + 8192);   // 4 KB  kv bias concat
  float2* mlb = (float2*)(ws + (30u<<20));         // 512 KB attn (m,l) partials
  u16* memb   = (u16*)(ws + (32u<<20));            // 4 MB  memory in bf16
  float* ctxp = (float*)(ws + (36u<<20));          // 16 MB attn ctx partials (2 halves)
  u16* ffh    = (u16*)(ws + (36u<<20));            // 16 MB FF hidden (reuses ctxp region)
  u16* wtA    = (u16*)(ws + (52u<<20));            // 4 MB  8x 512x512 attn weightT (stacked)
  u16* l1wt   = vb;                                // 2 MB  (after cross vperm)
  u16* l2wt   = (u16*)(ws + (22u<<20));            // 2 MB

  float* out = (float*)d_out;
  const int W55 = 512*512;

  prep_k<<<dim3(16), 256, 0, stream>>>(mkpm, saqb, sakb, savb, cakb, cavb, bias, bc0, bc1);
  cvt_f2b<<<dim3(MROWS*DIM/256), 256, 0, stream>>>(mem, memb, MROWS*DIM);
  ln_kernel<0><<<MROWS, 128, 0, stream>>>(tgt, pos, tkpm, n1g, n1b, xres, t2n);
  transpose8_f2b<<<dim3(16,16,8), dim3(32,8), 0, stream>>>(saqw, sakw, savw, saow,
                                                           caqw, cakw, cavw, caow, wtA);

  #define G44(EP)  gemm64<EP> <<<dim3(8,64),  256, 0, stream>>>
  #define G128(EP, NB128) gemm_bt<EP,128><<<dim3(NB128,32), 256, 0, stream>>>

  // ---- self attention (fused QKV: N=1536, wtA rows 0..1535 are Wq|Wk|Wv ^T)
  G128(EPI_QKV, 12)(t2n, wtA, bc0, qb, nullptr, nullptr, nullptr, 512, 1536);
  transpose_vperm<<<dim3(DIM/32, KLn/32, NB), dim3(32,8), 0, stream>>>(vb, vt);
  attn6<true><<<dim3(QL/64, NH, NB*2), 256, 0, stream>>>(qb, kb, vt, nullptr, ctxp, mlb);
  attn_merge<<<dim3(MROWS*DIM/1024), 256, 0, stream>>>(ctxp, mlb, t2n);
  G44(EPI_RES)   (t2n, wtA + 3*W55, saob, nullptr, xres, nullptr, nullptr, 512, 512);

  ln_kernel<1><<<MROWS, 128, 0, stream>>>(xres, nullptr, nullptr, n2g, n2b, nullptr, t2n);

  // ---- cross attention (fused KV: N=1024)
  G44(EPI_SCALEQ)(t2n,  wtA + 4*W55, caqb, qb, nullptr, nullptr, nullptr, 512, 512);
  G128(EPI_KV, 8)(memb, wtA + 5*W55, bc1, kb, nullptr, nullptr, nullptr, 512, 1024);
  transpose_vperm<<<dim3(DIM/32, KLn/32, NB), dim3(32,8), 0, stream>>>(vb, vt);
  transpose_f2b<<<dim3(FFD/32, 512/32), dim3(32,8), 0, stream>>>(l1w, l1wt, 512, FFD);
  transpose_f2b<<<dim3(512/32, FFD/32), dim3(32,8), 0, stream>>>(l2w, l2wt, FFD, 512);
  attn6<false><<<dim3(QL/64, NH, NB*2), 256, 0, stream>>>(qb, kb, vt, bias, ctxp, mlb);
  attn_merge<<<dim3(MROWS*DIM/1024), 256, 0, stream>>>(ctxp, mlb, t2n);
  G44(EPI_RES)   (t2n, wtA + 7*W55, caob, nullptr, xres, nullptr, nullptr, 512, 512);

  ln_kernel<1><<<MROWS, 128, 0, stream>>>(xres, nullptr, nullptr, n3g, n3b, nullptr, t2n);

  // ---- feed-forward (FF2 epilogue fuses residual add + tkpm scale + f32 out)
  G128(EPI_RELU, 16)(t2n, l1wt, l1b, ffh, nullptr, nullptr, nullptr, 512, FFD);
  G44(EPI_FIN)  (ffh, l2wt, l2b, nullptr, xres, tkpm, out, FFD, 512);

  #undef G44
  #undef G128
}

// Round 10
// 194.046 us; speedup vs baseline: 2.7975x; 1.1681x over previous
//
#include <hip/hip_runtime.h>
#include <hip/hip_bf16.h>
#include <stdint.h>

#define QL   2048
#define KLn  2048
#define DIM  512
#define NH   8
#define DH   64
#define NB   2
#define MROWS (NB*QL)   // 4096
#define FFD  2048

typedef unsigned short u16;
typedef unsigned int u32;
typedef __attribute__((ext_vector_type(8))) short short8;
typedef __attribute__((ext_vector_type(4))) float f32x4;

__device__ __forceinline__ u16 f2b(float f){
  union { float f; u32 i; } v; v.f = f;
  u32 r = v.i + 0x7FFFu + ((v.i >> 16) & 1u);
  return (u16)(r >> 16);
}
__device__ __forceinline__ float b2f(u16 u){
  union { u32 i; float f; } v; v.i = ((u32)u) << 16; return v.f;
}
// two f32 -> packed bf16x2 in one instruction (lo=a, hi=b, RNE)
__device__ __forceinline__ u32 cvtpk(float a, float b){
  u32 r;
  asm("v_cvt_pk_bf16_f32 %0, %1, %2" : "=v"(r) : "v"(a), "v"(b));
  return r;
}

typedef __attribute__((address_space(3))) void as3void;
typedef __attribute__((address_space(1))) void as1void;
__device__ __forceinline__ void gload_lds16(const void* g, void* l){
  __builtin_amdgcn_global_load_lds((as1void*)g, (as3void*)l, 16, 0, 0);
}

// ---------------------------------------------------------------- GEMM (64x64)
// All GEMMs: 64x64 tiles, 4 waves of 32x32, BK=64, chunk-XOR bank swizzle
// (both-sides involution), prefetch single-buffer loop, and a chunked
// XCD-aware block swizzle (T1): consecutive ids land on one XCD covering a
// 512-row A-panel (2 MB, L2-resident) -- critical for FF2's K=2048 16MB A.
#define BK 64
enum { EPI_BIAS=0, EPI_SCALEQ=1, EPI_RELU=2, EPI_RES=3, EPI_FIN=5, EPI_QKV=6, EPI_KV=7 };
// 1/sqrt(64) * log2(e): folds softmax exp->exp2 conversion into Q scale
#define QSCALE 0.1803368801111244f

template<int EPI>
__global__ __launch_bounds__(256, 4)
void gemm64(const u16* __restrict__ A, const u16* __restrict__ Bt,
            const float* __restrict__ bias,
            u16* __restrict__ Obf, float* __restrict__ Ores,
            const float* __restrict__ tk, float* __restrict__ fout,
            int K, int N)
{
  __shared__ __align__(16) u16 As[64*BK];
  __shared__ __align__(16) u16 Bs[64*BK];
  const int t  = threadIdx.x;
  const int l  = t & 63;
  const int lq = l & 15, lg = l >> 4;
  const int w  = t >> 6;
  const int wm = (w >> 1) * 32;
  const int wn = (w & 1) * 32;

  // XCD-chunked swizzle (all our grids have nwg % 8 == 0)
  const int gx   = gridDim.x;
  const int nwg  = gx * gridDim.y;
  const int orig = blockIdx.x + gx * blockIdx.y;
  const int wgid = (orig & 7) * (nwg >> 3) + (orig >> 3);
  const int m0 = (wgid / gx) * 64;
  const int n0 = (wgid % gx) * 64;

  const int srow = t >> 3;   // 0..31
  const int scs  = t & 7;

  auto stage = [&](int k0){
    #pragma unroll
    for (int i = 0; i < 2; ++i){
      const int row = i*32 + srow;
      gload_lds16(A  + (size_t)(m0 + row)*K + k0 + ((scs ^ (row & 7)) << 3),
                  &As[row*BK + scs*8]);
      gload_lds16(Bt + (size_t)(n0 + row)*K + k0 + ((scs ^ (row & 7)) << 3),
                  &Bs[row*BK + scs*8]);
    }
  };

  f32x4 acc[2][2];
  #pragma unroll
  for (int i=0;i<2;i++)
    #pragma unroll
    for (int j=0;j<2;j++) acc[i][j] = (f32x4){0.f,0.f,0.f,0.f};

  stage(0);
  for (int k0 = 0; k0 < K; k0 += BK){
    __syncthreads();                     // staged data visible (drains vmcnt)
    short8 af[2][2], bf[2][2];
    #pragma unroll
    for (int kc = 0; kc < 2; ++kc){
      #pragma unroll
      for (int i=0;i<2;i++){
        af[i][kc] = *(const short8*)&As[(wm + i*16 + lq)*BK + (((kc*4 + lg) ^ (lq & 7)) << 3)];
        bf[i][kc] = *(const short8*)&Bs[(wn + i*16 + lq)*BK + (((kc*4 + lg) ^ (lq & 7)) << 3)];
      }
    }
    __syncthreads();                     // all waves done reading LDS
    if (k0 + BK < K) stage(k0 + BK);     // async staging overlaps MFMA
    __builtin_amdgcn_s_setprio(1);
    #pragma unroll
    for (int kc = 0; kc < 2; ++kc)
      #pragma unroll
      for (int i=0;i<2;i++)
        #pragma unroll
        for (int j=0;j<2;j++)
          acc[i][j] = __builtin_amdgcn_mfma_f32_16x16x32_bf16(af[i][kc], bf[j][kc], acc[i][j], 0,0,0);
    __builtin_amdgcn_s_setprio(0);
  }

  #pragma unroll
  for (int i=0;i<2;i++){
    #pragma unroll
    for (int j=0;j<2;j++){
      #pragma unroll
      for (int rr=0;rr<4;rr++){
        const int row = m0 + wm + i*16 + lg*4 + rr;
        const int col = n0 + wn + j*16 + lq;
        float v = acc[i][j][rr] + bias[col];
        if (EPI == EPI_SCALEQ) v *= QSCALE;
        if (EPI == EPI_RELU)   v = fmaxf(v, 0.f);
        if (EPI == EPI_RES)    Ores[(size_t)row*N + col] += v;
        else if (EPI == EPI_FIN){
          const size_t idx = (size_t)row*N + col;
          fout[idx] = (Ores[idx] + v) * tk[row];
        }
        else if (EPI == EPI_QKV){
          // contiguous q|k|v buffers (2M u16 each). seg uniform per block.
          const int seg = col >> 9, c = col & 511;
          if (seg == 0)      Obf[(size_t)row*512 + c] = f2b(v * QSCALE);
          else if (seg == 1){
            const int bb = row >> 11, kv = row & 2047;
            const int hh = c >> 6,  dh = c & 63;
            Obf[(2u<<20) + ((((size_t)(bb*NH + hh) << 11) + kv) << 6) + (dh ^ ((kv & 7) << 3))] = f2b(v);
          }
          else               Obf[(4u<<20) + (size_t)row*512 + c] = f2b(v);
        }
        else if (EPI == EPI_KV){
          const int seg = col >> 9, c = col & 511;
          if (seg == 0){
            const int bb = row >> 11, kv = row & 2047;
            const int hh = c >> 6,  dh = c & 63;
            Obf[((((size_t)(bb*NH + hh) << 11) + kv) << 6) + (dh ^ ((kv & 7) << 3))] = f2b(v);
          }
          else               Obf[(2u<<20) + (size_t)row*512 + c] = f2b(v);
        }
        else                   Obf[(size_t)row*N + col] = f2b(v);
      }
    }
  }
}

// ---------------------------------------------------------------- attention v6c
// 4 waves x 16 q-rows, KVBLK=64, cross-block KV-split x2, dbuf LDS via
// global_load_lds with baked XOR swizzle, swapped QK^T, lane-local P,
// defer-max, setprio, cvt_pk pack. Partials now bf16 (halves merge traffic).
template<bool CAUSAL>
__global__ __launch_bounds__(256, 4)
void attn6(const u16* __restrict__ Q, const u16* __restrict__ Kbh,
           const u16* __restrict__ Vth, const float* __restrict__ bias,
           u16* __restrict__ ctxp, float2* __restrict__ mlb)
{
  __shared__ __align__(16) u16 Kl[2][64*64];
  __shared__ __align__(16) u16 Vl[2][64*64];
  const int tid = threadIdx.x;
  const int l  = tid & 63;
  const int w  = tid >> 6;
  const int lq = l & 15, lg = l >> 4;
  const int h    = blockIdx.y;
  const int b    = blockIdx.z >> 1;
  const int half = blockIdx.z & 1;
  const int qtile = CAUSAL ? ((b & 1) ? (31 - (int)blockIdx.x) : (int)blockIdx.x)
                           : (int)blockIdx.x;
  const int q0w = qtile*64 + w*16;

  const u16* kg = Kbh + ((size_t)(b*NH + h) << 17);   // [2048][64]
  const u16* vg = Vth + ((size_t)(b*NH + h) << 17);   // [64][2048]

  short8 aq[2];
  #pragma unroll
  for (int kc = 0; kc < 2; ++kc)
    aq[kc] = *(const short8*)(Q + (size_t)(b*QL + q0w + lq)*DIM + h*DH + kc*32 + lg*8);

  f32x4 ctx[4];
  #pragma unroll
  for (int d = 0; d < 4; ++d) ctx[d] = (f32x4){0.f,0.f,0.f,0.f};
  f32x4 lsum4 = (f32x4){0.f,0.f,0.f,0.f};
  float m = -INFINITY;

  const int ntiles = CAUSAL ? (qtile + 1) : (KLn >> 6);

  auto stage = [&](int buf, int t){
    const int kvs = t*64;
    #pragma unroll
    for (int i = 0; i < 2; ++i){
      gload_lds16(kg + (size_t)kvs*64 + w*1024 + i*512 + l*8,
                  &Kl[buf][w*1024 + i*512 + l*8]);
      gload_lds16(vg + (size_t)(w*16 + i*8 + (l>>3))*KLn + kvs + (l&7)*8,
                  &Vl[buf][w*1024 + i*512 + l*8]);
    }
  };

  stage(0, half);
  __syncthreads();
  int cur = 0;

  for (int t = half; t < ntiles; t += 2){
    if (t + 2 < ntiles) stage(cur ^ 1, t + 2);
    const int kvs = t*64;
    // ---- QK^T (A-frag = K rows from LDS, B-frag = Q in regs)
    f32x4 s[4];
    #pragma unroll
    for (int sub = 0; sub < 4; ++sub) s[sub] = (f32x4){0.f,0.f,0.f,0.f};
    __builtin_amdgcn_s_setprio(1);
    #pragma unroll
    for (int sub = 0; sub < 4; ++sub){
      const int r = sub*16 + lq;
      #pragma unroll
      for (int kc = 0; kc < 2; ++kc){
        short8 bk = *(const short8*)&Kl[cur][r*64 + (((kc*4 + lg) ^ (r & 7)) << 3)];
        s[sub] = __builtin_amdgcn_mfma_f32_16x16x32_bf16(bk, aq[kc], s[sub], 0,0,0);
      }
    }
    __builtin_amdgcn_s_setprio(0);
    // lane holds S[kv = kvs+sub*16+lg*4+rr][q = q0w+lq]
    if (CAUSAL){
      if (kvs + 63 > q0w){
        #pragma unroll
        for (int sub = 0; sub < 4; ++sub)
          #pragma unroll
          for (int rr = 0; rr < 4; ++rr)
            if (kvs + sub*16 + lg*4 + rr > q0w + lq) s[sub][rr] = -INFINITY;
      }
    } else {
      #pragma unroll
      for (int sub = 0; sub < 4; ++sub){
        f32x4 bv = *(const f32x4*)(bias + b*KLn + kvs + sub*16 + lg*4);
        s[sub] += bv;
      }
    }
    // ---- online softmax, defer-max
    float mx[4];
    #pragma unroll
    for (int sub = 0; sub < 4; ++sub)
      mx[sub] = fmaxf(fmaxf(s[sub][0], s[sub][1]), fmaxf(s[sub][2], s[sub][3]));
    float pmax = fmaxf(fmaxf(mx[0], mx[1]), fmaxf(mx[2], mx[3]));
    if (!__all(pmax <= m + 8.0f)){
      pmax = fmaxf(pmax, __shfl_xor(pmax, 16));
      pmax = fmaxf(pmax, __shfl_xor(pmax, 32));
      const float mnew = fmaxf(m, pmax);
      const float corr = exp2f(m - mnew);
      lsum4 *= corr;
      float corr4[4];
      #pragma unroll
      for (int rr = 0; rr < 4; ++rr) corr4[rr] = __shfl(corr, lg*4 + rr);
      #pragma unroll
      for (int d = 0; d < 4; ++d)
        #pragma unroll
        for (int rr = 0; rr < 4; ++rr) ctx[d][rr] *= corr4[rr];
      m = mnew;
    }
    u32 pk[4][2];
    #pragma unroll
    for (int sub = 0; sub < 4; ++sub){
      float p0 = exp2f(s[sub][0] - m);
      float p1 = exp2f(s[sub][1] - m);
      float p2 = exp2f(s[sub][2] - m);
      float p3 = exp2f(s[sub][3] - m);
      lsum4 += (f32x4){p0, p1, p2, p3};
      pk[sub][0] = cvtpk(p0, p1);
      pk[sub][1] = cvtpk(p2, p3);
    }
    // ---- PV (A-frag = lane-local P regs, B-frag = V^T rows from LDS)
    union { u32 u[4]; short8 s8; } pa0, pa1;
    pa0.u[0] = pk[0][0]; pa0.u[1] = pk[0][1]; pa0.u[2] = pk[1][0]; pa0.u[3] = pk[1][1];
    pa1.u[0] = pk[2][0]; pa1.u[1] = pk[2][1]; pa1.u[2] = pk[3][0]; pa1.u[3] = pk[3][1];
    __builtin_amdgcn_s_setprio(1);
    #pragma unroll
    for (int d0 = 0; d0 < 4; ++d0){
      const int dl = d0*16 + lq;
      short8 v0 = *(const short8*)&Vl[cur][dl*64 + ((lg       ^ (dl & 7)) << 3)];
      short8 v1 = *(const short8*)&Vl[cur][dl*64 + (((4 + lg) ^ (dl & 7)) << 3)];
      ctx[d0] = __builtin_amdgcn_mfma_f32_16x16x32_bf16(pa0.s8, v0, ctx[d0], 0,0,0);
      ctx[d0] = __builtin_amdgcn_mfma_f32_16x16x32_bf16(pa1.s8, v1, ctx[d0], 0,0,0);
    }
    __builtin_amdgcn_s_setprio(0);
    __syncthreads();   // drains vmcnt(0): prefetch landed; buffers safe to swap
    cur ^= 1;
  }

  // ---- write bf16 partials (merge kernel normalizes)
  float hs = (lsum4[0] + lsum4[1]) + (lsum4[2] + lsum4[3]);
  hs += __shfl_xor(hs, 16);
  hs += __shfl_xor(hs, 32);
  if (lg == 0)
    mlb[((size_t)((half*NB + b)*NH + h) << 11) + q0w + lq] = make_float2(m, hs);
  u16* cp = ctxp + (size_t)half*MROWS*DIM;
  #pragma unroll
  for (int d0 = 0; d0 < 4; ++d0)
    #pragma unroll
    for (int rr = 0; rr < 4; ++rr)
      cp[(size_t)(b*QL + q0w + lg*4 + rr)*DIM + h*DH + d0*16 + lq] = f2b(ctx[d0][rr]);
}

// merge the two KV-half partials: out = sum(ctx_k*w_k)/sum(l_k*w_k)
__global__ __launch_bounds__(256)
void attn_merge(const u16* __restrict__ ctxp, const float2* __restrict__ mlb,
                u16* __restrict__ O)
{
  const int idx = blockIdx.x*256 + threadIdx.x;
  const int row = idx >> 7;          // 0..4095
  const int col = (idx & 127) * 4;   // 0..508
  const int b = row >> 11, qr = row & 2047, h = col >> 6;
  const float2 a0 = mlb[((size_t)((      b)*NH + h) << 11) + qr];
  const float2 a1 = mlb[((size_t)((NB  + b)*NH + h) << 11) + qr];
  const float mg = fmaxf(a0.x, a1.x);
  const float w0 = exp2f(a0.x - mg), w1 = exp2f(a1.x - mg);
  const float rden = 1.f / (a0.y*w0 + a1.y*w1);
  union { uint2 v; u16 h4[4]; } c0u, c1u;
  c0u.v = *(const uint2*)&ctxp[(size_t)row*DIM + col];
  c1u.v = *(const uint2*)&ctxp[(size_t)MROWS*DIM + (size_t)row*DIM + col];
  u16 o[4];
  #pragma unroll
  for (int i = 0; i < 4; ++i)
    o[i] = f2b((b2f(c0u.h4[i])*w0 + b2f(c1u.h4[i])*w1) * rden);
  *(uint2*)&O[(size_t)row*DIM + col] = *(const uint2*)o;
}

// ---------------------------------------------------------------- layernorm
template<int MODE>
__global__ __launch_bounds__(128)
void ln_kernel(const float* __restrict__ in0, const float* __restrict__ in1,
               const float* __restrict__ tkpm,
               const float* __restrict__ g, const float* __restrict__ bvec,
               float* __restrict__ xres, u16* __restrict__ outb)
{
  const int row = blockIdx.x;
  const int t = threadIdx.x;
  float v[4];
  #pragma unroll
  for (int i = 0; i < 4; ++i){
    const int c = t + i*128;
    float x = in0[(size_t)row*DIM + c];
    if (MODE == 0){
      x += in1[(size_t)row*DIM + c];
      xres[(size_t)row*DIM + c] = x;
    }
    v[i] = x;
  }
  float s = v[0]+v[1]+v[2]+v[3];
  #pragma unroll
  for (int off = 1; off < 64; off <<= 1) s += __shfl_xor(s, off);
  __shared__ float red[4];
  if ((t & 63) == 0) red[t >> 6] = s;
  __syncthreads();
  const float mean = (red[0] + red[1]) * (1.f/512.f);
  float q = 0.f;
  #pragma unroll
  for (int i = 0; i < 4; ++i){ const float d = v[i]-mean; q += d*d; }
  #pragma unroll
  for (int off = 1; off < 64; off <<= 1) q += __shfl_xor(q, off);
  if ((t & 63) == 0) red[2 + (t >> 6)] = q;
  __syncthreads();
  const float var = (red[2] + red[3]) * (1.f/512.f);
  const float rs = rsqrtf(var + 1e-5f);
  const float tk = (MODE == 0) ? tkpm[row] : 1.f;
  #pragma unroll
  for (int i = 0; i < 4; ++i){
    const int c = t + i*128;
    const float y = (v[i] - mean) * rs * g[c] + bvec[c];
    outb[(size_t)row*DIM + c] = f2b(y * tk);
  }
}

// ---------------------------------------------------------------- fused prep
// One launch for: 8x weight transpose (blocks 0..2047), memory f32->bf16
// (2048..4095), mask-bias + bias concats (4096..4111).
__global__ __launch_bounds__(256)
void prep_all(const float* w0, const float* w1, const float* w2, const float* w3,
              const float* w4, const float* w5, const float* w6, const float* w7,
              const float* __restrict__ mem, const int* __restrict__ mkpm,
              const float* saqb, const float* sakb, const float* savb,
              const float* cakb, const float* cavb,
              u16* __restrict__ wtA, u16* __restrict__ memb,
              float* __restrict__ bias, float* __restrict__ bc0,
              float* __restrict__ bc1)
{
  __shared__ float tile[32][33];
  const int id = blockIdx.x;
  const int tid = threadIdx.x;
  if (id < 2048){
    const int z = id >> 8, rem = id & 255;
    const int r0 = (rem >> 4) * 32, c0 = (rem & 15) * 32;
    const float* wp[8] = {w0,w1,w2,w3,w4,w5,w6,w7};
    const float* w = wp[z];
    u16* o = wtA + (size_t)z * 512 * 512;
    const int tx = tid & 31, ty = tid >> 5;
    #pragma unroll
    for (int i = 0; i < 4; ++i)
      tile[ty + i*8][tx] = w[(size_t)(r0 + ty + i*8)*512 + c0 + tx];
    __syncthreads();
    #pragma unroll
    for (int i = 0; i < 4; ++i)
      o[(size_t)(c0 + ty + i*8)*512 + r0 + tx] = f2b(tile[tx][ty + i*8]);
  } else if (id < 4096){
    const int i = (id - 2048)*1024 + tid*4;
    f32x4 v = *(const f32x4*)&mem[i];
    uint2 p; p.x = cvtpk(v[0], v[1]); p.y = cvtpk(v[2], v[3]);
    *(uint2*)&memb[i] = p;
  } else {
    const int j = (id - 4096)*256 + tid;   // 0..4095
    bias[j] = mkpm[j] ? 0.f : -1e30f;
    if (j < 1536) bc0[j] = (j < 512) ? saqb[j] : (j < 1024) ? sakb[j-512] : savb[j-1024];
    if (j < 1024) bc1[j] = (j < 512) ? cakb[j] : cavb[j-512];
  }
}

// V [b][kv][512] -> Vth [b][h][dh][kv'] with PV K-slot permutation AND
// bank XOR-swizzle folded into the kv index. (standalone, self-attn side)
__global__ __launch_bounds__(256)
void transpose_vperm(const u16* __restrict__ in, u16* __restrict__ out)
{
  __shared__ u16 tile[32][33];
  in  += (size_t)blockIdx.z * KLn * DIM;
  out += (size_t)blockIdx.z * NH * DH * KLn;
  const int tx = threadIdx.x, ty = threadIdx.y;
  const int r0 = blockIdx.y*32, c0 = blockIdx.x*32;   // r=kv, c=dcol
  #pragma unroll
  for (int i = 0; i < 4; ++i)
    tile[ty + i*8][tx] = in[(size_t)(r0 + ty + i*8)*DIM + c0 + tx];
  __syncthreads();
  const int kv = r0 + tx;
  const int s  = (kv & ~31) | (((kv>>2)&3)<<3) | (((kv>>4)&1)<<2) | (kv&3);
  #pragma unroll
  for (int i = 0; i < 4; ++i){
    const int dcol = c0 + ty + i*8;
    const int hh = dcol >> 6, dh = dcol & 63;
    const int kvpos = (s & ~63) | (((((s>>3)&7) ^ (dh&7)) << 3)) | (s & 7);
    out[((size_t)(hh*DH + dh))*KLn + kvpos] = tile[tx][ty + i*8];
  }
}

// Cross-side fused: V perm-transpose (blocks 0..2047) + l1w^T (2048..3071)
// + l2w^T (3072..4095). l1wt/l2wt live in non-aliasing regions.
__global__ __launch_bounds__(256)
void prep_cross(const u16* __restrict__ vb, u16* __restrict__ vt,
                const float* __restrict__ l1w, u16* __restrict__ l1wt,
                const float* __restrict__ l2w, u16* __restrict__ l2wt)
{
  const int id = blockIdx.x;
  const int tid = threadIdx.x;
  const int tx = tid & 31, ty = tid >> 5;
  if (id < 2048){
    __shared__ u16 tileu[32][33];
    const int z = id >> 10, rem = id & 1023;
    const int c0 = (rem & 15) * 32, r0 = (rem >> 4) * 32;
    const u16* in = vb + (size_t)z * KLn * DIM;
    u16* out = vt + (size_t)z * NH * DH * KLn;
    #pragma unroll
    for (int i = 0; i < 4; ++i)
      tileu[ty + i*8][tx] = in[(size_t)(r0 + ty + i*8)*DIM + c0 + tx];
    __syncthreads();
    const int kv = r0 + tx;
    const int s  = (kv & ~31) | (((kv>>2)&3)<<3) | (((kv>>4)&1)<<2) | (kv&3);
    #pragma unroll
    for (int i = 0; i < 4; ++i){
      const int dcol = c0 + ty + i*8;
      const int hh = dcol >> 6, dh = dcol & 63;
      const int kvpos = (s & ~63) | (((((s>>3)&7) ^ (dh&7)) << 3)) | (s & 7);
      out[((size_t)(hh*DH + dh))*KLn + kvpos] = tileu[tx][ty + i*8];
    }
  } else {
    __shared__ float tilef[32][33];
    const float* in; u16* out; int R, C, rem;
    if (id < 3072){ rem = id - 2048; in = l1w; out = l1wt; R = 512; C = FFD;
      // original grid (64,16): x=rem&63, y=rem>>6
      const int c0 = (rem & 63) * 32, r0 = (rem >> 6) * 32;
      #pragma unroll
      for (int i = 0; i < 4; ++i)
        tilef[ty + i*8][tx] = in[(size_t)(r0 + ty + i*8)*C + c0 + tx];
      __syncthreads();
      #pragma unroll
      for (int i = 0; i < 4; ++i)
        out[(size_t)(c0 + ty + i*8)*R + r0 + tx] = f2b(tilef[tx][ty + i*8]);
    } else { rem = id - 3072; in = l2w; out = l2wt; R = FFD; C = 512;
      const int c0 = (rem & 15) * 32, r0 = (rem >> 4) * 32;
      #pragma unroll
      for (int i = 0; i < 4; ++i)
        tilef[ty + i*8][tx] = in[(size_t)(r0 + ty + i*8)*C + c0 + tx];
      __syncthreads();
      #pragma unroll
      for (int i = 0; i < 4; ++i)
        out[(size_t)(c0 + ty + i*8)*R + r0 + tx] = f2b(tilef[tx][ty + i*8]);
    }
  }
}

// ---------------------------------------------------------------- launch
extern "C" void kernel_launch(void* const* d_in, const int* in_sizes, int n_in,
                              void* d_out, int out_size, void* d_ws, size_t ws_size,
                              hipStream_t stream)
{
  const float* tgt  = (const float*)d_in[1];
  const float* mem  = (const float*)d_in[2];
  const float* pos  = (const float*)d_in[3];
  const float* tkpm = (const float*)d_in[5];
  const int*   mkpm = (const int*)d_in[6];
  const float* saqw = (const float*)d_in[7];  const float* saqb = (const float*)d_in[8];
  const float* sakw = (const float*)d_in[9];  const float* sakb = (const float*)d_in[10];
  const float* savw = (const float*)d_in[11]; const float* savb = (const float*)d_in[12];
  const float* saow = (const float*)d_in[13]; const float* saob = (const float*)d_in[14];
  const float* caqw = (const float*)d_in[15]; const float* caqb = (const float*)d_in[16];
  const float* cakw = (const float*)d_in[17]; const float* cakb = (const float*)d_in[18];
  const float* cavw = (const float*)d_in[19]; const float* cavb = (const float*)d_in[20];
  const float* caow = (const float*)d_in[21]; const float* caob = (const float*)d_in[22];
  const float* l1w  = (const float*)d_in[23]; const float* l1b  = (const float*)d_in[24];
  const float* l2w  = (const float*)d_in[25]; const float* l2b  = (const float*)d_in[26];
  const float* n1g  = (const float*)d_in[27]; const float* n1b  = (const float*)d_in[28];
  const float* n2g  = (const float*)d_in[29]; const float* n2b  = (const float*)d_in[30];
  const float* n3g  = (const float*)d_in[31]; const float* n3b  = (const float*)d_in[32];

  if (ws_size < 58720256) return;  // 56 MB scratch

  char* ws = (char*)d_ws;
  // layout (MB): 0-8 xres | 8-12 t2n | 12-16 qb | 16-20 kb | 20-24 vb |
  // 24-28 vt | 28 smalls | 29-31 l1wt | 31-33 l2wt | 33-37 memb |
  // 37-41 wtA | 41-49 ctxp(bf16 x2) | ffh(16MB) aliases 12-28 in FF phase
  float* xres = (float*)(ws);
  u16* t2n    = (u16*)(ws + (8u<<20));
  u16* qb     = (u16*)(ws + (12u<<20));
  u16* kb     = (u16*)(ws + (16u<<20));
  u16* vb     = (u16*)(ws + (20u<<20));
  u16* vt     = (u16*)(ws + (24u<<20));
  float* bias = (float*)(ws + (28u<<20));              // 16 KB
  float* bc0  = (float*)(ws + (28u<<20) + 16384);      // 6 KB
  float* bc1  = (float*)(ws + (28u<<20) + 24576);      // 4 KB
  float2* mlb = (float2*)(ws + (28u<<20) + 32768);     // 512 KB
  u16* l1wt   = (u16*)(ws + (29u<<20));
  u16* l2wt   = (u16*)(ws + (31u<<20));
  u16* memb   = (u16*)(ws + (33u<<20));
  u16* wtA    = (u16*)(ws + (37u<<20));
  u16* ctxp   = (u16*)(ws + (41u<<20));
  u16* ffh    = (u16*)(ws + (12u<<20));   // aliases qb..vt (dead by FF phase)

  float* out = (float*)d_out;
  const int W55 = 512*512;

  prep_all<<<dim3(4112), 256, 0, stream>>>(saqw, sakw, savw, saow,
                                           caqw, cakw, cavw, caow,
                                           mem, mkpm, saqb, sakb, savb, cakb, cavb,
                                           wtA, memb, bias, bc0, bc1);
  ln_kernel<0><<<MROWS, 128, 0, stream>>>(tgt, pos, tkpm, n1g, n1b, xres, t2n);

  #define G(EP, GX) gemm64<EP><<<dim3(GX,64), 256, 0, stream>>>

  // ---- self attention (fused QKV: N=1536)
  G(EPI_QKV, 24)(t2n, wtA, bc0, qb, nullptr, nullptr, nullptr, 512, 1536);
  transpose_vperm<<<dim3(DIM/32, KLn/32, NB), dim3(32,8), 0, stream>>>(vb, vt);
  attn6<true><<<dim3(QL/64, NH, NB*2), 256, 0, stream>>>(qb, kb, vt, nullptr, ctxp, mlb);
  attn_merge<<<dim3(MROWS*DIM/1024), 256, 0, stream>>>(ctxp, mlb, t2n);
  G(EPI_RES, 8)(t2n, wtA + 3*W55, saob, nullptr, xres, nullptr, nullptr, 512, 512);

  ln_kernel<1><<<MROWS, 128, 0, stream>>>(xres, nullptr, nullptr, n2g, n2b, nullptr, t2n);

  // ---- cross attention (fused KV: N=1024)
  G(EPI_SCALEQ, 8)(t2n,  wtA + 4*W55, caqb, qb, nullptr, nullptr, nullptr, 512, 512);
  G(EPI_KV, 16)(memb, wtA + 5*W55, bc1, kb, nullptr, nullptr, nullptr, 512, 1024);
  prep_cross<<<dim3(4096), 256, 0, stream>>>(vb, vt, l1w, l1wt, l2w, l2wt);
  attn6<false><<<dim3(QL/64, NH, NB*2), 256, 0, stream>>>(qb, kb, vt, bias, ctxp, mlb);
  attn_merge<<<dim3(MROWS*DIM/1024), 256, 0, stream>>>(ctxp, mlb, t2n);
  G(EPI_RES, 8)(t2n, wtA + 7*W55, caob, nullptr, xres, nullptr, nullptr, 512, 512);

  ln_kernel<1><<<MROWS, 128, 0, stream>>>(xres, nullptr, nullptr, n3g, n3b, nullptr, t2n);

  // ---- feed-forward (FF2 epilogue fuses residual add + tkpm scale + f32 out)
  G(EPI_RELU, 32)(t2n, l1wt, l1b, ffh, nullptr, nullptr, nullptr, 512, FFD);
  G(EPI_FIN, 8)(ffh, l2wt, l2b, nullptr, xres, tkpm, out, 2048, 512);

  #undef G
}

// Round 11
// 193.192 us; speedup vs baseline: 2.8099x; 1.0044x over previous
//
#include <hip/hip_runtime.h>
#include <hip/hip_bf16.h>
#include <stdint.h>

#define QL   2048
#define KLn  2048
#define DIM  512
#define NH   8
#define DH   64
#define NB   2
#define MROWS (NB*QL)   // 4096
#define FFD  2048

typedef unsigned short u16;
typedef unsigned int u32;
typedef __attribute__((ext_vector_type(8))) short short8;
typedef __attribute__((ext_vector_type(4))) float f32x4;

__device__ __forceinline__ u16 f2b(float f){
  union { float f; u32 i; } v; v.f = f;
  u32 r = v.i + 0x7FFFu + ((v.i >> 16) & 1u);
  return (u16)(r >> 16);
}
__device__ __forceinline__ float b2f(u16 u){
  union { u32 i; float f; } v; v.i = ((u32)u) << 16; return v.f;
}
// two f32 -> packed bf16x2 in one instruction (lo=a, hi=b, RNE)
__device__ __forceinline__ u32 cvtpk(float a, float b){
  u32 r;
  asm("v_cvt_pk_bf16_f32 %0, %1, %2" : "=v"(r) : "v"(a), "v"(b));
  return r;
}

typedef __attribute__((address_space(3))) void as3void;
typedef __attribute__((address_space(1))) void as1void;
__device__ __forceinline__ void gload_lds16(const void* g, void* l){
  __builtin_amdgcn_global_load_lds((as1void*)g, (as3void*)l, 16, 0, 0);
}

// ---------------------------------------------------------------- GEMM (64x64)
// 64x64 tiles, 4 waves of 32x32, BK=64, chunk-XOR bank swizzle (both-sides
// involution), XCD-chunked block swizzle. R11: double-buffered LDS with
// counted-vmcnt raw-barrier protocol (T3/T4): each stage = exactly 4
// global_load_lds; "stage(next); vmcnt(4); s_barrier; reads; s_barrier; MFMA"
// -- the next tile's loads stay in flight across the barriers instead of
// being drained by __syncthreads' vmcnt(0).
#define BK 64
enum { EPI_BIAS=0, EPI_SCALEQ=1, EPI_RELU=2, EPI_RES=3, EPI_FIN=5, EPI_QKV=6, EPI_KV=7 };
// 1/sqrt(64) * log2(e): folds softmax exp->exp2 conversion into Q scale
#define QSCALE 0.1803368801111244f

template<int EPI>
__global__ __launch_bounds__(256, 4)
void gemm64(const u16* __restrict__ A, const u16* __restrict__ Bt,
            const float* __restrict__ bias,
            u16* __restrict__ Obf, float* __restrict__ Ores,
            const float* __restrict__ tk, float* __restrict__ fout,
            int K, int N)
{
  __shared__ __align__(16) u16 As[2][64*BK];
  __shared__ __align__(16) u16 Bs[2][64*BK];
  const int t  = threadIdx.x;
  const int l  = t & 63;
  const int lq = l & 15, lg = l >> 4;
  const int w  = t >> 6;
  const int wm = (w >> 1) * 32;
  const int wn = (w & 1) * 32;

  // XCD-chunked swizzle (all our grids have nwg % 8 == 0)
  const int gx   = gridDim.x;
  const int nwg  = gx * gridDim.y;
  const int orig = blockIdx.x + gx * blockIdx.y;
  const int wgid = (orig & 7) * (nwg >> 3) + (orig >> 3);
  const int m0 = (wgid / gx) * 64;
  const int n0 = (wgid % gx) * 64;

  const int srow = t >> 3;   // 0..31
  const int scs  = t & 7;

  // 4 gload ops per stage call (2 A + 2 B)
  auto stageG = [&](u16* dA, u16* dB, int k0){
    _Pragma("unroll")
    for (int i = 0; i < 2; ++i){
      const int row = i*32 + srow;
      gload_lds16(A  + (size_t)(m0 + row)*K + k0 + ((scs ^ (row & 7)) << 3),
                  dA + row*BK + scs*8);
      gload_lds16(Bt + (size_t)(n0 + row)*K + k0 + ((scs ^ (row & 7)) << 3),
                  dB + row*BK + scs*8);
    }
  };

  // hoisted LDS byte offsets (loop-invariant)
  int aoff[2][2], boff[2][2];
  _Pragma("unroll")
  for (int i = 0; i < 2; ++i)
    _Pragma("unroll")
    for (int kc = 0; kc < 2; ++kc){
      const int sw = (((kc*4 + lg) ^ (lq & 7)) << 3);
      aoff[i][kc] = ((wm + i*16 + lq)*BK + sw) * 2;
      boff[i][kc] = ((wn + i*16 + lq)*BK + sw) * 2;
    }

  f32x4 acc[2][2];
  _Pragma("unroll")
  for (int i=0;i<2;i++)
    _Pragma("unroll")
    for (int j=0;j<2;j++) acc[i][j] = (f32x4){0.f,0.f,0.f,0.f};

#define GBODY(BUF, KK)                                                        \
  {                                                                           \
    { const int ks = ((KK) + BK < K) ? (KK) + BK : 0;                         \
      stageG(As[(BUF)^1], Bs[(BUF)^1], ks); }                                 \
    asm volatile("s_waitcnt vmcnt(4)" ::: "memory");                          \
    __builtin_amdgcn_s_barrier();                                             \
    __builtin_amdgcn_sched_barrier(0);                                        \
    short8 af[2][2], bf[2][2];                                                \
    _Pragma("unroll")                                                         \
    for (int kc = 0; kc < 2; ++kc)                                            \
      _Pragma("unroll")                                                       \
      for (int i = 0; i < 2; ++i){                                            \
        af[i][kc] = *(const short8*)((const char*)As + (BUF)*8192 + aoff[i][kc]); \
        bf[i][kc] = *(const short8*)((const char*)Bs + (BUF)*8192 + boff[i][kc]); \
      }                                                                       \
    __builtin_amdgcn_s_barrier();                                             \
    __builtin_amdgcn_s_setprio(1);                                            \
    _Pragma("unroll")                                                         \
    for (int kc = 0; kc < 2; ++kc)                                            \
      _Pragma("unroll")                                                       \
      for (int i = 0; i < 2; ++i)                                             \
        _Pragma("unroll")                                                     \
        for (int j = 0; j < 2; ++j)                                           \
          acc[i][j] = __builtin_amdgcn_mfma_f32_16x16x32_bf16(af[i][kc], bf[j][kc], acc[i][j], 0,0,0); \
    __builtin_amdgcn_s_setprio(0);                                            \
  }

  stageG(As[0], Bs[0], 0);
  for (int k0 = 0; k0 < K; k0 += 2*BK){
    GBODY(0, k0)
    GBODY(1, k0 + BK)
  }
#undef GBODY

  _Pragma("unroll")
  for (int i=0;i<2;i++){
    _Pragma("unroll")
    for (int j=0;j<2;j++){
      _Pragma("unroll")
      for (int rr=0;rr<4;rr++){
        const int row = m0 + wm + i*16 + lg*4 + rr;
        const int col = n0 + wn + j*16 + lq;
        float v = acc[i][j][rr] + bias[col];
        if (EPI == EPI_SCALEQ) v *= QSCALE;
        if (EPI == EPI_RELU)   v = fmaxf(v, 0.f);
        if (EPI == EPI_RES)    Ores[(size_t)row*N + col] += v;
        else if (EPI == EPI_FIN){
          const size_t idx = (size_t)row*N + col;
          fout[idx] = (Ores[idx] + v) * tk[row];
        }
        else if (EPI == EPI_QKV){
          // contiguous q|k|v buffers (2M u16 each). seg uniform per block.
          const int seg = col >> 9, c = col & 511;
          if (seg == 0)      Obf[(size_t)row*512 + c] = f2b(v * QSCALE);
          else if (seg == 1){
            const int bb = row >> 11, kv = row & 2047;
            const int hh = c >> 6,  dh = c & 63;
            Obf[(2u<<20) + ((((size_t)(bb*NH + hh) << 11) + kv) << 6) + (dh ^ ((kv & 7) << 3))] = f2b(v);
          }
          else               Obf[(4u<<20) + (size_t)row*512 + c] = f2b(v);
        }
        else if (EPI == EPI_KV){
          const int seg = col >> 9, c = col & 511;
          if (seg == 0){
            const int bb = row >> 11, kv = row & 2047;
            const int hh = c >> 6,  dh = c & 63;
            Obf[((((size_t)(bb*NH + hh) << 11) + kv) << 6) + (dh ^ ((kv & 7) << 3))] = f2b(v);
          }
          else               Obf[(2u<<20) + (size_t)row*512 + c] = f2b(v);
        }
        else                   Obf[(size_t)row*N + col] = f2b(v);
      }
    }
  }
}

// ---------------------------------------------------------------- attention v7
// = v6c structure (4 waves x 16 q-rows, KVBLK=64, cross-block KV-split x2,
// baked XOR swizzle, swapped QK^T, lane-local P, defer-max, setprio, cvt_pk,
// bf16 partials) with:
//  - loop unrolled x2 -> compile-time buffer index; all 16 LDS read offsets
//    precomputed pre-loop (buffer select folds into ds offset immediate)
//  - counted-vmcnt raw-barrier protocol: stage = exactly 4 gload ops;
//    cross-attn bias f32x4 loads issued BEFORE the stage so manual wait is
//    vmcnt(8) and the compiler's own bias wait (vmcnt(4)) leaves the
//    prefetch in flight. Causal: vmcnt(4).
template<bool CAUSAL>
__global__ __launch_bounds__(256, 4)
void attn7(const u16* __restrict__ Q, const u16* __restrict__ Kbh,
           const u16* __restrict__ Vth, const float* __restrict__ bias,
           u16* __restrict__ ctxp, float2* __restrict__ mlb)
{
  __shared__ __align__(16) u16 Kl[2][64*64];
  __shared__ __align__(16) u16 Vl[2][64*64];
  const int tid = threadIdx.x;
  const int l  = tid & 63;
  const int w  = tid >> 6;
  const int lq = l & 15, lg = l >> 4;
  const int h    = blockIdx.y;
  const int b    = blockIdx.z >> 1;
  const int half = blockIdx.z & 1;
  const int qtile = CAUSAL ? ((b & 1) ? (31 - (int)blockIdx.x) : (int)blockIdx.x)
                           : (int)blockIdx.x;
  const int q0w = qtile*64 + w*16;

  const u16* kg = Kbh + ((size_t)(b*NH + h) << 17);   // [2048][64]
  const u16* vg = Vth + ((size_t)(b*NH + h) << 17);   // [64][2048]

  short8 aq[2];
  _Pragma("unroll")
  for (int kc = 0; kc < 2; ++kc)
    aq[kc] = *(const short8*)(Q + (size_t)(b*QL + q0w + lq)*DIM + h*DH + kc*32 + lg*8);

  // hoisted LDS byte offsets (sub*16 and d0*16 are 0 mod 8 so swizzle term
  // depends only on lq&7)
  int koff[4][2], voff[4][2];
  _Pragma("unroll")
  for (int j = 0; j < 4; ++j)
    _Pragma("unroll")
    for (int kc = 0; kc < 2; ++kc){
      const int sw = (((kc*4 + lg) ^ (lq & 7)) << 3);
      koff[j][kc] = ((j*16 + lq)*64 + sw) * 2;
      voff[j][kc] = koff[j][kc];
    }

  f32x4 ctx[4];
  _Pragma("unroll")
  for (int d = 0; d < 4; ++d) ctx[d] = (f32x4){0.f,0.f,0.f,0.f};
  f32x4 lsum4 = (f32x4){0.f,0.f,0.f,0.f};
  float m = -INFINITY;

  const int ntiles = CAUSAL ? (qtile + 1) : (KLn >> 6);
  const int P = (ntiles > half) ? ((ntiles - half + 1) >> 1) : 0;

  // 4 gload ops per stage call (2 K + 2 V)
  auto stageA = [&](u16* dK, u16* dV, int tile){
    const u16* kgs = kg + ((size_t)tile << 12);
    const u16* vgs = vg + tile*64;
    gload_lds16(kgs + w*1024 + l*8,       dK + w*1024 + l*8);
    gload_lds16(kgs + w*1024 + 512 + l*8, dK + w*1024 + 512 + l*8);
    gload_lds16(vgs + (size_t)(w*16 +     (l>>3))*KLn + (l&7)*8, dV + w*1024 + l*8);
    gload_lds16(vgs + (size_t)(w*16 + 8 + (l>>3))*KLn + (l&7)*8, dV + w*1024 + 512 + l*8);
  };

#define ABODY(BUF, TT)                                                        \
  {                                                                           \
    f32x4 bv[4];                                                              \
    if (!CAUSAL){                                                             \
      _Pragma("unroll")                                                       \
      for (int sub = 0; sub < 4; ++sub)                                       \
        bv[sub] = *(const f32x4*)(bias + b*KLn + (TT)*64 + sub*16 + lg*4);    \
    }                                                                         \
    { const int ts = ((TT) + 2 < ntiles) ? (TT) + 2 : half;                   \
      stageA(Kl[(BUF)^1], Vl[(BUF)^1], ts); }                                 \
    if (CAUSAL) asm volatile("s_waitcnt vmcnt(4)" ::: "memory");              \
    else        asm volatile("s_waitcnt vmcnt(8)" ::: "memory");              \
    __builtin_amdgcn_s_barrier();                                             \
    __builtin_amdgcn_sched_barrier(0);                                        \
    f32x4 s[4];                                                               \
    _Pragma("unroll")                                                         \
    for (int sub = 0; sub < 4; ++sub) s[sub] = (f32x4){0.f,0.f,0.f,0.f};      \
    __builtin_amdgcn_s_setprio(1);                                            \
    _Pragma("unroll")                                                         \
    for (int sub = 0; sub < 4; ++sub)                                         \
      _Pragma("unroll")                                                       \
      for (int kc = 0; kc < 2; ++kc){                                         \
        short8 bk = *(const short8*)((const char*)Kl + (BUF)*8192 + koff[sub][kc]); \
        s[sub] = __builtin_amdgcn_mfma_f32_16x16x32_bf16(bk, aq[kc], s[sub], 0,0,0); \
      }                                                                       \
    __builtin_amdgcn_s_setprio(0);                                            \
    if (CAUSAL){                                                              \
      if ((TT)*64 + 63 > q0w){                                                \
        _Pragma("unroll")                                                     \
        for (int sub = 0; sub < 4; ++sub)                                     \
          _Pragma("unroll")                                                   \
          for (int rr = 0; rr < 4; ++rr)                                      \
            if ((TT)*64 + sub*16 + lg*4 + rr > q0w + lq) s[sub][rr] = -INFINITY; \
      }                                                                       \
    } else {                                                                  \
      _Pragma("unroll")                                                       \
      for (int sub = 0; sub < 4; ++sub) s[sub] += bv[sub];                    \
    }                                                                         \
    float mx[4];                                                              \
    _Pragma("unroll")                                                         \
    for (int sub = 0; sub < 4; ++sub)                                         \
      mx[sub] = fmaxf(fmaxf(s[sub][0], s[sub][1]), fmaxf(s[sub][2], s[sub][3])); \
    float pmax = fmaxf(fmaxf(mx[0], mx[1]), fmaxf(mx[2], mx[3]));             \
    if (!__all(pmax <= m + 8.0f)){                                            \
      pmax = fmaxf(pmax, __shfl_xor(pmax, 16));                               \
      pmax = fmaxf(pmax, __shfl_xor(pmax, 32));                               \
      const float mnew = fmaxf(m, pmax);                                      \
      const float corr = exp2f(m - mnew);                                     \
      lsum4 *= corr;                                                          \
      float corr4[4];                                                         \
      _Pragma("unroll")                                                       \
      for (int rr = 0; rr < 4; ++rr) corr4[rr] = __shfl(corr, lg*4 + rr);     \
      _Pragma("unroll")                                                       \
      for (int d = 0; d < 4; ++d)                                             \
        _Pragma("unroll")                                                     \
        for (int rr = 0; rr < 4; ++rr) ctx[d][rr] *= corr4[rr];               \
      m = mnew;                                                               \
    }                                                                         \
    u32 pk[4][2];                                                             \
    _Pragma("unroll")                                                         \
    for (int sub = 0; sub < 4; ++sub){                                        \
      float p0 = exp2f(s[sub][0] - m);                                        \
      float p1 = exp2f(s[sub][1] - m);                                        \
      float p2 = exp2f(s[sub][2] - m);                                        \
      float p3 = exp2f(s[sub][3] - m);                                        \
      lsum4 += (f32x4){p0, p1, p2, p3};                                       \
      pk[sub][0] = cvtpk(p0, p1);                                             \
      pk[sub][1] = cvtpk(p2, p3);                                             \
    }                                                                         \
    union { u32 u[4]; short8 s8; } pa0, pa1;                                  \
    pa0.u[0] = pk[0][0]; pa0.u[1] = pk[0][1]; pa0.u[2] = pk[1][0]; pa0.u[3] = pk[1][1]; \
    pa1.u[0] = pk[2][0]; pa1.u[1] = pk[2][1]; pa1.u[2] = pk[3][0]; pa1.u[3] = pk[3][1]; \
    __builtin_amdgcn_s_setprio(1);                                            \
    _Pragma("unroll")                                                         \
    for (int d0 = 0; d0 < 4; ++d0){                                           \
      short8 v0 = *(const short8*)((const char*)Vl + (BUF)*8192 + voff[d0][0]); \
      short8 v1 = *(const short8*)((const char*)Vl + (BUF)*8192 + voff[d0][1]); \
      ctx[d0] = __builtin_amdgcn_mfma_f32_16x16x32_bf16(pa0.s8, v0, ctx[d0], 0,0,0); \
      ctx[d0] = __builtin_amdgcn_mfma_f32_16x16x32_bf16(pa1.s8, v1, ctx[d0], 0,0,0); \
    }                                                                         \
    __builtin_amdgcn_s_setprio(0);                                            \
    __builtin_amdgcn_s_barrier();                                             \
  }

  if (P > 0){
    stageA(Kl[0], Vl[0], half);
    int t = half;
    for (int it = 0; it < P; it += 2){
      ABODY(0, t)
      if (it + 1 < P) ABODY(1, t + 2)
      t += 4;
    }
  }
#undef ABODY

  // ---- write bf16 partials (merge kernel normalizes)
  float hs = (lsum4[0] + lsum4[1]) + (lsum4[2] + lsum4[3]);
  hs += __shfl_xor(hs, 16);
  hs += __shfl_xor(hs, 32);
  if (lg == 0)
    mlb[((size_t)((half*NB + b)*NH + h) << 11) + q0w + lq] = make_float2(m, hs);
  u16* cp = ctxp + (size_t)half*MROWS*DIM;
  _Pragma("unroll")
  for (int d0 = 0; d0 < 4; ++d0)
    _Pragma("unroll")
    for (int rr = 0; rr < 4; ++rr)
      cp[(size_t)(b*QL + q0w + lg*4 + rr)*DIM + h*DH + d0*16 + lq] = f2b(ctx[d0][rr]);
}

// merge the two KV-half partials: out = sum(ctx_k*w_k)/sum(l_k*w_k)
__global__ __launch_bounds__(256)
void attn_merge(const u16* __restrict__ ctxp, const float2* __restrict__ mlb,
                u16* __restrict__ O)
{
  const int idx = blockIdx.x*256 + threadIdx.x;
  const int row = idx >> 7;          // 0..4095
  const int col = (idx & 127) * 4;   // 0..508
  const int b = row >> 11, qr = row & 2047, h = col >> 6;
  const float2 a0 = mlb[((size_t)((      b)*NH + h) << 11) + qr];
  const float2 a1 = mlb[((size_t)((NB  + b)*NH + h) << 11) + qr];
  const float mg = fmaxf(a0.x, a1.x);
  const float w0 = exp2f(a0.x - mg), w1 = exp2f(a1.x - mg);
  const float rden = 1.f / (a0.y*w0 + a1.y*w1);
  union { uint2 v; u16 h4[4]; } c0u, c1u;
  c0u.v = *(const uint2*)&ctxp[(size_t)row*DIM + col];
  c1u.v = *(const uint2*)&ctxp[(size_t)MROWS*DIM + (size_t)row*DIM + col];
  u16 o[4];
  #pragma unroll
  for (int i = 0; i < 4; ++i)
    o[i] = f2b((b2f(c0u.h4[i])*w0 + b2f(c1u.h4[i])*w1) * rden);
  *(uint2*)&O[(size_t)row*DIM + col] = *(const uint2*)o;
}

// ---------------------------------------------------------------- layernorm
template<int MODE>
__global__ __launch_bounds__(128)
void ln_kernel(const float* __restrict__ in0, const float* __restrict__ in1,
               const float* __restrict__ tkpm,
               const float* __restrict__ g, const float* __restrict__ bvec,
               float* __restrict__ xres, u16* __restrict__ outb)
{
  const int row = blockIdx.x;
  const int t = threadIdx.x;
  float v[4];
  #pragma unroll
  for (int i = 0; i < 4; ++i){
    const int c = t + i*128;
    float x = in0[(size_t)row*DIM + c];
    if (MODE == 0){
      x += in1[(size_t)row*DIM + c];
      xres[(size_t)row*DIM + c] = x;
    }
    v[i] = x;
  }
  float s = v[0]+v[1]+v[2]+v[3];
  #pragma unroll
  for (int off = 1; off < 64; off <<= 1) s += __shfl_xor(s, off);
  __shared__ float red[4];
  if ((t & 63) == 0) red[t >> 6] = s;
  __syncthreads();
  const float mean = (red[0] + red[1]) * (1.f/512.f);
  float q = 0.f;
  #pragma unroll
  for (int i = 0; i < 4; ++i){ const float d = v[i]-mean; q += d*d; }
  #pragma unroll
  for (int off = 1; off < 64; off <<= 1) q += __shfl_xor(q, off);
  if ((t & 63) == 0) red[2 + (t >> 6)] = q;
  __syncthreads();
  const float var = (red[2] + red[3]) * (1.f/512.f);
  const float rs = rsqrtf(var + 1e-5f);
  const float tk = (MODE == 0) ? tkpm[row] : 1.f;
  #pragma unroll
  for (int i = 0; i < 4; ++i){
    const int c = t + i*128;
    const float y = (v[i] - mean) * rs * g[c] + bvec[c];
    outb[(size_t)row*DIM + c] = f2b(y * tk);
  }
}

// ---------------------------------------------------------------- fused prep
__global__ __launch_bounds__(256)
void prep_all(const float* w0, const float* w1, const float* w2, const float* w3,
              const float* w4, const float* w5, const float* w6, const float* w7,
              const float* __restrict__ mem, const int* __restrict__ mkpm,
              const float* saqb, const float* sakb, const float* savb,
              const float* cakb, const float* cavb,
              u16* __restrict__ wtA, u16* __restrict__ memb,
              float* __restrict__ bias, float* __restrict__ bc0,
              float* __restrict__ bc1)
{
  __shared__ float tile[32][33];
  const int id = blockIdx.x;
  const int tid = threadIdx.x;
  if (id < 2048){
    const int z = id >> 8, rem = id & 255;
    const int r0 = (rem >> 4) * 32, c0 = (rem & 15) * 32;
    const float* wp[8] = {w0,w1,w2,w3,w4,w5,w6,w7};
    const float* w = wp[z];
    u16* o = wtA + (size_t)z * 512 * 512;
    const int tx = tid & 31, ty = tid >> 5;
    #pragma unroll
    for (int i = 0; i < 4; ++i)
      tile[ty + i*8][tx] = w[(size_t)(r0 + ty + i*8)*512 + c0 + tx];
    __syncthreads();
    #pragma unroll
    for (int i = 0; i < 4; ++i)
      o[(size_t)(c0 + ty + i*8)*512 + r0 + tx] = f2b(tile[tx][ty + i*8]);
  } else if (id < 4096){
    const int i = (id - 2048)*1024 + tid*4;
    f32x4 v = *(const f32x4*)&mem[i];
    uint2 p; p.x = cvtpk(v[0], v[1]); p.y = cvtpk(v[2], v[3]);
    *(uint2*)&memb[i] = p;
  } else {
    const int j = (id - 4096)*256 + tid;   // 0..4095
    bias[j] = mkpm[j] ? 0.f : -1e30f;
    if (j < 1536) bc0[j] = (j < 512) ? saqb[j] : (j < 1024) ? sakb[j-512] : savb[j-1024];
    if (j < 1024) bc1[j] = (j < 512) ? cakb[j] : cavb[j-512];
  }
}

// V [b][kv][512] -> Vth [b][h][dh][kv'] with PV K-slot permutation AND
// bank XOR-swizzle folded into the kv index. (standalone, self-attn side)
__global__ __launch_bounds__(256)
void transpose_vperm(const u16* __restrict__ in, u16* __restrict__ out)
{
  __shared__ u16 tile[32][33];
  in  += (size_t)blockIdx.z * KLn * DIM;
  out += (size_t)blockIdx.z * NH * DH * KLn;
  const int tx = threadIdx.x, ty = threadIdx.y;
  const int r0 = blockIdx.y*32, c0 = blockIdx.x*32;   // r=kv, c=dcol
  #pragma unroll
  for (int i = 0; i < 4; ++i)
    tile[ty + i*8][tx] = in[(size_t)(r0 + ty + i*8)*DIM + c0 + tx];
  __syncthreads();
  const int kv = r0 + tx;
  const int s  = (kv & ~31) | (((kv>>2)&3)<<3) | (((kv>>4)&1)<<2) | (kv&3);
  #pragma unroll
  for (int i = 0; i < 4; ++i){
    const int dcol = c0 + ty + i*8;
    const int hh = dcol >> 6, dh = dcol & 63;
    const int kvpos = (s & ~63) | (((((s>>3)&7) ^ (dh&7)) << 3)) | (s & 7);
    out[((size_t)(hh*DH + dh))*KLn + kvpos] = tile[tx][ty + i*8];
  }
}

// Cross-side fused: V perm-transpose (blocks 0..2047) + l1w^T (2048..3071)
// + l2w^T (3072..4095).
__global__ __launch_bounds__(256)
void prep_cross(const u16* __restrict__ vb, u16* __restrict__ vt,
                const float* __restrict__ l1w, u16* __restrict__ l1wt,
                const float* __restrict__ l2w, u16* __restrict__ l2wt)
{
  const int id = blockIdx.x;
  const int tid = threadIdx.x;
  const int tx = tid & 31, ty = tid >> 5;
  if (id < 2048){
    __shared__ u16 tileu[32][33];
    const int z = id >> 10, rem = id & 1023;
    const int c0 = (rem & 15) * 32, r0 = (rem >> 4) * 32;
    const u16* in = vb + (size_t)z * KLn * DIM;
    u16* out = vt + (size_t)z * NH * DH * KLn;
    #pragma unroll
    for (int i = 0; i < 4; ++i)
      tileu[ty + i*8][tx] = in[(size_t)(r0 + ty + i*8)*DIM + c0 + tx];
    __syncthreads();
    const int kv = r0 + tx;
    const int s  = (kv & ~31) | (((kv>>2)&3)<<3) | (((kv>>4)&1)<<2) | (kv&3);
    #pragma unroll
    for (int i = 0; i < 4; ++i){
      const int dcol = c0 + ty + i*8;
      const int hh = dcol >> 6, dh = dcol & 63;
      const int kvpos = (s & ~63) | (((((s>>3)&7) ^ (dh&7)) << 3)) | (s & 7);
      out[((size_t)(hh*DH + dh))*KLn + kvpos] = tileu[tx][ty + i*8];
    }
  } else {
    __shared__ float tilef[32][33];
    if (id < 3072){
      const int rem = id - 2048;
      const int c0 = (rem & 63) * 32, r0 = (rem >> 6) * 32;
      #pragma unroll
      for (int i = 0; i < 4; ++i)
        tilef[ty + i*8][tx] = l1w[(size_t)(r0 + ty + i*8)*FFD + c0 + tx];
      __syncthreads();
      #pragma unroll
      for (int i = 0; i < 4; ++i)
        l1wt[(size_t)(c0 + ty + i*8)*512 + r0 + tx] = f2b(tilef[tx][ty + i*8]);
    } else {
      const int rem = id - 3072;
      const int c0 = (rem & 15) * 32, r0 = (rem >> 4) * 32;
      #pragma unroll
      for (int i = 0; i < 4; ++i)
        tilef[ty + i*8][tx] = l2w[(size_t)(r0 + ty + i*8)*512 + c0 + tx];
      __syncthreads();
      #pragma unroll
      for (int i = 0; i < 4; ++i)
        l2wt[(size_t)(c0 + ty + i*8)*FFD + r0 + tx] = f2b(tilef[tx][ty + i*8]);
    }
  }
}

// ---------------------------------------------------------------- launch
extern "C" void kernel_launch(void* const* d_in, const int* in_sizes, int n_in,
                              void* d_out, int out_size, void* d_ws, size_t ws_size,
                              hipStream_t stream)
{
  const float* tgt  = (const float*)d_in[1];
  const float* mem  = (const float*)d_in[2];
  const float* pos  = (const float*)d_in[3];
  const float* tkpm = (const float*)d_in[5];
  const int*   mkpm = (const int*)d_in[6];
  const float* saqw = (const float*)d_in[7];  const float* saqb = (const float*)d_in[8];
  const float* sakw = (const float*)d_in[9];  const float* sakb = (const float*)d_in[10];
  const float* savw = (const float*)d_in[11]; const float* savb = (const float*)d_in[12];
  const float* saow = (const float*)d_in[13]; const float* saob = (const float*)d_in[14];
  const float* caqw = (const float*)d_in[15]; const float* caqb = (const float*)d_in[16];
  const float* cakw = (const float*)d_in[17]; const float* cakb = (const float*)d_in[18];
  const float* cavw = (const float*)d_in[19]; const float* cavb = (const float*)d_in[20];
  const float* caow = (const float*)d_in[21]; const float* caob = (const float*)d_in[22];
  const float* l1w  = (const float*)d_in[23]; const float* l1b  = (const float*)d_in[24];
  const float* l2w  = (const float*)d_in[25]; const float* l2b  = (const float*)d_in[26];
  const float* n1g  = (const float*)d_in[27]; const float* n1b  = (const float*)d_in[28];
  const float* n2g  = (const float*)d_in[29]; const float* n2b  = (const float*)d_in[30];
  const float* n3g  = (const float*)d_in[31]; const float* n3b  = (const float*)d_in[32];

  if (ws_size < 58720256) return;  // 56 MB scratch

  char* ws = (char*)d_ws;
  float* xres = (float*)(ws);
  u16* t2n    = (u16*)(ws + (8u<<20));
  u16* qb     = (u16*)(ws + (12u<<20));
  u16* kb     = (u16*)(ws + (16u<<20));
  u16* vb     = (u16*)(ws + (20u<<20));
  u16* vt     = (u16*)(ws + (24u<<20));
  float* bias = (float*)(ws + (28u<<20));              // 16 KB
  float* bc0  = (float*)(ws + (28u<<20) + 16384);      // 6 KB
  float* bc1  = (float*)(ws + (28u<<20) + 24576);      // 4 KB
  float2* mlb = (float2*)(ws + (28u<<20) + 32768);     // 512 KB
  u16* l1wt   = (u16*)(ws + (29u<<20));
  u16* l2wt   = (u16*)(ws + (31u<<20));
  u16* memb   = (u16*)(ws + (33u<<20));
  u16* wtA    = (u16*)(ws + (37u<<20));
  u16* ctxp   = (u16*)(ws + (41u<<20));
  u16* ffh    = (u16*)(ws + (12u<<20));   // aliases qb..vt (dead by FF phase)

  float* out = (float*)d_out;
  const int W55 = 512*512;

  prep_all<<<dim3(4112), 256, 0, stream>>>(saqw, sakw, savw, saow,
                                           caqw, cakw, cavw, caow,
                                           mem, mkpm, saqb, sakb, savb, cakb, cavb,
                                           wtA, memb, bias, bc0, bc1);
  ln_kernel<0><<<MROWS, 128, 0, stream>>>(tgt, pos, tkpm, n1g, n1b, xres, t2n);

  #define G(EP, GX) gemm64<EP><<<dim3(GX,64), 256, 0, stream>>>

  // ---- self attention (fused QKV: N=1536)
  G(EPI_QKV, 24)(t2n, wtA, bc0, qb, nullptr, nullptr, nullptr, 512, 1536);
  transpose_vperm<<<dim3(DIM/32, KLn/32, NB), dim3(32,8), 0, stream>>>(vb, vt);
  attn7<true><<<dim3(QL/64, NH, NB*2), 256, 0, stream>>>(qb, kb, vt, nullptr, ctxp, mlb);
  attn_merge<<<dim3(MROWS*DIM/1024), 256, 0, stream>>>(ctxp, mlb, t2n);
  G(EPI_RES, 8)(t2n, wtA + 3*W55, saob, nullptr, xres, nullptr, nullptr, 512, 512);

  ln_kernel<1><<<MROWS, 128, 0, stream>>>(xres, nullptr, nullptr, n2g, n2b, nullptr, t2n);

  // ---- cross attention (fused KV: N=1024)
  G(EPI_SCALEQ, 8)(t2n,  wtA + 4*W55, caqb, qb, nullptr, nullptr, nullptr, 512, 512);
  G(EPI_KV, 16)(memb, wtA + 5*W55, bc1, kb, nullptr, nullptr, nullptr, 512, 1024);
  prep_cross<<<dim3(4096), 256, 0, stream>>>(vb, vt, l1w, l1wt, l2w, l2wt);
  attn7<false><<<dim3(QL/64, NH, NB*2), 256, 0, stream>>>(qb, kb, vt, bias, ctxp, mlb);
  attn_merge<<<dim3(MROWS*DIM/1024), 256, 0, stream>>>(ctxp, mlb, t2n);
  G(EPI_RES, 8)(t2n, wtA + 7*W55, caob, nullptr, xres, nullptr, nullptr, 512, 512);

  ln_kernel<1><<<MROWS, 128, 0, stream>>>(xres, nullptr, nullptr, n3g, n3b, nullptr, t2n);

  // ---- feed-forward (FF2 epilogue fuses residual add + tkpm scale + f32 out)
  G(EPI_RELU, 32)(t2n, l1wt, l1b, ffh, nullptr, nullptr, nullptr, 512, FFD);
  G(EPI_FIN, 8)(ffh, l2wt, l2b, nullptr, xres, tkpm, out, 2048, 512);

  #undef G
}